// Round 1
// baseline (409.658 us; speedup 1.0000x reference)
//
#include <hip/hip_runtime.h>

#define H 512
#define S 256
#define B 32
#define R 16
#define IN_N 4
#define NN 16
#define NTOT 20   // IN+NN
#define OPN 6
#define NEG -1000000000000.0f

__device__ __forceinline__ float fast_tanh(float x) {
  float t = __expf(-2.f * fabsf(x));
  float r = (1.f - t) / (1.f + t);
  return copysignf(r, x);
}
__device__ __forceinline__ float fast_sigmoid(float x) {
  return 1.f / (1.f + __expf(-x));
}

// ---------------- gates: current_node ----------------
__global__ __launch_bounds__(512) void k_gates(
    const float* node_emb, const float* left, const int* has_left,
    const float* Wcl, const float* bcl, const float* Wclg, const float* bclg,
    const float* Wcr, const float* bcr, const float* Wcrg, const float* bcrg,
    float* cur_node, float* out_cn)
{
  int b = blockIdx.x; int h = threadIdx.x;
  __shared__ float sc[H], sl[H];
  sc[h] = node_emb[b*H + h];
  sl[h] = left[b*H + h];
  __syncthreads();
  float a1 = 0.f, a2 = 0.f, v;
  if (has_left[b]) {
    for (int k = 0; k < 2*H; ++k) {
      float x = (k < H) ? sl[k] : sc[k - H];
      a1 += x * Wcr[k*H + h];
      a2 += x * Wcrg[k*H + h];
    }
    v = fast_tanh(a1 + bcr[h]) * fast_sigmoid(a2 + bcrg[h]);
  } else {
    for (int k = 0; k < H; ++k) {
      float x = sc[k];
      a1 += x * Wcl[k*H + h];
      a2 += x * Wclg[k*H + h];
    }
    v = fast_tanh(a1 + bcl[h]) * fast_sigmoid(a2 + bclg[h]);
  }
  cur_node[b*H + h] = v;
  out_cn[b*H + h] = v;
}

// ---------------- CW = cur_node@Wh + battn ; FW = fs@Wff + bfattn ----------------
__global__ __launch_bounds__(512) void k_cwfw(
    const float* cur_node, const float* fs,
    const float* Wattn, const float* battn,
    const float* Wfattn, const float* bfattn,
    float* CW, float* FW)
{
  int r = blockIdx.x; int h = threadIdx.x;
  __shared__ float src[H];
  if (r < B) src[h] = cur_node[r*H + h];
  else       src[h] = fs[(r - B)*H + h];
  __syncthreads();
  float acc = 0.f;
  if (r < B) {
    for (int k = 0; k < H; ++k) acc += src[k] * Wattn[k*H + h];        // Wh
    CW[r*H + h] = acc + battn[h];
  } else {
    for (int k = 0; k < H; ++k) acc += src[k] * Wfattn[(H + k)*H + h]; // Wff
    FW[(r - B)*H + h] = acc + bfattn[h];
  }
}

// ---------------- generic f32 tiled GEMM: C = act(A@W + bias) ----------------
#define BM 64
#define BN 64
#define BK 16
__global__ __launch_bounds__(256) void k_gemm(
    const float* __restrict__ A, const float* __restrict__ W, float* __restrict__ C,
    int M, int N, int K, int lda, int ldw, int ldc,
    const float* __restrict__ bias, int act)
{
  __shared__ float As[BK][BM];
  __shared__ float Ws[BK][BN];
  int bm = blockIdx.x * BM, bn = blockIdx.y * BN;
  int tid = threadIdx.x;
  int tx = tid & 15, ty = tid >> 4;
  float acc[4][4] = {{0.f}};
  for (int k0 = 0; k0 < K; k0 += BK) {
    int idx = tid * 4;
    int ra = idx >> 4;          // 0..63
    int ca = idx & 15;          // multiple of 4
    float4 av = *(const float4*)(A + (size_t)(bm + ra) * lda + k0 + ca);
    As[ca+0][ra] = av.x; As[ca+1][ra] = av.y; As[ca+2][ra] = av.z; As[ca+3][ra] = av.w;
    int rw = idx >> 6;          // 0..15
    int cw = idx & 63;          // multiple of 4
    *(float4*)&Ws[rw][cw] = *(const float4*)(W + (size_t)(k0 + rw) * ldw + bn + cw);
    __syncthreads();
    #pragma unroll
    for (int k = 0; k < BK; ++k) {
      float4 a = *(const float4*)&As[k][ty*4];
      float4 w = *(const float4*)&Ws[k][tx*4];
      float avv[4] = {a.x, a.y, a.z, a.w};
      float wvv[4] = {w.x, w.y, w.z, w.w};
      #pragma unroll
      for (int i = 0; i < 4; ++i) {
        #pragma unroll
        for (int j = 0; j < 4; ++j) acc[i][j] += avv[i] * wvv[j];
      }
    }
    __syncthreads();
  }
  #pragma unroll
  for (int i = 0; i < 4; ++i) {
    int row = bm + ty*4 + i;
    #pragma unroll
    for (int j = 0; j < 4; ++j) {
      int col = bn + tx*4 + j;
      float v = acc[i][j];
      if (bias) v += bias[col];
      if (act == 1) v = fast_tanh(v);
      C[(size_t)row * ldc + col] = v;
    }
  }
}

// ---------------- en[b,s] = sum_h tanh(CW+EWe)*wattn_s + battn_s, masked ----------------
__global__ __launch_bounds__(64) void k_en(
    const float* CW, const float* EWe, const float* wattn_s, const float* battn_s,
    const int* seq_mask, float* en)
{
  int id = blockIdx.x;       // b*S + s
  int b = id / S, s = id % S;
  int lane = threadIdx.x;
  const float* ew = EWe + (size_t)(s*B + b) * H;
  const float* cw = CW + b*H;
  float acc = 0.f;
  for (int i = 0; i < H/64; ++i) {
    int h = lane + 64*i;
    acc += fast_tanh(cw[h] + ew[h]) * wattn_s[h];
  }
  for (int o = 32; o >= 1; o >>= 1) acc += __shfl_down(acc, o, 64);
  if (lane == 0) {
    float v = acc + battn_s[0];
    en[b*S + s] = seq_mask[b*S + s] ? NEG : v;
  }
}

// ---------------- softmax over S per b (in place) ----------------
__global__ __launch_bounds__(256) void k_softmax_attn(float* en)
{
  int b = blockIdx.x, s = threadIdx.x;
  __shared__ float red[256];
  float x = en[b*S + s];
  red[s] = x; __syncthreads();
  for (int o = 128; o > 0; o >>= 1) { if (s < o) red[s] = fmaxf(red[s], red[s+o]); __syncthreads(); }
  float m = red[0]; __syncthreads();
  float e = __expf(x - m);
  red[s] = e; __syncthreads();
  for (int o = 128; o > 0; o >>= 1) { if (s < o) red[s] += red[s+o]; __syncthreads(); }
  float sum = red[0];
  en[b*S + s] = e / sum;
}

// ---------------- current_context + leaf assembly ----------------
__global__ __launch_bounds__(512) void k_ctx(
    const float* attn, const float* enc, const float* cur_node,
    float* out_ctx, float* leaf)
{
  int b = blockIdx.x, h = threadIdx.x;
  __shared__ float sa[S];
  if (h < S) sa[h] = attn[b*S + h];
  __syncthreads();
  float acc = 0.f;
  for (int s = 0; s < S; ++s)
    acc += sa[s] * enc[((size_t)s*B + b)*H + h];
  out_ctx[b*H + h] = acc;
  leaf[b*2*H + H + h] = acc;
  leaf[b*2*H + h] = cur_node[b*H + h];
}

// ---------------- fen[b,r,s] ----------------
__global__ __launch_bounds__(64) void k_fen(
    const float* FW, const float* EWfe, const float* wfattn_s, const float* bfattn_s,
    const int* seq_mask, float* fen)
{
  int id = blockIdx.x;         // (b*R + r)*S + s
  int s = id % S; int br = id / S;
  int r = br % R; int b = br / R;
  int lane = threadIdx.x;
  const float* ew = EWfe + (size_t)(s*B + b) * H;
  const float* fw = FW + r*H;
  float acc = 0.f;
  for (int i = 0; i < H/64; ++i) {
    int h = lane + 64*i;
    acc += fast_tanh(fw[h] + ew[h]) * wfattn_s[h];
  }
  for (int o = 32; o >= 1; o >>= 1) acc += __shfl_down(acc, o, 64);
  if (lane == 0) {
    float v = acc + bfattn_s[0];
    fen[id] = seq_mask[b*S + s] ? NEG : v;
  }
}

// ---------------- softmax over S per (b,r) + add 0.2*attn -> coef (in place) ----------------
__global__ __launch_bounds__(256) void k_softmax_f(float* fen, const float* attn)
{
  int br = blockIdx.x;   // b*R + r
  int b = br / R;
  int s = threadIdx.x;
  __shared__ float red[256];
  float x = fen[br*S + s];
  red[s] = x; __syncthreads();
  for (int o = 128; o > 0; o >>= 1) { if (s < o) red[s] = fmaxf(red[s], red[s+o]); __syncthreads(); }
  float m = red[0]; __syncthreads();
  float e = __expf(x - m);
  red[s] = e; __syncthreads();
  for (int o = 128; o > 0; o >>= 1) { if (s < o) red[s] += red[s+o]; __syncthreads(); }
  float sum = red[0];
  fen[br*S + s] = e / sum + 0.2f * attn[b*S + s];
}

// ---------------- formulas_context ----------------
__global__ __launch_bounds__(512) void k_fctx(
    const float* coef, const float* enc, float* fctx)
{
  int br = blockIdx.x; int b = br / R;
  int h = threadIdx.x;
  __shared__ float sa[S];
  if (h < S) sa[h] = coef[br*S + h];
  __syncthreads();
  float acc = 0.f;
  for (int s = 0; s < S; ++s)
    acc += sa[s] * enc[((size_t)s*B + b)*H + h];
  fctx[(size_t)br*H + h] = acc;
}

// ---------------- formula_feat + logit ----------------
__global__ __launch_bounds__(512) void k_ff(
    const float* fctx, const float* Wfp1, const float* bfp1,
    const float* Wfp2, const float* bfp2, float* logit)
{
  int br = blockIdx.x; int h = threadIdx.x;
  __shared__ float row[H];
  __shared__ float red[512];
  row[h] = fctx[(size_t)br*H + h];
  __syncthreads();
  float acc = 0.f;
  for (int k = 0; k < H; ++k) acc += row[k] * Wfp1[k*H + h];
  float ffv = fast_tanh(acc + bfp1[h]);
  red[h] = ffv * Wfp2[h];
  __syncthreads();
  for (int o = 256; o > 0; o >>= 1) { if (h < o) red[h] += red[h+o]; __syncthreads(); }
  if (h == 0) logit[br] = red[0] + bfp2[0];
}

// ---------------- formula_prob: softmax over R per b ----------------
__global__ __launch_bounds__(64) void k_fprob(const float* logit, float* out_fp)
{
  int b = blockIdx.x; int lane = threadIdx.x;
  float x = (lane < R) ? logit[b*R + lane] : NEG;
  float m = x;
  for (int o = 8; o >= 1; o >>= 1) m = fmaxf(m, __shfl_xor(m, o, 16));
  float e = (lane < R) ? __expf(x - m) : 0.f;
  float sum = e;
  for (int o = 8; o >= 1; o >>= 1) sum += __shfl_xor(sum, o, 16);
  if (lane < R) out_fp[b*R + lane] = e / sum;
}

// ---------------- emb_w output copy ----------------
__global__ __launch_bounds__(256) void k_embw(
    const float* emb_w, const float* num_pades, float* out_embw)
{
  int idx = blockIdx.x*256 + threadIdx.x;   // < B*NTOT*H
  int h = idx % H; int bn = idx / H;
  int n = bn % NTOT; int b = bn / NTOT;
  float v = (n < IN_N) ? emb_w[n*H + h]
                       : num_pades[((size_t)b*NN + (n - IN_N))*H + h];
  out_embw[idx] = v;
}

// ---------------- ein materialization ----------------
__global__ __launch_bounds__(512) void k_ein(
    const float* leaf, const float* emb_w, const float* num_pades, float* ein)
{
  int row = blockIdx.x;  // b*20+n
  int n = row % NTOT, b = row / NTOT;
  for (int idx = threadIdx.x; idx < 3*H; idx += 512) {
    float v;
    if (idx < 2*H) v = leaf[b*2*H + idx];
    else {
      int h = idx - 2*H;
      v = (n < IN_N) ? emb_w[n*H + h] : num_pades[((size_t)b*NN + (n - IN_N))*H + h];
    }
    ein[(size_t)row*3*H + idx] = v;
  }
}

// ---------------- num_score reduce ----------------
__global__ __launch_bounds__(64) void k_ns(
    const float* T, const float* wscore_s, const int* mask_nums, float* out_ns)
{
  int row = blockIdx.x; int lane = threadIdx.x;
  float acc = 0.f;
  for (int i = 0; i < H/64; ++i) {
    int h = lane + 64*i;
    acc += T[(size_t)row*H + h] * wscore_s[h];
  }
  for (int o = 32; o >= 1; o >>= 1) acc += __shfl_down(acc, o, 64);
  if (lane == 0) out_ns[row] = mask_nums[row] ? NEG : acc;
}

// ---------------- op ----------------
__global__ __launch_bounds__(64) void k_op(
    const float* leaf, const float* Wops, const float* bops, float* out_op)
{
  int id = blockIdx.x; int o = id % OPN, b = id / OPN;
  int lane = threadIdx.x;
  float acc = 0.f;
  for (int i = 0; i < 2*H/64; ++i) {
    int k = lane + 64*i;
    acc += leaf[b*2*H + k] * Wops[k*OPN + o];
  }
  for (int off = 32; off >= 1; off >>= 1) acc += __shfl_down(acc, off, 64);
  if (lane == 0) out_op[b*OPN + o] = acc + bops[o];
}

extern "C" void kernel_launch(void* const* d_in, const int* in_sizes, int n_in,
                              void* d_out, int out_size, void* d_ws, size_t ws_size,
                              hipStream_t stream)
{
  const float* node_emb = (const float*)d_in[0];
  const float* left     = (const float*)d_in[1];
  const float* enc      = (const float*)d_in[2];
  const float* num_pades= (const float*)d_in[3];
  const float* fs       = (const float*)d_in[4];
  const int*   has_left = (const int*)d_in[5];
  const int*   seq_mask = (const int*)d_in[6];
  const int*   mask_nums= (const int*)d_in[7];
  const float* emb_w    = (const float*)d_in[8];
  const float* Wcl  = (const float*)d_in[9];
  const float* bcl  = (const float*)d_in[10];
  const float* Wclg = (const float*)d_in[11];
  const float* bclg = (const float*)d_in[12];
  const float* Wcr  = (const float*)d_in[13];
  const float* bcr  = (const float*)d_in[14];
  const float* Wcrg = (const float*)d_in[15];
  const float* bcrg = (const float*)d_in[16];
  const float* Wops = (const float*)d_in[17];
  const float* bops = (const float*)d_in[18];
  const float* Wattn  = (const float*)d_in[19];
  const float* battn  = (const float*)d_in[20];
  const float* wattn_s= (const float*)d_in[21];
  const float* battn_s= (const float*)d_in[22];
  const float* Wfattn = (const float*)d_in[23];
  const float* bfattn = (const float*)d_in[24];
  const float* wfattn_s = (const float*)d_in[25];
  const float* bfattn_s = (const float*)d_in[26];
  const float* Wscore   = (const float*)d_in[27];
  const float* bscore   = (const float*)d_in[28];
  const float* wscore_s = (const float*)d_in[29];
  const float* Wfp1 = (const float*)d_in[30];
  const float* bfp1 = (const float*)d_in[31];
  const float* Wfp2 = (const float*)d_in[32];
  const float* bfp2 = (const float*)d_in[33];

  float* out = (float*)d_out;
  float* out_ns   = out + 0;        // (B,20)
  float* out_op   = out + 640;      // (B,6)
  float* out_cn   = out + 832;      // (B,1,H)
  float* out_ctx  = out + 17216;    // (B,1,H)
  float* out_embw = out + 33600;    // (B,20,H)
  float* out_fp   = out + 361280;   // (B,R)

  // workspace layout (floats); needs ~34.4 MB total
  float* ws = (float*)d_ws;
  float* cur_node = ws + 0;         // 16384
  float* CW   = ws + 16384;         // 16384
  float* FW   = ws + 32768;         // 8192
  float* en   = ws + 40960;         // 8192  (en -> attn in place)
  float* fen  = ws + 49152;         // 131072 (fen -> coef in place)
  float* leaf = ws + 180224;        // 32768
  float* EWe  = ws + 212992;        // 4194304
  float* EWfe = ws + 4407296;       // 4194304
  float* ein  = EWe;                // alias (EWe dead after k_en)
  float* T    = EWe + 983040;       // alias
  float* fctx = EWfe;               // alias (EWfe dead after k_fen)
  float* logit= EWfe + 262144;      // alias

  k_gates<<<B, 512, 0, stream>>>(node_emb, left, has_left, Wcl, bcl, Wclg, bclg,
                                 Wcr, bcr, Wcrg, bcrg, cur_node, out_cn);
  k_cwfw<<<B + R, 512, 0, stream>>>(cur_node, fs, Wattn, battn, Wfattn, bfattn, CW, FW);

  dim3 g1(S*B/BM, H/BN);
  k_gemm<<<g1, 256, 0, stream>>>(enc, Wattn + H*H, EWe, S*B, H, H, H, H, H, nullptr, 0);
  k_gemm<<<g1, 256, 0, stream>>>(enc, Wfattn,      EWfe, S*B, H, H, H, H, H, nullptr, 0);

  k_en<<<B*S, 64, 0, stream>>>(CW, EWe, wattn_s, battn_s, seq_mask, en);
  k_softmax_attn<<<B, 256, 0, stream>>>(en);
  k_ctx<<<B, 512, 0, stream>>>(en, enc, cur_node, out_ctx, leaf);

  k_fen<<<B*R*S, 64, 0, stream>>>(FW, EWfe, wfattn_s, bfattn_s, seq_mask, fen);
  k_softmax_f<<<B*R, 256, 0, stream>>>(fen, en);
  k_fctx<<<B*R, 512, 0, stream>>>(fen, enc, fctx);
  k_ff<<<B*R, 512, 0, stream>>>(fctx, Wfp1, bfp1, Wfp2, bfp2, logit);
  k_fprob<<<B, 64, 0, stream>>>(logit, out_fp);

  k_embw<<<(B*NTOT*H)/256, 256, 0, stream>>>(emb_w, num_pades, out_embw);
  k_ein<<<B*NTOT, 512, 0, stream>>>(leaf, emb_w, num_pades, ein);
  dim3 g2(B*NTOT/BM, H/BN);
  k_gemm<<<g2, 256, 0, stream>>>(ein, Wscore, T, B*NTOT, H, 3*H, 3*H, H, H, bscore, 1);
  k_ns<<<B*NTOT, 64, 0, stream>>>(T, wscore_s, mask_nums, out_ns);
  k_op<<<B*OPN, 64, 0, stream>>>(leaf, Wops, bops, out_op);
}

// Round 2
// 200.388 us; speedup vs baseline: 2.0443x; 2.0443x over previous
//
#include <hip/hip_runtime.h>
#include <hip/hip_bf16.h>
#include <stdint.h>

#define H 512
#define S 256
#define B 32
#define R 16
#define IN_N 4
#define NN 16
#define NTOT 20
#define OPN 6
#define NEG -1000000000000.0f

typedef unsigned short u16;
typedef short short8 __attribute__((ext_vector_type(8)));
typedef float f32x4 __attribute__((ext_vector_type(4)));

__device__ __forceinline__ float bf2f(u16 u) {
  unsigned int v = ((unsigned int)u) << 16;
  float f; __builtin_memcpy(&f, &v, 4); return f;
}
__device__ __forceinline__ u16 f2u(float x) {
  __hip_bfloat16 h = __float2bfloat16(x);
  u16 u; __builtin_memcpy(&u, &h, 2); return u;
}
__device__ __forceinline__ float ftanh(float x) {
  float e = __expf(2.f * x);
  return 1.f - 2.f * __builtin_amdgcn_rcpf(e + 1.f);
}
__device__ __forceinline__ float fsig(float x) {
  return __builtin_amdgcn_rcpf(1.f + __expf(-x));
}
__device__ __forceinline__ void gload16(const void* g, void* l) {
  __builtin_amdgcn_global_load_lds(
      (const __attribute__((address_space(1))) unsigned int*)g,
      (__attribute__((address_space(3))) unsigned int*)l, 16, 0, 0);
}

// ---------- enc f32 -> bf16 ----------
__global__ __launch_bounds__(256) void k_conv(const float* __restrict__ src,
                                              u16* __restrict__ dst) {
  int i = (blockIdx.x * 256 + threadIdx.x) * 8;
  float4 a = *(const float4*)(src + i);
  float4 b = *(const float4*)(src + i + 4);
  short8 o;
  o[0] = (short)f2u(a.x); o[1] = (short)f2u(a.y); o[2] = (short)f2u(a.z); o[3] = (short)f2u(a.w);
  o[4] = (short)f2u(b.x); o[5] = (short)f2u(b.y); o[6] = (short)f2u(b.z); o[7] = (short)f2u(b.w);
  *(short8*)(dst + i) = o;
}

// ---------- transpose+convert: dst[n*Krows + k] = bf16(src[k*512 + n']) ----------
__global__ __launch_bounds__(256) void k_trans(const float* __restrict__ srcA,
                                               const float* __restrict__ srcB,
                                               int nsplit, u16* __restrict__ dst,
                                               int Krows) {
  __shared__ float tile[64][65];
  int n0 = blockIdx.x * 64, k0 = blockIdx.y * 64;
  const float* src; int nb;
  if (n0 < nsplit) { src = srcA; nb = n0; } else { src = srcB; nb = n0 - nsplit; }
  int t = threadIdx.x;
  #pragma unroll
  for (int it = 0; it < 16; ++it) {
    int f = it * 256 + t; int r = f >> 6, c = f & 63;
    tile[r][c] = src[(size_t)(k0 + r) * 512 + nb + c];
  }
  __syncthreads();
  #pragma unroll
  for (int it = 0; it < 16; ++it) {
    int f = it * 256 + t; int r = f >> 6, c = f & 63;
    dst[(size_t)(n0 + r) * Krows + k0 + c] = f2u(tile[c][r]);
  }
}

// ---------- MFMA GEMM: C[M,N] = A[M,K] @ Bt[N,K]^T, bf16 in, f32 acc ----------
template <int FM, int FN, bool OUT16>
__global__ __launch_bounds__(256) void k_mfma(const u16* __restrict__ A,
                                              const u16* __restrict__ Bt,
                                              u16* __restrict__ C16,
                                              float* __restrict__ C32,
                                              int lda, int ldb, int ldc,
                                              int ksteps, long zstrideC) {
  constexpr int BM = FM * 32, BN = FN * 32;
  __shared__ u16 As[BM * 32];
  __shared__ u16 Bs[BN * 32];
  const int tid = threadIdx.x;
  const int lane = tid & 63;
  const int wid = tid >> 6;
  const int bm = blockIdx.x * BM, bn = blockIdx.y * BN;
  const int kbase = blockIdx.z * ksteps * 32;
  const int wr = (wid >> 1) * (FM * 16);
  const int wc = (wid & 1) * (FN * 16);
  f32x4 acc[FM][FN];
  #pragma unroll
  for (int m = 0; m < FM; ++m)
    #pragma unroll
    for (int n = 0; n < FN; ++n)
      #pragma unroll
      for (int q = 0; q < 4; ++q) acc[m][n][q] = 0.f;

  const int kb = (lane >> 4) * 8;
  const int rr = lane & 15;
  for (int ks = 0; ks < ksteps; ++ks) {
    int k0 = kbase + ks * 32;
    #pragma unroll
    for (int it = 0; it < BM / 64; ++it) {
      int c = it * 256 + tid;
      gload16(A + (size_t)(bm + (c >> 2)) * lda + k0 + (c & 3) * 8, As + c * 8);
    }
    #pragma unroll
    for (int it = 0; it < BN / 64; ++it) {
      int c = it * 256 + tid;
      gload16(Bt + (size_t)(bn + (c >> 2)) * ldb + k0 + (c & 3) * 8, Bs + c * 8);
    }
    __syncthreads();
    short8 af[FM], bf[FN];
    #pragma unroll
    for (int m = 0; m < FM; ++m)
      af[m] = *(const short8*)(As + (wr + m * 16 + rr) * 32 + kb);
    #pragma unroll
    for (int n = 0; n < FN; ++n)
      bf[n] = *(const short8*)(Bs + (wc + n * 16 + rr) * 32 + kb);
    #pragma unroll
    for (int m = 0; m < FM; ++m)
      #pragma unroll
      for (int n = 0; n < FN; ++n)
        acc[m][n] = __builtin_amdgcn_mfma_f32_16x16x32_bf16(af[m], bf[n], acc[m][n], 0, 0, 0);
    __syncthreads();
  }
  long zoff = (long)blockIdx.z * zstrideC;
  int r0 = (lane >> 4) * 4, cc = lane & 15;
  #pragma unroll
  for (int m = 0; m < FM; ++m)
    #pragma unroll
    for (int n = 0; n < FN; ++n)
      #pragma unroll
      for (int q = 0; q < 4; ++q) {
        long row = bm + wr + m * 16 + r0 + q;
        long col = bn + wc + n * 16 + cc;
        if (OUT16) C16[zoff + row * ldc + col] = f2u(acc[m][n][q]);
        else       C32[zoff + row * ldc + col] = acc[m][n][q];
      }
}

// ---------- gates partial ----------
__global__ __launch_bounds__(256) void k_gates_p(
    const float* __restrict__ node_emb, const float* __restrict__ left,
    const int* __restrict__ has_left,
    const float* __restrict__ Wcl, const float* __restrict__ Wclg,
    const float* __restrict__ Wcr, const float* __restrict__ Wcrg,
    float* __restrict__ gp1, float* __restrict__ gp2) {
  int b = blockIdx.x, kc = blockIdx.y, t = threadIdx.x;
  int hl = has_left[b];
  int k0 = kc * 128;
  float* o1 = gp1 + ((size_t)b * 8 + kc) * 512;
  float* o2 = gp2 + ((size_t)b * 8 + kc) * 512;
  if (!hl && kc >= 4) { o1[t] = 0.f; o1[t + 256] = 0.f; o2[t] = 0.f; o2[t + 256] = 0.f; return; }
  __shared__ float x[128];
  if (t < 128) {
    int k = k0 + t;
    x[t] = hl ? (k < 512 ? left[b * 512 + k] : node_emb[b * 512 + k - 512])
              : node_emb[b * 512 + k];
  }
  __syncthreads();
  const float* W1 = hl ? Wcr : Wcl;
  const float* W2 = hl ? Wcrg : Wclg;
  float a1 = 0.f, a2 = 0.f, a3 = 0.f, a4 = 0.f;
  for (int kk = 0; kk < 128; ++kk) {
    float xv = x[kk];
    const float* w1r = W1 + (size_t)(k0 + kk) * 512;
    const float* w2r = W2 + (size_t)(k0 + kk) * 512;
    a1 += xv * w1r[t]; a2 += xv * w1r[t + 256];
    a3 += xv * w2r[t]; a4 += xv * w2r[t + 256];
  }
  o1[t] = a1; o1[t + 256] = a2; o2[t] = a3; o2[t + 256] = a4;
}

__global__ __launch_bounds__(512) void k_gates_c(
    const float* __restrict__ gp1, const float* __restrict__ gp2,
    const int* __restrict__ has_left,
    const float* __restrict__ bcl, const float* __restrict__ bclg,
    const float* __restrict__ bcr, const float* __restrict__ bcrg,
    float* __restrict__ cur_node, float* __restrict__ out_cn) {
  int b = blockIdx.x, h = threadIdx.x;
  float s1 = 0.f, s2 = 0.f;
  for (int kc = 0; kc < 8; ++kc) {
    s1 += gp1[((size_t)b * 8 + kc) * 512 + h];
    s2 += gp2[((size_t)b * 8 + kc) * 512 + h];
  }
  int hl = has_left[b];
  float v = ftanh(s1 + (hl ? bcr[h] : bcl[h])) * fsig(s2 + (hl ? bcrg[h] : bclg[h]));
  cur_node[b * 512 + h] = v;
  out_cn[b * 512 + h] = v;
}

// ---------- CW/FW partial ----------
__global__ __launch_bounds__(256) void k_cwfw_p(
    const float* __restrict__ cur_node, const float* __restrict__ fs,
    const float* __restrict__ Wattn, const float* __restrict__ Wfattn,
    float* __restrict__ cwp) {
  int row = blockIdx.x, kc = blockIdx.y, t = threadIdx.x;
  int k0 = kc * 128;
  __shared__ float x[128];
  if (t < 128)
    x[t] = (row < 32) ? cur_node[row * 512 + k0 + t] : fs[(row - 32) * 512 + k0 + t];
  __syncthreads();
  const float* W = (row < 32) ? (Wattn + (size_t)k0 * 512)
                              : (Wfattn + (size_t)(512 + k0) * 512);
  float a1 = 0.f, a2 = 0.f;
  for (int kk = 0; kk < 128; ++kk) {
    const float* wr_ = W + (size_t)kk * 512;
    float xv = x[kk];
    a1 += xv * wr_[t]; a2 += xv * wr_[t + 256];
  }
  float* o = cwp + ((size_t)row * 4 + kc) * 512;
  o[t] = a1; o[t + 256] = a2;
}

__global__ __launch_bounds__(512) void k_cwfw_c(
    const float* __restrict__ cwp, const float* __restrict__ battn,
    const float* __restrict__ bfattn, float* __restrict__ CW, float* __restrict__ FW) {
  int row = blockIdx.x, h = threadIdx.x;
  float s = 0.f;
  for (int kc = 0; kc < 4; ++kc) s += cwp[((size_t)row * 4 + kc) * 512 + h];
  if (row < 32) CW[row * 512 + h] = s + battn[h];
  else          FW[(row - 32) * 512 + h] = s + bfattn[h];
}

// ---------- en + fen fused ----------
__global__ __launch_bounds__(256) void k_enfen(
    const u16* __restrict__ EW, const float* __restrict__ CW,
    const float* __restrict__ FW,
    const float* __restrict__ wattn_s, const float* __restrict__ battn_s,
    const float* __restrict__ wfattn_s, const float* __restrict__ bfattn_s,
    const int* __restrict__ seq_mask, float* __restrict__ en, float* __restrict__ fen) {
  __shared__ float sFW[16 * 512];
  __shared__ float swf[512], swa[512], scw[512];
  int bid = blockIdx.x;
  int b = bid >> 6;
  int s0 = (bid & 63) * 4;
  int t = threadIdx.x;
  #pragma unroll
  for (int q = 0; q < 32; ++q) sFW[q * 256 + t] = FW[q * 256 + t];
  swf[t] = wfattn_s[t]; swf[256 + t] = wfattn_s[256 + t];
  swa[t] = wattn_s[t];  swa[256 + t] = wattn_s[256 + t];
  scw[t] = CW[b * 512 + t]; scw[256 + t] = CW[b * 512 + 256 + t];
  __syncthreads();
  int w = t >> 6, lane = t & 63;
  int s = s0 + w;
  const u16* ew = EW + (size_t)(s * 32 + b) * 1024;
  float ewf[8], wfv[8];
  float accE = 0.f;
  #pragma unroll
  for (int i = 0; i < 8; ++i) {
    int h = lane + 64 * i;
    accE += ftanh(scw[h] + bf2f(ew[h])) * swa[h];
    ewf[i] = bf2f(ew[512 + h]);
    wfv[i] = swf[h];
  }
  for (int o = 32; o >= 1; o >>= 1) accE += __shfl_down(accE, o);
  int msk = seq_mask[b * 256 + s];
  if (lane == 0) en[b * 256 + s] = msk ? NEG : (accE + battn_s[0]);
  for (int r = 0; r < 16; ++r) {
    float a = 0.f;
    #pragma unroll
    for (int i = 0; i < 8; ++i) {
      int h = lane + 64 * i;
      a += ftanh(sFW[r * 512 + h] + ewf[i]) * wfv[i];
    }
    for (int o = 32; o >= 1; o >>= 1) a += __shfl_down(a, o);
    if (lane == 0) fen[((size_t)b * 16 + r) * 256 + s] = msk ? NEG : (a + bfattn_s[0]);
  }
}

// ---------- softmaxes + contexts fused ----------
__global__ __launch_bounds__(512) void k_ctxall(
    const float* __restrict__ en, const float* __restrict__ fen,
    const u16* __restrict__ encb, const float* __restrict__ cur_node,
    float* __restrict__ out_ctx, float* __restrict__ leaf, float* __restrict__ fctx) {
  int br = blockIdx.x;
  int b = br / 17, j = br % 17;
  int t = threadIdx.x;
  __shared__ float red[512];
  __shared__ float sa[256];
  float xe = (t < 256) ? en[b * 256 + t] : NEG;
  red[t] = xe; __syncthreads();
  for (int o = 256; o > 0; o >>= 1) { if (t < o) red[t] = fmaxf(red[t], red[t + o]); __syncthreads(); }
  float m = red[0]; __syncthreads();
  float ee = (t < 256) ? __expf(xe - m) : 0.f;
  red[t] = ee; __syncthreads();
  for (int o = 256; o > 0; o >>= 1) { if (t < o) red[t] += red[t + o]; __syncthreads(); }
  float attn_v = ee / red[0];
  __syncthreads();
  float coef = attn_v;
  if (j < 16) {
    float xf = (t < 256) ? fen[((size_t)b * 16 + j) * 256 + t] : NEG;
    red[t] = xf; __syncthreads();
    for (int o = 256; o > 0; o >>= 1) { if (t < o) red[t] = fmaxf(red[t], red[t + o]); __syncthreads(); }
    float mf = red[0]; __syncthreads();
    float ef = (t < 256) ? __expf(xf - mf) : 0.f;
    red[t] = ef; __syncthreads();
    for (int o = 256; o > 0; o >>= 1) { if (t < o) red[t] += red[t + o]; __syncthreads(); }
    coef = ef / red[0] + 0.2f * attn_v;
    __syncthreads();
  }
  if (t < 256) sa[t] = coef;
  __syncthreads();
  int h = t;
  float acc = 0.f;
  for (int s = 0; s < 256; ++s)
    acc += sa[s] * bf2f(encb[((size_t)s * 32 + b) * 512 + h]);
  if (j < 16) {
    fctx[((size_t)b * 16 + j) * 512 + h] = acc;
  } else {
    out_ctx[b * 512 + h] = acc;
    leaf[b * 1024 + 512 + h] = acc;
    leaf[b * 1024 + h] = cur_node[b * 512 + h];
  }
}

// ---------- emb_w output copy + bf16 A2 ----------
__global__ __launch_bounds__(256) void k_embw(
    const float* __restrict__ emb_w, const float* __restrict__ num_pades,
    float* __restrict__ out_embw, u16* __restrict__ A2) {
  int idx = blockIdx.x * 256 + threadIdx.x;
  int h = idx & 511; int bn = idx >> 9;
  int n = bn % 20; int b = bn / 20;
  float v = (n < 4) ? emb_w[n * 512 + h] : num_pades[((size_t)b * 16 + n - 4) * 512 + h];
  out_embw[idx] = v;
  A2[idx] = f2u(v);
}

// ---------- T1 partial: leaf @ Wscore[:1024] ----------
__global__ __launch_bounds__(256) void k_T1p(const float* __restrict__ leaf,
                                             const float* __restrict__ Wscore,
                                             float* __restrict__ T1p) {
  int b = blockIdx.x, kc = blockIdx.y, t = threadIdx.x;
  int k0 = kc * 256;
  __shared__ float x[256];
  x[t] = leaf[b * 1024 + k0 + t];
  __syncthreads();
  float a1 = 0.f, a2 = 0.f;
  for (int kk = 0; kk < 256; ++kk) {
    const float* wr_ = Wscore + (size_t)(k0 + kk) * 512;
    float xv = x[kk];
    a1 += xv * wr_[t]; a2 += xv * wr_[t + 256];
  }
  float* o = T1p + ((size_t)b * 4 + kc) * 512;
  o[t] = a1; o[t + 256] = a2;
}

// ---------- num_score ----------
__global__ __launch_bounds__(64) void k_ns(
    const float* __restrict__ T1p, const float* __restrict__ T2p,
    const float* __restrict__ bscore, const float* __restrict__ wscore_s,
    const int* __restrict__ mask_nums, float* __restrict__ out_ns) {
  int row = blockIdx.x; int b = row / 20; int lane = threadIdx.x;
  float acc = 0.f;
  #pragma unroll
  for (int i = 0; i < 8; ++i) {
    int h = lane + 64 * i;
    float t1 = T1p[((size_t)b * 4 + 0) * 512 + h] + T1p[((size_t)b * 4 + 1) * 512 + h] +
               T1p[((size_t)b * 4 + 2) * 512 + h] + T1p[((size_t)b * 4 + 3) * 512 + h];
    float t2 = T2p[(size_t)row * 512 + h] + T2p[327680 + (size_t)row * 512 + h] +
               T2p[2L * 327680 + (size_t)row * 512 + h] + T2p[3L * 327680 + (size_t)row * 512 + h];
    acc += ftanh(t1 + t2 + bscore[h]) * wscore_s[h];
  }
  for (int o = 32; o >= 1; o >>= 1) acc += __shfl_down(acc, o);
  if (lane == 0) out_ns[row] = mask_nums[row] ? NEG : acc;
}

// ---------- formula feat + logit ----------
__global__ __launch_bounds__(512) void k_ff(
    const float* __restrict__ fctx, const float* __restrict__ Wfp1,
    const float* __restrict__ bfp1, const float* __restrict__ Wfp2,
    const float* __restrict__ bfp2, float* __restrict__ logit) {
  int r0 = blockIdx.x * 8;
  int t = threadIdx.x;
  __shared__ float tile[8 * 512];
  __shared__ float partw[64];
  #pragma unroll
  for (int q = 0; q < 8; ++q) tile[q * 512 + t] = fctx[(size_t)(r0 + q) * 512 + t];
  __syncthreads();
  float acc[8];
  #pragma unroll
  for (int q = 0; q < 8; ++q) acc[q] = 0.f;
  for (int k = 0; k < 512; k += 4) {
    float wv0 = Wfp1[(size_t)k * 512 + t];
    float wv1 = Wfp1[(size_t)(k + 1) * 512 + t];
    float wv2 = Wfp1[(size_t)(k + 2) * 512 + t];
    float wv3 = Wfp1[(size_t)(k + 3) * 512 + t];
    #pragma unroll
    for (int q = 0; q < 8; ++q) {
      float4 tv = *(const float4*)&tile[q * 512 + k];
      acc[q] += tv.x * wv0 + tv.y * wv1 + tv.z * wv2 + tv.w * wv3;
    }
  }
  float w2 = Wfp2[t];
  float bf1 = bfp1[t];
  int lane = t & 63, w = t >> 6;
  #pragma unroll
  for (int q = 0; q < 8; ++q) {
    float pv = ftanh(acc[q] + bf1) * w2;
    for (int o = 32; o >= 1; o >>= 1) pv += __shfl_down(pv, o);
    if (lane == 0) partw[w * 8 + q] = pv;
  }
  __syncthreads();
  if (t < 8) {
    float sres = 0.f;
    for (int ww = 0; ww < 8; ++ww) sres += partw[ww * 8 + t];
    logit[r0 + t] = sres + bfp2[0];
  }
}

// ---------- formula_prob softmax ----------
__global__ __launch_bounds__(64) void k_fprob(const float* __restrict__ logit,
                                              float* __restrict__ out_fp) {
  int b = blockIdx.x; int lane = threadIdx.x;
  float x = (lane < 16) ? logit[b * 16 + lane] : NEG;
  float m = x;
  for (int o = 8; o >= 1; o >>= 1) m = fmaxf(m, __shfl_xor(m, o, 16));
  float e = (lane < 16) ? __expf(x - m) : 0.f;
  float sum = e;
  for (int o = 8; o >= 1; o >>= 1) sum += __shfl_xor(sum, o, 16);
  if (lane < 16) out_fp[b * 16 + lane] = e / sum;
}

// ---------- op ----------
__global__ __launch_bounds__(64) void k_op(
    const float* __restrict__ leaf, const float* __restrict__ Wops,
    const float* __restrict__ bops, float* __restrict__ out_op) {
  int id = blockIdx.x; int o = id % 6, b = id / 6;
  int lane = threadIdx.x;
  float acc = 0.f;
  #pragma unroll
  for (int i = 0; i < 16; ++i) {
    int k = lane + 64 * i;
    acc += leaf[b * 1024 + k] * Wops[(size_t)k * 6 + o];
  }
  for (int off = 32; off >= 1; off >>= 1) acc += __shfl_down(acc, off);
  if (lane == 0) out_op[b * 6 + o] = acc + bops[o];
}

extern "C" void kernel_launch(void* const* d_in, const int* in_sizes, int n_in,
                              void* d_out, int out_size, void* d_ws, size_t ws_size,
                              hipStream_t stream) {
  const float* node_emb  = (const float*)d_in[0];
  const float* left      = (const float*)d_in[1];
  const float* enc       = (const float*)d_in[2];
  const float* num_pades = (const float*)d_in[3];
  const float* fs        = (const float*)d_in[4];
  const int*   has_left  = (const int*)d_in[5];
  const int*   seq_mask  = (const int*)d_in[6];
  const int*   mask_nums = (const int*)d_in[7];
  const float* emb_w     = (const float*)d_in[8];
  const float* Wcl  = (const float*)d_in[9];
  const float* bcl  = (const float*)d_in[10];
  const float* Wclg = (const float*)d_in[11];
  const float* bclg = (const float*)d_in[12];
  const float* Wcr  = (const float*)d_in[13];
  const float* bcr  = (const float*)d_in[14];
  const float* Wcrg = (const float*)d_in[15];
  const float* bcrg = (const float*)d_in[16];
  const float* Wops = (const float*)d_in[17];
  const float* bops = (const float*)d_in[18];
  const float* Wattn   = (const float*)d_in[19];
  const float* battn   = (const float*)d_in[20];
  const float* wattn_s = (const float*)d_in[21];
  const float* battn_s = (const float*)d_in[22];
  const float* Wfattn   = (const float*)d_in[23];
  const float* bfattn   = (const float*)d_in[24];
  const float* wfattn_s = (const float*)d_in[25];
  const float* bfattn_s = (const float*)d_in[26];
  const float* Wscore   = (const float*)d_in[27];
  const float* bscore   = (const float*)d_in[28];
  const float* wscore_s = (const float*)d_in[29];
  const float* Wfp1 = (const float*)d_in[30];
  const float* bfp1 = (const float*)d_in[31];
  const float* Wfp2 = (const float*)d_in[32];
  const float* bfp2 = (const float*)d_in[33];

  float* out = (float*)d_out;
  float* out_ns   = out + 0;
  float* out_op   = out + 640;
  float* out_cn   = out + 832;
  float* out_ctx  = out + 17216;
  float* out_embw = out + 33600;
  float* out_fp   = out + 361280;

  uint8_t* wsb = (uint8_t*)d_ws;
  u16*   encb = (u16*)(wsb + 0);            // 8,388,608 B  (dead after k_ctxall)
  u16*   A2   = (u16*)(wsb + 0);            // alias: 655,360 B
  float* T2p  = (float*)(wsb + 1048576);    // alias: 5,242,880 B
  u16*   Wt   = (u16*)(wsb + 8388608);      // 1,048,576 B
  u16*   Wt2  = (u16*)(wsb + 9437184);      // 524,288 B
  u16*   EW   = (u16*)(wsb + 9961472);      // 16,777,216 B
  float* fb   = (float*)(wsb + 26738688);
  float* cur_node = fb + 0;        // 16384
  float* CW   = fb + 16384;        // 16384
  float* FW   = fb + 32768;        // 8192
  float* en   = fb + 40960;        // 8192
  float* fen  = fb + 49152;        // 131072
  float* leaf = fb + 180224;       // 32768
  float* fctx = fb + 212992;       // 262144
  float* logit= fb + 475136;       // 512
  float* gp1  = fb + 475648;       // 131072
  float* gp2  = fb + 606720;       // 131072
  float* cwp  = fb + 737792;       // 98304
  float* T1p  = fb + 836096;       // 65536

  // prep: enc->bf16, packed transposed weights
  k_conv<<<2048, 256, 0, stream>>>(enc, encb);
  k_trans<<<dim3(16, 8), 256, 0, stream>>>(Wattn + 512 * 512, Wfattn, 512, Wt, 512);
  k_trans<<<dim3(8, 8), 256, 0, stream>>>(Wscore + 1024 * 512, Wscore + 1024 * 512, 4096, Wt2, 512);

  // gates + CW/FW
  k_gates_p<<<dim3(32, 8), 256, 0, stream>>>(node_emb, left, has_left, Wcl, Wclg, Wcr, Wcrg, gp1, gp2);
  k_gates_c<<<32, 512, 0, stream>>>(gp1, gp2, has_left, bcl, bclg, bcr, bcrg, cur_node, out_cn);
  k_cwfw_p<<<dim3(48, 4), 256, 0, stream>>>(cur_node, fs, Wattn, Wfattn, cwp);
  k_cwfw_c<<<48, 512, 0, stream>>>(cwp, battn, bfattn, CW, FW);

  // G1: EW[8192][1024] = enc @ [We|Wfe]
  k_mfma<4, 4, true><<<dim3(64, 8, 1), 256, 0, stream>>>(encb, Wt, EW, nullptr, 512, 512, 1024, 16, 0);

  k_enfen<<<2048, 256, 0, stream>>>(EW, CW, FW, wattn_s, battn_s, wfattn_s, bfattn_s, seq_mask, en, fen);
  k_ctxall<<<544, 512, 0, stream>>>(en, fen, encb, cur_node, out_ctx, leaf, fctx);

  // leaf-score path (factorized Wscore GEMM)
  k_embw<<<1280, 256, 0, stream>>>(emb_w, num_pades, out_embw, A2);
  k_mfma<2, 2, false><<<dim3(10, 8, 4), 256, 0, stream>>>(A2, Wt2, nullptr, T2p, 512, 512, 512, 4, 327680);
  k_T1p<<<dim3(32, 4), 256, 0, stream>>>(leaf, Wscore, T1p);
  k_ns<<<640, 64, 0, stream>>>(T1p, T2p, bscore, wscore_s, mask_nums, out_ns);

  // formula prob path
  k_ff<<<64, 512, 0, stream>>>(fctx, Wfp1, bfp1, Wfp2, bfp2, logit);
  k_fprob<<<32, 64, 0, stream>>>(logit, out_fp);

  k_op<<<192, 64, 0, stream>>>(leaf, Wops, bops, out_op);
}

// Round 3
// 154.345 us; speedup vs baseline: 2.6542x; 1.2983x over previous
//
#include <hip/hip_runtime.h>
#include <hip/hip_bf16.h>
#include <stdint.h>

#define H 512
#define S 256
#define B 32
#define R 16
#define IN_N 4
#define NN 16
#define NTOT 20
#define OPN 6
#define NEG -1000000000000.0f

typedef unsigned short u16;
typedef short short8 __attribute__((ext_vector_type(8)));
typedef float f32x4 __attribute__((ext_vector_type(4)));

__device__ __forceinline__ float bf2f(u16 u) {
  unsigned int v = ((unsigned int)u) << 16;
  float f; __builtin_memcpy(&f, &v, 4); return f;
}
__device__ __forceinline__ u16 f2u(float x) {
  __hip_bfloat16 h = __float2bfloat16(x);
  u16 u; __builtin_memcpy(&u, &h, 2); return u;
}
__device__ __forceinline__ float ftanh(float x) {
  float e = __expf(2.f * x);
  return 1.f - 2.f * __builtin_amdgcn_rcpf(e + 1.f);
}
__device__ __forceinline__ float fsig(float x) {
  return __builtin_amdgcn_rcpf(1.f + __expf(-x));
}
__device__ __forceinline__ void gload16(const void* g, void* l) {
  __builtin_amdgcn_global_load_lds(
      (const __attribute__((address_space(1))) unsigned int*)g,
      (__attribute__((address_space(3))) unsigned int*)l, 16, 0, 0);
}

// ---------- enc f32 -> bf16 ----------
__global__ __launch_bounds__(256) void k_conv(const float* __restrict__ src,
                                              u16* __restrict__ dst) {
  int i = (blockIdx.x * 256 + threadIdx.x) * 8;
  float4 a = *(const float4*)(src + i);
  float4 b = *(const float4*)(src + i + 4);
  short8 o;
  o[0] = (short)f2u(a.x); o[1] = (short)f2u(a.y); o[2] = (short)f2u(a.z); o[3] = (short)f2u(a.w);
  o[4] = (short)f2u(b.x); o[5] = (short)f2u(b.y); o[6] = (short)f2u(b.z); o[7] = (short)f2u(b.w);
  *(short8*)(dst + i) = o;
}

// ---------- transpose+convert: dst[n*Krows + k] = bf16(src[k*512 + n']) ----------
__global__ __launch_bounds__(256) void k_trans(const float* __restrict__ srcA,
                                               const float* __restrict__ srcB,
                                               int nsplit, u16* __restrict__ dst,
                                               int Krows) {
  __shared__ float tile[64][65];
  int n0 = blockIdx.x * 64, k0 = blockIdx.y * 64;
  const float* src; int nb;
  if (n0 < nsplit) { src = srcA; nb = n0; } else { src = srcB; nb = n0 - nsplit; }
  int t = threadIdx.x;
  #pragma unroll
  for (int it = 0; it < 16; ++it) {
    int f = it * 256 + t; int r = f >> 6, c = f & 63;
    tile[r][c] = src[(size_t)(k0 + r) * 512 + nb + c];
  }
  __syncthreads();
  #pragma unroll
  for (int it = 0; it < 16; ++it) {
    int f = it * 256 + t; int r = f >> 6, c = f & 63;
    dst[(size_t)(n0 + r) * Krows + k0 + c] = f2u(tile[c][r]);
  }
}

// ---------- MFMA GEMM: C[M,N] = A[M,K] @ Bt[N,K]^T, bf16 in, f32 acc ----------
template <int FM, int FN, bool OUT16>
__global__ __launch_bounds__(256) void k_mfma(const u16* __restrict__ A,
                                              const u16* __restrict__ Bt,
                                              u16* __restrict__ C16,
                                              float* __restrict__ C32,
                                              int lda, int ldb, int ldc,
                                              int ksteps, long zstrideC) {
  constexpr int BM = FM * 32, BN = FN * 32;
  __shared__ u16 As[BM * 32];
  __shared__ u16 Bs[BN * 32];
  const int tid = threadIdx.x;
  const int lane = tid & 63;
  const int wid = tid >> 6;
  const int bm = blockIdx.x * BM, bn = blockIdx.y * BN;
  const int kbase = blockIdx.z * ksteps * 32;
  const int wr = (wid >> 1) * (FM * 16);
  const int wc = (wid & 1) * (FN * 16);
  f32x4 acc[FM][FN];
  #pragma unroll
  for (int m = 0; m < FM; ++m)
    #pragma unroll
    for (int n = 0; n < FN; ++n)
      #pragma unroll
      for (int q = 0; q < 4; ++q) acc[m][n][q] = 0.f;

  const int kb = (lane >> 4) * 8;
  const int rr = lane & 15;
  for (int ks = 0; ks < ksteps; ++ks) {
    int k0 = kbase + ks * 32;
    #pragma unroll
    for (int it = 0; it < BM / 64; ++it) {
      int c = it * 256 + tid;
      gload16(A + (size_t)(bm + (c >> 2)) * lda + k0 + (c & 3) * 8, As + c * 8);
    }
    #pragma unroll
    for (int it = 0; it < BN / 64; ++it) {
      int c = it * 256 + tid;
      gload16(Bt + (size_t)(bn + (c >> 2)) * ldb + k0 + (c & 3) * 8, Bs + c * 8);
    }
    __syncthreads();
    short8 af[FM], bf[FN];
    #pragma unroll
    for (int m = 0; m < FM; ++m)
      af[m] = *(const short8*)(As + (wr + m * 16 + rr) * 32 + kb);
    #pragma unroll
    for (int n = 0; n < FN; ++n)
      bf[n] = *(const short8*)(Bs + (wc + n * 16 + rr) * 32 + kb);
    #pragma unroll
    for (int m = 0; m < FM; ++m)
      #pragma unroll
      for (int n = 0; n < FN; ++n)
        acc[m][n] = __builtin_amdgcn_mfma_f32_16x16x32_bf16(af[m], bf[n], acc[m][n], 0, 0, 0);
    __syncthreads();
  }
  long zoff = (long)blockIdx.z * zstrideC;
  int r0 = (lane >> 4) * 4, cc = lane & 15;
  #pragma unroll
  for (int m = 0; m < FM; ++m)
    #pragma unroll
    for (int n = 0; n < FN; ++n)
      #pragma unroll
      for (int q = 0; q < 4; ++q) {
        long row = bm + wr + m * 16 + r0 + q;
        long col = bn + wc + n * 16 + cc;
        if (OUT16) C16[zoff + row * ldc + col] = f2u(acc[m][n][q]);
        else       C32[zoff + row * ldc + col] = acc[m][n][q];
      }
}

// ---------- gates partial ----------
__global__ __launch_bounds__(256) void k_gates_p(
    const float* __restrict__ node_emb, const float* __restrict__ left,
    const int* __restrict__ has_left,
    const float* __restrict__ Wcl, const float* __restrict__ Wclg,
    const float* __restrict__ Wcr, const float* __restrict__ Wcrg,
    float* __restrict__ gp1, float* __restrict__ gp2) {
  int b = blockIdx.x, kc = blockIdx.y, t = threadIdx.x;
  int hl = has_left[b];
  int k0 = kc * 128;
  float* o1 = gp1 + ((size_t)b * 8 + kc) * 512;
  float* o2 = gp2 + ((size_t)b * 8 + kc) * 512;
  if (!hl && kc >= 4) { o1[t] = 0.f; o1[t + 256] = 0.f; o2[t] = 0.f; o2[t + 256] = 0.f; return; }
  __shared__ float x[128];
  if (t < 128) {
    int k = k0 + t;
    x[t] = hl ? (k < 512 ? left[b * 512 + k] : node_emb[b * 512 + k - 512])
              : node_emb[b * 512 + k];
  }
  __syncthreads();
  const float* W1 = hl ? Wcr : Wcl;
  const float* W2 = hl ? Wcrg : Wclg;
  float a1 = 0.f, a2 = 0.f, a3 = 0.f, a4 = 0.f;
  for (int kk = 0; kk < 128; ++kk) {
    float xv = x[kk];
    const float* w1r = W1 + (size_t)(k0 + kk) * 512;
    const float* w2r = W2 + (size_t)(k0 + kk) * 512;
    a1 += xv * w1r[t]; a2 += xv * w1r[t + 256];
    a3 += xv * w2r[t]; a4 += xv * w2r[t + 256];
  }
  o1[t] = a1; o1[t + 256] = a2; o2[t] = a3; o2[t + 256] = a4;
}

__global__ __launch_bounds__(512) void k_gates_c(
    const float* __restrict__ gp1, const float* __restrict__ gp2,
    const int* __restrict__ has_left,
    const float* __restrict__ bcl, const float* __restrict__ bclg,
    const float* __restrict__ bcr, const float* __restrict__ bcrg,
    float* __restrict__ cur_node, float* __restrict__ out_cn) {
  int b = blockIdx.x, h = threadIdx.x;
  float s1 = 0.f, s2 = 0.f;
  for (int kc = 0; kc < 8; ++kc) {
    s1 += gp1[((size_t)b * 8 + kc) * 512 + h];
    s2 += gp2[((size_t)b * 8 + kc) * 512 + h];
  }
  int hl = has_left[b];
  float v = ftanh(s1 + (hl ? bcr[h] : bcl[h])) * fsig(s2 + (hl ? bcrg[h] : bclg[h]));
  cur_node[b * 512 + h] = v;
  out_cn[b * 512 + h] = v;
}

// ---------- CW/FW partial ----------
__global__ __launch_bounds__(256) void k_cwfw_p(
    const float* __restrict__ cur_node, const float* __restrict__ fs,
    const float* __restrict__ Wattn, const float* __restrict__ Wfattn,
    float* __restrict__ cwp) {
  int row = blockIdx.x, kc = blockIdx.y, t = threadIdx.x;
  int k0 = kc * 128;
  __shared__ float x[128];
  if (t < 128)
    x[t] = (row < 32) ? cur_node[row * 512 + k0 + t] : fs[(row - 32) * 512 + k0 + t];
  __syncthreads();
  const float* W = (row < 32) ? (Wattn + (size_t)k0 * 512)
                              : (Wfattn + (size_t)(512 + k0) * 512);
  float a1 = 0.f, a2 = 0.f;
  for (int kk = 0; kk < 128; ++kk) {
    const float* wr_ = W + (size_t)kk * 512;
    float xv = x[kk];
    a1 += xv * wr_[t]; a2 += xv * wr_[t + 256];
  }
  float* o = cwp + ((size_t)row * 4 + kc) * 512;
  o[t] = a1; o[t + 256] = a2;
}

__global__ __launch_bounds__(512) void k_cwfw_c(
    const float* __restrict__ cwp, const float* __restrict__ battn,
    const float* __restrict__ bfattn, float* __restrict__ CW, float* __restrict__ FW) {
  int row = blockIdx.x, h = threadIdx.x;
  float s = 0.f;
  for (int kc = 0; kc < 4; ++kc) s += cwp[((size_t)row * 4 + kc) * 512 + h];
  if (row < 32) CW[row * 512 + h] = s + battn[h];
  else          FW[(row - 32) * 512 + h] = s + bfattn[h];
}

// ---------- en + fen fused ----------
__global__ __launch_bounds__(256) void k_enfen(
    const u16* __restrict__ EW, const float* __restrict__ CW,
    const float* __restrict__ FW,
    const float* __restrict__ wattn_s, const float* __restrict__ battn_s,
    const float* __restrict__ wfattn_s, const float* __restrict__ bfattn_s,
    const int* __restrict__ seq_mask, float* __restrict__ en, float* __restrict__ fen) {
  __shared__ float sFW[16 * 512];
  __shared__ float swf[512], swa[512], scw[512];
  int bid = blockIdx.x;
  int b = bid >> 6;
  int s0 = (bid & 63) * 4;
  int t = threadIdx.x;
  #pragma unroll
  for (int q = 0; q < 32; ++q) sFW[q * 256 + t] = FW[q * 256 + t];
  swf[t] = wfattn_s[t]; swf[256 + t] = wfattn_s[256 + t];
  swa[t] = wattn_s[t];  swa[256 + t] = wattn_s[256 + t];
  scw[t] = CW[b * 512 + t]; scw[256 + t] = CW[b * 512 + 256 + t];
  __syncthreads();
  int w = t >> 6, lane = t & 63;
  int s = s0 + w;
  const u16* ew = EW + (size_t)(s * 32 + b) * 1024;
  float ewf[8], wfv[8];
  float accE = 0.f;
  #pragma unroll
  for (int i = 0; i < 8; ++i) {
    int h = lane + 64 * i;
    accE += ftanh(scw[h] + bf2f(ew[h])) * swa[h];
    ewf[i] = bf2f(ew[512 + h]);
    wfv[i] = swf[h];
  }
  for (int o = 32; o >= 1; o >>= 1) accE += __shfl_down(accE, o);
  int msk = seq_mask[b * 256 + s];
  if (lane == 0) en[b * 256 + s] = msk ? NEG : (accE + battn_s[0]);
  for (int r = 0; r < 16; ++r) {
    float a = 0.f;
    #pragma unroll
    for (int i = 0; i < 8; ++i) {
      int h = lane + 64 * i;
      a += ftanh(sFW[r * 512 + h] + ewf[i]) * wfv[i];
    }
    for (int o = 32; o >= 1; o >>= 1) a += __shfl_down(a, o);
    if (lane == 0) fen[((size_t)b * 16 + r) * 256 + s] = msk ? NEG : (a + bfattn_s[0]);
  }
}

// ---------- softmaxes + contexts fused ----------
__global__ __launch_bounds__(512) void k_ctxall(
    const float* __restrict__ en, const float* __restrict__ fen,
    const u16* __restrict__ encb, const float* __restrict__ cur_node,
    float* __restrict__ out_ctx, float* __restrict__ leaf, u16* __restrict__ fctxb) {
  int br = blockIdx.x;
  int b = br / 17, j = br % 17;
  int t = threadIdx.x;
  __shared__ float red[512];
  __shared__ float sa[256];
  float xe = (t < 256) ? en[b * 256 + t] : NEG;
  red[t] = xe; __syncthreads();
  for (int o = 256; o > 0; o >>= 1) { if (t < o) red[t] = fmaxf(red[t], red[t + o]); __syncthreads(); }
  float m = red[0]; __syncthreads();
  float ee = (t < 256) ? __expf(xe - m) : 0.f;
  red[t] = ee; __syncthreads();
  for (int o = 256; o > 0; o >>= 1) { if (t < o) red[t] += red[t + o]; __syncthreads(); }
  float attn_v = ee / red[0];
  __syncthreads();
  float coef = attn_v;
  if (j < 16) {
    float xf = (t < 256) ? fen[((size_t)b * 16 + j) * 256 + t] : NEG;
    red[t] = xf; __syncthreads();
    for (int o = 256; o > 0; o >>= 1) { if (t < o) red[t] = fmaxf(red[t], red[t + o]); __syncthreads(); }
    float mf = red[0]; __syncthreads();
    float ef = (t < 256) ? __expf(xf - mf) : 0.f;
    red[t] = ef; __syncthreads();
    for (int o = 256; o > 0; o >>= 1) { if (t < o) red[t] += red[t + o]; __syncthreads(); }
    coef = ef / red[0] + 0.2f * attn_v;
    __syncthreads();
  }
  if (t < 256) sa[t] = coef;
  __syncthreads();
  int h = t;
  float acc = 0.f;
  for (int s = 0; s < 256; ++s)
    acc += sa[s] * bf2f(encb[((size_t)s * 32 + b) * 512 + h]);
  if (j < 16) {
    fctxb[((size_t)b * 16 + j) * 512 + h] = f2u(acc);
  } else {
    out_ctx[b * 512 + h] = acc;
    leaf[b * 1024 + 512 + h] = acc;
    leaf[b * 1024 + h] = cur_node[b * 512 + h];
  }
}

// ---------- emb_w output copy + bf16 A2 ----------
__global__ __launch_bounds__(256) void k_embw(
    const float* __restrict__ emb_w, const float* __restrict__ num_pades,
    float* __restrict__ out_embw, u16* __restrict__ A2) {
  int idx = blockIdx.x * 256 + threadIdx.x;
  int h = idx & 511; int bn = idx >> 9;
  int n = bn % 20; int b = bn / 20;
  float v = (n < 4) ? emb_w[n * 512 + h] : num_pades[((size_t)b * 16 + n - 4) * 512 + h];
  out_embw[idx] = v;
  A2[idx] = f2u(v);
}

// ---------- T1 partial: leaf @ Wscore[:1024] ----------
__global__ __launch_bounds__(256) void k_T1p(const float* __restrict__ leaf,
                                             const float* __restrict__ Wscore,
                                             float* __restrict__ T1p) {
  int b = blockIdx.x, kc = blockIdx.y, t = threadIdx.x;
  int k0 = kc * 256;
  __shared__ float x[256];
  x[t] = leaf[b * 1024 + k0 + t];
  __syncthreads();
  float a1 = 0.f, a2 = 0.f;
  for (int kk = 0; kk < 256; ++kk) {
    const float* wr_ = Wscore + (size_t)(k0 + kk) * 512;
    float xv = x[kk];
    a1 += xv * wr_[t]; a2 += xv * wr_[t + 256];
  }
  float* o = T1p + ((size_t)b * 4 + kc) * 512;
  o[t] = a1; o[t + 256] = a2;
}

// ---------- num_score ----------
__global__ __launch_bounds__(64) void k_ns(
    const float* __restrict__ T1p, const float* __restrict__ T2p,
    const float* __restrict__ bscore, const float* __restrict__ wscore_s,
    const int* __restrict__ mask_nums, float* __restrict__ out_ns) {
  int row = blockIdx.x; int b = row / 20; int lane = threadIdx.x;
  float acc = 0.f;
  #pragma unroll
  for (int i = 0; i < 8; ++i) {
    int h = lane + 64 * i;
    float t1 = T1p[((size_t)b * 4 + 0) * 512 + h] + T1p[((size_t)b * 4 + 1) * 512 + h] +
               T1p[((size_t)b * 4 + 2) * 512 + h] + T1p[((size_t)b * 4 + 3) * 512 + h];
    float t2 = T2p[(size_t)row * 512 + h] + T2p[327680 + (size_t)row * 512 + h] +
               T2p[2L * 327680 + (size_t)row * 512 + h] + T2p[3L * 327680 + (size_t)row * 512 + h];
    acc += ftanh(t1 + t2 + bscore[h]) * wscore_s[h];
  }
  for (int o = 32; o >= 1; o >>= 1) acc += __shfl_down(acc, o);
  if (lane == 0) out_ns[row] = mask_nums[row] ? NEG : acc;
}

// ---------- logit: tanh(T3a+T3b+bfp1)·Wfp2 + bfp2 ----------
__global__ __launch_bounds__(64) void k_ffr(
    const float* __restrict__ T3p, const float* __restrict__ bfp1,
    const float* __restrict__ Wfp2, const float* __restrict__ bfp2,
    float* __restrict__ logit) {
  int row = blockIdx.x; int lane = threadIdx.x;
  float acc = 0.f;
  #pragma unroll
  for (int i = 0; i < 8; ++i) {
    int h = lane + 64 * i;
    float v = T3p[(size_t)row * 512 + h] + T3p[262144 + (size_t)row * 512 + h] + bfp1[h];
    acc += ftanh(v) * Wfp2[h];
  }
  for (int o = 32; o >= 1; o >>= 1) acc += __shfl_down(acc, o);
  if (lane == 0) logit[row] = acc + bfp2[0];
}

// ---------- formula_prob softmax ----------
__global__ __launch_bounds__(64) void k_fprob(const float* __restrict__ logit,
                                              float* __restrict__ out_fp) {
  int b = blockIdx.x; int lane = threadIdx.x;
  float x = (lane < 16) ? logit[b * 16 + lane] : NEG;
  float m = x;
  for (int o = 8; o >= 1; o >>= 1) m = fmaxf(m, __shfl_xor(m, o, 16));
  float e = (lane < 16) ? __expf(x - m) : 0.f;
  float sum = e;
  for (int o = 8; o >= 1; o >>= 1) sum += __shfl_xor(sum, o, 16);
  if (lane < 16) out_fp[b * 16 + lane] = e / sum;
}

// ---------- op ----------
__global__ __launch_bounds__(64) void k_op(
    const float* __restrict__ leaf, const float* __restrict__ Wops,
    const float* __restrict__ bops, float* __restrict__ out_op) {
  int id = blockIdx.x; int o = id % 6, b = id / 6;
  int lane = threadIdx.x;
  float acc = 0.f;
  #pragma unroll
  for (int i = 0; i < 16; ++i) {
    int k = lane + 64 * i;
    acc += leaf[b * 1024 + k] * Wops[(size_t)k * 6 + o];
  }
  for (int off = 32; off >= 1; off >>= 1) acc += __shfl_down(acc, off);
  if (lane == 0) out_op[b * 6 + o] = acc + bops[o];
}

extern "C" void kernel_launch(void* const* d_in, const int* in_sizes, int n_in,
                              void* d_out, int out_size, void* d_ws, size_t ws_size,
                              hipStream_t stream) {
  const float* node_emb  = (const float*)d_in[0];
  const float* left      = (const float*)d_in[1];
  const float* enc       = (const float*)d_in[2];
  const float* num_pades = (const float*)d_in[3];
  const float* fs        = (const float*)d_in[4];
  const int*   has_left  = (const int*)d_in[5];
  const int*   seq_mask  = (const int*)d_in[6];
  const int*   mask_nums = (const int*)d_in[7];
  const float* emb_w     = (const float*)d_in[8];
  const float* Wcl  = (const float*)d_in[9];
  const float* bcl  = (const float*)d_in[10];
  const float* Wclg = (const float*)d_in[11];
  const float* bclg = (const float*)d_in[12];
  const float* Wcr  = (const float*)d_in[13];
  const float* bcr  = (const float*)d_in[14];
  const float* Wcrg = (const float*)d_in[15];
  const float* bcrg = (const float*)d_in[16];
  const float* Wops = (const float*)d_in[17];
  const float* bops = (const float*)d_in[18];
  const float* Wattn   = (const float*)d_in[19];
  const float* battn   = (const float*)d_in[20];
  const float* wattn_s = (const float*)d_in[21];
  const float* battn_s = (const float*)d_in[22];
  const float* Wfattn   = (const float*)d_in[23];
  const float* bfattn   = (const float*)d_in[24];
  const float* wfattn_s = (const float*)d_in[25];
  const float* bfattn_s = (const float*)d_in[26];
  const float* Wscore   = (const float*)d_in[27];
  const float* bscore   = (const float*)d_in[28];
  const float* wscore_s = (const float*)d_in[29];
  const float* Wfp1 = (const float*)d_in[30];
  const float* bfp1 = (const float*)d_in[31];
  const float* Wfp2 = (const float*)d_in[32];
  const float* bfp2 = (const float*)d_in[33];

  float* out = (float*)d_out;
  float* out_ns   = out + 0;
  float* out_op   = out + 640;
  float* out_cn   = out + 832;
  float* out_ctx  = out + 17216;
  float* out_embw = out + 33600;
  float* out_fp   = out + 361280;

  uint8_t* wsb = (uint8_t*)d_ws;
  u16*   encb = (u16*)(wsb + 0);            // 8,388,608 B (dead after k_ctxall)
  u16*   A2   = (u16*)(wsb + 0);            // alias: 655,360 B
  float* T2p  = (float*)(wsb + 1048576);    // alias: 5,242,880 B
  float* T3p  = (float*)(wsb + 6291456);    // alias: 2,097,152 B (over encb tail)
  u16*   Wt   = (u16*)(wsb + 8388608);      // 1,048,576 B
  u16*   Wt2  = (u16*)(wsb + 9437184);      // 524,288 B
  u16*   EW   = (u16*)(wsb + 9961472);      // 16,777,216 B
  float* fb   = (float*)(wsb + 26738688);
  float* cur_node = fb + 0;        // 16384
  float* CW   = fb + 16384;        // 16384
  float* FW   = fb + 32768;        // 8192
  float* en   = fb + 40960;        // 8192
  float* fen  = fb + 49152;        // 131072
  float* leaf = fb + 180224;       // 32768
  u16*   fctxb= (u16*)(fb + 212992);  // 524,288 B (262144 u16)
  u16*   Wt3  = (u16*)(fb + 344064);  // 524,288 B
  float* logit= fb + 475136;       // 512
  float* gp1  = fb + 475648;       // 131072
  float* gp2  = fb + 606720;       // 131072
  float* cwp  = fb + 737792;       // 98304
  float* T1p  = fb + 836096;       // 65536

  // prep: enc->bf16, packed transposed weights
  k_conv<<<2048, 256, 0, stream>>>(enc, encb);
  k_trans<<<dim3(16, 8), 256, 0, stream>>>(Wattn + 512 * 512, Wfattn, 512, Wt, 512);
  k_trans<<<dim3(8, 8), 256, 0, stream>>>(Wscore + 1024 * 512, Wscore + 1024 * 512, 4096, Wt2, 512);
  k_trans<<<dim3(8, 8), 256, 0, stream>>>(Wfp1, Wfp1, 4096, Wt3, 512);

  // gates + CW/FW
  k_gates_p<<<dim3(32, 8), 256, 0, stream>>>(node_emb, left, has_left, Wcl, Wclg, Wcr, Wcrg, gp1, gp2);
  k_gates_c<<<32, 512, 0, stream>>>(gp1, gp2, has_left, bcl, bclg, bcr, bcrg, cur_node, out_cn);
  k_cwfw_p<<<dim3(48, 4), 256, 0, stream>>>(cur_node, fs, Wattn, Wfattn, cwp);
  k_cwfw_c<<<48, 512, 0, stream>>>(cwp, battn, bfattn, CW, FW);

  // G1: EW[8192][1024] = enc @ [We|Wfe]
  k_mfma<4, 4, true><<<dim3(64, 8, 1), 256, 0, stream>>>(encb, Wt, EW, nullptr, 512, 512, 1024, 16, 0);

  k_enfen<<<2048, 256, 0, stream>>>(EW, CW, FW, wattn_s, battn_s, wfattn_s, bfattn_s, seq_mask, en, fen);
  k_ctxall<<<544, 512, 0, stream>>>(en, fen, encb, cur_node, out_ctx, leaf, fctxb);

  // leaf-score path (factorized Wscore GEMM)
  k_embw<<<1280, 256, 0, stream>>>(emb_w, num_pades, out_embw, A2);
  k_mfma<2, 2, false><<<dim3(10, 8, 4), 256, 0, stream>>>(A2, Wt2, nullptr, T2p, 512, 512, 512, 4, 327680);
  k_T1p<<<dim3(32, 4), 256, 0, stream>>>(leaf, Wscore, T1p);
  k_ns<<<640, 64, 0, stream>>>(T1p, T2p, bscore, wscore_s, mask_nums, out_ns);

  // formula prob path: T3 = fctxb @ Wfp1 (split-K=2), then logit + softmax
  k_mfma<2, 2, false><<<dim3(8, 8, 2), 256, 0, stream>>>(fctxb, Wt3, nullptr, T3p, 512, 512, 512, 8, 262144);
  k_ffr<<<512, 64, 0, stream>>>(T3p, bfp1, Wfp2, bfp2, logit);
  k_fprob<<<32, 64, 0, stream>>>(logit, out_fp);

  k_op<<<192, 64, 0, stream>>>(leaf, Wops, bops, out_op);
}

// Round 4
// 126.952 us; speedup vs baseline: 3.2269x; 1.2158x over previous
//
#include <hip/hip_runtime.h>
#include <hip/hip_bf16.h>
#include <stdint.h>

#define H 512
#define S 256
#define B 32
#define R 16
#define NEG -1000000000000.0f

typedef unsigned short u16;
typedef short short8 __attribute__((ext_vector_type(8)));
typedef float f32x4 __attribute__((ext_vector_type(4)));

__device__ __forceinline__ float bf2f(u16 u) {
  unsigned int v = ((unsigned int)u) << 16;
  float f; __builtin_memcpy(&f, &v, 4); return f;
}
__device__ __forceinline__ u16 f2u(float x) {
  __hip_bfloat16 h = __float2bfloat16(x);
  u16 u; __builtin_memcpy(&u, &h, 2); return u;
}
__device__ __forceinline__ float ftanh(float x) {
  float e = __expf(2.f * x);
  return 1.f - 2.f * __builtin_amdgcn_rcpf(e + 1.f);
}
__device__ __forceinline__ float fsig(float x) {
  return __builtin_amdgcn_rcpf(1.f + __expf(-x));
}
__device__ __forceinline__ void gload16(const void* g, void* l) {
  __builtin_amdgcn_global_load_lds(
      (const __attribute__((address_space(1))) unsigned int*)g,
      (__attribute__((address_space(3))) unsigned int*)l, 16, 0, 0);
}

// ---------- trans tile helper: dst[(n0+r)*Krows + k0+c] = bf16(src[(k0+r)*512 + nb+c]) ----------
__device__ __forceinline__ void trans_tile(const float* __restrict__ src, int nb, int k0,
                                           u16* __restrict__ dst, int n0, int Krows,
                                           float (*tile)[65], int t) {
  #pragma unroll
  for (int it = 0; it < 16; ++it) {
    int f = it * 256 + t; int r = f >> 6, c = f & 63;
    tile[r][c] = src[(size_t)(k0 + r) * 512 + nb + c];
  }
  __syncthreads();
  #pragma unroll
  for (int it = 0; it < 16; ++it) {
    int f = it * 256 + t; int r = f >> 6, c = f & 63;
    dst[(size_t)(n0 + r) * Krows + k0 + c] = f2u(tile[c][r]);
  }
}

// ---------- mega prep: enc->bf16 + 3 weight transposes ----------
__global__ __launch_bounds__(256) void k_prep(
    const float* __restrict__ enc, u16* __restrict__ encb,
    const float* __restrict__ Wattn, const float* __restrict__ Wfattn, u16* __restrict__ Wt,
    const float* __restrict__ Wscore, u16* __restrict__ Wt2f,
    const float* __restrict__ Wfp1, u16* __restrict__ Wt3) {
  __shared__ float tile[64][65];
  int id = blockIdx.x, t = threadIdx.x;
  if (id < 2048) {
    int i = (id * 256 + t) * 8;
    float4 a = *(const float4*)(enc + i);
    float4 b = *(const float4*)(enc + i + 4);
    short8 o;
    o[0] = (short)f2u(a.x); o[1] = (short)f2u(a.y); o[2] = (short)f2u(a.z); o[3] = (short)f2u(a.w);
    o[4] = (short)f2u(b.x); o[5] = (short)f2u(b.y); o[6] = (short)f2u(b.z); o[7] = (short)f2u(b.w);
    *(short8*)(encb + i) = o;
  } else if (id < 2176) {            // Wt: [We | Wfe] -> [1024][512]
    int f = id - 2048; int gx = f & 15, gy = f >> 4;
    int n0 = gx * 64, k0 = gy * 64;
    const float* src = (n0 < 512) ? (Wattn + 512 * 512) : Wfattn;
    int nb = (n0 < 512) ? n0 : n0 - 512;
    trans_tile(src, nb, k0, Wt, n0, 512, tile, t);
  } else if (id < 2368) {            // Wt2f: Wscore^T [512][1536]
    int f = id - 2176; int gx = f & 7, gy = f >> 3;
    trans_tile(Wscore, gx * 64, gy * 64, Wt2f, gx * 64, 1536, tile, t);
  } else {                           // Wt3: Wfp1^T [512][512]
    int f = id - 2368; int gx = f & 7, gy = f >> 3;
    trans_tile(Wfp1, gx * 64, gy * 64, Wt3, gx * 64, 512, tile, t);
  }
}

// ---------- MFMA GEMM: C[M,N] = A[M,K] @ Bt[N,K]^T, bf16 in, f32 acc ----------
template <int FM, int FN, bool OUT16>
__global__ __launch_bounds__(256) void k_mfma(const u16* __restrict__ A,
                                              const u16* __restrict__ Bt,
                                              u16* __restrict__ C16,
                                              float* __restrict__ C32,
                                              int lda, int ldb, int ldc,
                                              int ksteps, long zstrideC) {
  constexpr int BM = FM * 32, BN = FN * 32;
  __shared__ u16 As[BM * 32];
  __shared__ u16 Bs[BN * 32];
  const int tid = threadIdx.x;
  const int lane = tid & 63;
  const int wid = tid >> 6;
  const int bm = blockIdx.x * BM, bn = blockIdx.y * BN;
  const int kbase = blockIdx.z * ksteps * 32;
  const int wr = (wid >> 1) * (FM * 16);
  const int wc = (wid & 1) * (FN * 16);
  f32x4 acc[FM][FN];
  #pragma unroll
  for (int m = 0; m < FM; ++m)
    #pragma unroll
    for (int n = 0; n < FN; ++n)
      #pragma unroll
      for (int q = 0; q < 4; ++q) acc[m][n][q] = 0.f;

  const int kb = (lane >> 4) * 8;
  const int rr = lane & 15;
  for (int ks = 0; ks < ksteps; ++ks) {
    int k0 = kbase + ks * 32;
    #pragma unroll
    for (int it = 0; it < BM / 64; ++it) {
      int c = it * 256 + tid;
      gload16(A + (size_t)(bm + (c >> 2)) * lda + k0 + (c & 3) * 8, As + c * 8);
    }
    #pragma unroll
    for (int it = 0; it < BN / 64; ++it) {
      int c = it * 256 + tid;
      gload16(Bt + (size_t)(bn + (c >> 2)) * ldb + k0 + (c & 3) * 8, Bs + c * 8);
    }
    __syncthreads();
    short8 af[FM], bf[FN];
    #pragma unroll
    for (int m = 0; m < FM; ++m)
      af[m] = *(const short8*)(As + (wr + m * 16 + rr) * 32 + kb);
    #pragma unroll
    for (int n = 0; n < FN; ++n)
      bf[n] = *(const short8*)(Bs + (wc + n * 16 + rr) * 32 + kb);
    #pragma unroll
    for (int m = 0; m < FM; ++m)
      #pragma unroll
      for (int n = 0; n < FN; ++n)
        acc[m][n] = __builtin_amdgcn_mfma_f32_16x16x32_bf16(af[m], bf[n], acc[m][n], 0, 0, 0);
    __syncthreads();
  }
  long zoff = (long)blockIdx.z * zstrideC;
  int r0 = (lane >> 4) * 4, cc = lane & 15;
  #pragma unroll
  for (int m = 0; m < FM; ++m)
    #pragma unroll
    for (int n = 0; n < FN; ++n)
      #pragma unroll
      for (int q = 0; q < 4; ++q) {
        long row = bm + wr + m * 16 + r0 + q;
        long col = bn + wc + n * 16 + cc;
        if (OUT16) C16[zoff + row * ldc + col] = f2u(acc[m][n][q]);
        else       C32[zoff + row * ldc + col] = acc[m][n][q];
      }
}

// ---------- p1: gates partials (256 blocks) + FW partials (64 blocks) ----------
__global__ __launch_bounds__(256) void k_p1(
    const float* __restrict__ node_emb, const float* __restrict__ left,
    const int* __restrict__ has_left,
    const float* __restrict__ Wcl, const float* __restrict__ Wclg,
    const float* __restrict__ Wcr, const float* __restrict__ Wcrg,
    const float* __restrict__ fs, const float* __restrict__ Wfattn,
    float* __restrict__ gp1, float* __restrict__ gp2, float* __restrict__ cwp) {
  int id = blockIdx.x, t = threadIdx.x;
  __shared__ float x[128];
  if (id < 256) {
    int b = id >> 3, kc = id & 7;
    int hl = has_left[b];
    int k0 = kc * 128;
    float* o1 = gp1 + ((size_t)b * 8 + kc) * 512;
    float* o2 = gp2 + ((size_t)b * 8 + kc) * 512;
    if (!hl && kc >= 4) { o1[t] = 0.f; o1[t + 256] = 0.f; o2[t] = 0.f; o2[t + 256] = 0.f; return; }
    if (t < 128) {
      int k = k0 + t;
      x[t] = hl ? (k < 512 ? left[b * 512 + k] : node_emb[b * 512 + k - 512])
                : node_emb[b * 512 + k];
    }
    __syncthreads();
    const float* W1 = hl ? Wcr : Wcl;
    const float* W2 = hl ? Wcrg : Wclg;
    float a1 = 0.f, a2 = 0.f, a3 = 0.f, a4 = 0.f;
    for (int kk = 0; kk < 128; ++kk) {
      float xv = x[kk];
      const float* w1r = W1 + (size_t)(k0 + kk) * 512;
      const float* w2r = W2 + (size_t)(k0 + kk) * 512;
      a1 += xv * w1r[t]; a2 += xv * w1r[t + 256];
      a3 += xv * w2r[t]; a4 += xv * w2r[t + 256];
    }
    o1[t] = a1; o1[t + 256] = a2; o2[t] = a3; o2[t + 256] = a4;
  } else {
    int f = id - 256; int row = f >> 2, kc = f & 3;   // row<16 (fs), FW = fs@Wff
    int k0 = kc * 128;
    if (t < 128) x[t] = fs[row * 512 + k0 + t];
    __syncthreads();
    const float* W = Wfattn + (size_t)(512 + k0) * 512;
    float a1 = 0.f, a2 = 0.f;
    for (int kk = 0; kk < 128; ++kk) {
      float xv = x[kk];
      a1 += xv * W[(size_t)kk * 512 + t];
      a2 += xv * W[(size_t)kk * 512 + t + 256];
    }
    float* o = cwp + ((size_t)(32 + row) * 4 + kc) * 512;
    o[t] = a1; o[t + 256] = a2;
  }
}

// ---------- p2: finish gates (cur_node slice) + CW partials ----------
__global__ __launch_bounds__(256) void k_p2(
    const float* __restrict__ gp1, const float* __restrict__ gp2,
    const int* __restrict__ has_left,
    const float* __restrict__ bcl, const float* __restrict__ bclg,
    const float* __restrict__ bcr, const float* __restrict__ bcrg,
    const float* __restrict__ Wattn,
    float* __restrict__ cur_node, float* __restrict__ out_cn, float* __restrict__ cwp) {
  int id = blockIdx.x, t = threadIdx.x;
  int row = id >> 2, kc = id & 3;
  int k0 = kc * 128;
  __shared__ float x[128];
  int hl = has_left[row];
  if (t < 128) {
    int h = k0 + t;
    float s1 = 0.f, s2 = 0.f;
    #pragma unroll
    for (int c = 0; c < 8; ++c) {
      s1 += gp1[((size_t)row * 8 + c) * 512 + h];
      s2 += gp2[((size_t)row * 8 + c) * 512 + h];
    }
    float v = ftanh(s1 + (hl ? bcr[h] : bcl[h])) * fsig(s2 + (hl ? bcrg[h] : bclg[h]));
    x[t] = v;
    cur_node[row * 512 + h] = v;
    out_cn[row * 512 + h] = v;
  }
  __syncthreads();
  const float* W = Wattn + (size_t)k0 * 512;
  float a1 = 0.f, a2 = 0.f;
  for (int kk = 0; kk < 128; ++kk) {
    float xv = x[kk];
    a1 += xv * W[(size_t)kk * 512 + t];
    a2 += xv * W[(size_t)kk * 512 + t + 256];
  }
  float* o = cwp + ((size_t)row * 4 + kc) * 512;
  o[t] = a1; o[t + 256] = a2;
}

// ---------- combine CW/FW partials ----------
__global__ __launch_bounds__(512) void k_comb(
    const float* __restrict__ cwp, const float* __restrict__ battn,
    const float* __restrict__ bfattn, float* __restrict__ CW, float* __restrict__ FW) {
  int row = blockIdx.x, h = threadIdx.x;
  float s = 0.f;
  for (int kc = 0; kc < 4; ++kc) s += cwp[((size_t)row * 4 + kc) * 512 + h];
  if (row < 32) CW[row * 512 + h] = s + battn[h];
  else          FW[(row - 32) * 512 + h] = s + bfattn[h];
}

// ---------- en + fen fused ----------
__global__ __launch_bounds__(256) void k_enfen(
    const u16* __restrict__ EW, const float* __restrict__ CW,
    const float* __restrict__ FW,
    const float* __restrict__ wattn_s, const float* __restrict__ battn_s,
    const float* __restrict__ wfattn_s, const float* __restrict__ bfattn_s,
    const int* __restrict__ seq_mask, float* __restrict__ en, float* __restrict__ fen) {
  __shared__ float sFW[16 * 512];
  __shared__ float swf[512], swa[512], scw[512];
  int bid = blockIdx.x;
  int b = bid >> 6;
  int s0 = (bid & 63) * 4;
  int t = threadIdx.x;
  #pragma unroll
  for (int q = 0; q < 32; ++q) sFW[q * 256 + t] = FW[q * 256 + t];
  swf[t] = wfattn_s[t]; swf[256 + t] = wfattn_s[256 + t];
  swa[t] = wattn_s[t];  swa[256 + t] = wattn_s[256 + t];
  scw[t] = CW[b * 512 + t]; scw[256 + t] = CW[b * 512 + 256 + t];
  __syncthreads();
  int w = t >> 6, lane = t & 63;
  int s = s0 + w;
  const u16* ew = EW + (size_t)(s * 32 + b) * 1024;
  float ewf[8], wfv[8];
  float accE = 0.f;
  #pragma unroll
  for (int i = 0; i < 8; ++i) {
    int h = lane + 64 * i;
    accE += ftanh(scw[h] + bf2f(ew[h])) * swa[h];
    ewf[i] = bf2f(ew[512 + h]);
    wfv[i] = swf[h];
  }
  for (int o = 32; o >= 1; o >>= 1) accE += __shfl_down(accE, o);
  int msk = seq_mask[b * 256 + s];
  if (lane == 0) en[b * 256 + s] = msk ? NEG : (accE + battn_s[0]);
  for (int r = 0; r < 16; ++r) {
    float a = 0.f;
    #pragma unroll
    for (int i = 0; i < 8; ++i) {
      int h = lane + 64 * i;
      a += ftanh(sFW[r * 512 + h] + ewf[i]) * wfv[i];
    }
    for (int o = 32; o >= 1; o >>= 1) a += __shfl_down(a, o);
    if (lane == 0) fen[((size_t)b * 16 + r) * 256 + s] = msk ? NEG : (a + bfattn_s[0]);
  }
}

// ---------- softmaxes + contexts fused ----------
__global__ __launch_bounds__(512) void k_ctxall(
    const float* __restrict__ en, const float* __restrict__ fen,
    const u16* __restrict__ encb, const float* __restrict__ cur_node,
    float* __restrict__ out_ctx, float* __restrict__ leaf, u16* __restrict__ fctxb) {
  int br = blockIdx.x;
  int b = br / 17, j = br % 17;
  int t = threadIdx.x;
  __shared__ float red[512];
  __shared__ float sa[256];
  float xe = (t < 256) ? en[b * 256 + t] : NEG;
  red[t] = xe; __syncthreads();
  for (int o = 256; o > 0; o >>= 1) { if (t < o) red[t] = fmaxf(red[t], red[t + o]); __syncthreads(); }
  float m = red[0]; __syncthreads();
  float ee = (t < 256) ? __expf(xe - m) : 0.f;
  red[t] = ee; __syncthreads();
  for (int o = 256; o > 0; o >>= 1) { if (t < o) red[t] += red[t + o]; __syncthreads(); }
  float attn_v = ee / red[0];
  __syncthreads();
  float coef = attn_v;
  if (j < 16) {
    float xf = (t < 256) ? fen[((size_t)b * 16 + j) * 256 + t] : NEG;
    red[t] = xf; __syncthreads();
    for (int o = 256; o > 0; o >>= 1) { if (t < o) red[t] = fmaxf(red[t], red[t + o]); __syncthreads(); }
    float mf = red[0]; __syncthreads();
    float ef = (t < 256) ? __expf(xf - mf) : 0.f;
    red[t] = ef; __syncthreads();
    for (int o = 256; o > 0; o >>= 1) { if (t < o) red[t] += red[t + o]; __syncthreads(); }
    coef = ef / red[0] + 0.2f * attn_v;
    __syncthreads();
  }
  if (t < 256) sa[t] = coef;
  __syncthreads();
  int h = t;
  float acc = 0.f;
  for (int s = 0; s < 256; ++s)
    acc += sa[s] * bf2f(encb[((size_t)s * 32 + b) * 512 + h]);
  if (j < 16) {
    fctxb[((size_t)b * 16 + j) * 512 + h] = f2u(acc);
  } else {
    out_ctx[b * 512 + h] = acc;
    leaf[b * 1024 + 512 + h] = acc;
    leaf[b * 1024 + h] = cur_node[b * 512 + h];
  }
}

// ---------- post: out_embw + einb build ----------
__global__ __launch_bounds__(256) void k_post(
    const float* __restrict__ emb_w, const float* __restrict__ num_pades,
    const float* __restrict__ leaf, float* __restrict__ out_embw,
    u16* __restrict__ einb) {
  int row = blockIdx.x, t = threadIdx.x;   // row < 640
  int n = row % 20, b = row / 20;
  #pragma unroll
  for (int k = 0; k < 2; ++k) {
    int h = t + 256 * k;
    float v = (n < 4) ? emb_w[n * 512 + h] : num_pades[((size_t)b * 16 + n - 4) * 512 + h];
    out_embw[(size_t)row * 512 + h] = v;
    einb[(size_t)row * 1536 + 1024 + h] = f2u(v);
  }
  #pragma unroll
  for (int k = 0; k < 4; ++k) {
    int c = t + 256 * k;
    einb[(size_t)row * 1536 + c] = f2u(leaf[b * 1024 + c]);
  }
}

// ---------- num_score: sum split-K partials + tanh reduce ----------
__global__ __launch_bounds__(64) void k_ns(
    const float* __restrict__ Tp, const float* __restrict__ bscore,
    const float* __restrict__ wscore_s, const int* __restrict__ mask_nums,
    float* __restrict__ out_ns) {
  int row = blockIdx.x; int lane = threadIdx.x;
  float acc = 0.f;
  #pragma unroll
  for (int i = 0; i < 8; ++i) {
    int h = lane + 64 * i;
    float tv = Tp[(size_t)row * 512 + h] + Tp[327680 + (size_t)row * 512 + h] +
               Tp[2L * 327680 + (size_t)row * 512 + h] + Tp[3L * 327680 + (size_t)row * 512 + h] +
               bscore[h];
    acc += ftanh(tv) * wscore_s[h];
  }
  for (int o = 32; o >= 1; o >>= 1) acc += __shfl_down(acc, o);
  if (lane == 0) out_ns[row] = mask_nums[row] ? NEG : acc;
}

// ---------- logits + formula_prob softmax fused ----------
__global__ __launch_bounds__(512) void k_ffprob(
    const float* __restrict__ T3p, const float* __restrict__ bfp1,
    const float* __restrict__ Wfp2, const float* __restrict__ bfp2,
    float* __restrict__ out_fp) {
  int b = blockIdx.x, t = threadIdx.x;
  int w = t >> 6, lane = t & 63;
  __shared__ float lg[16];
  #pragma unroll
  for (int j2 = 0; j2 < 2; ++j2) {
    int j = w * 2 + j2;
    int row = b * 16 + j;
    float acc = 0.f;
    #pragma unroll
    for (int i = 0; i < 8; ++i) {
      int h = lane + 64 * i;
      float v = T3p[(size_t)row * 512 + h] + T3p[262144 + (size_t)row * 512 + h] + bfp1[h];
      acc += ftanh(v) * Wfp2[h];
    }
    for (int o = 32; o >= 1; o >>= 1) acc += __shfl_down(acc, o);
    if (lane == 0) lg[j] = acc + bfp2[0];
  }
  __syncthreads();
  if (t < 16) {
    float x = lg[t];
    float m = x;
    for (int o = 8; o >= 1; o >>= 1) m = fmaxf(m, __shfl_xor(m, o, 16));
    float e = __expf(x - m);
    float s = e;
    for (int o = 8; o >= 1; o >>= 1) s += __shfl_xor(s, o, 16);
    out_fp[b * 16 + t] = e / s;
  }
}

// ---------- op ----------
__global__ __launch_bounds__(64) void k_op(
    const float* __restrict__ leaf, const float* __restrict__ Wops,
    const float* __restrict__ bops, float* __restrict__ out_op) {
  int id = blockIdx.x; int o = id % 6, b = id / 6;
  int lane = threadIdx.x;
  float acc = 0.f;
  #pragma unroll
  for (int i = 0; i < 16; ++i) {
    int k = lane + 64 * i;
    acc += leaf[b * 1024 + k] * Wops[(size_t)k * 6 + o];
  }
  for (int off = 32; off >= 1; off >>= 1) acc += __shfl_down(acc, off);
  if (lane == 0) out_op[b * 6 + o] = acc + bops[o];
}

extern "C" void kernel_launch(void* const* d_in, const int* in_sizes, int n_in,
                              void* d_out, int out_size, void* d_ws, size_t ws_size,
                              hipStream_t stream) {
  const float* node_emb  = (const float*)d_in[0];
  const float* left      = (const float*)d_in[1];
  const float* enc       = (const float*)d_in[2];
  const float* num_pades = (const float*)d_in[3];
  const float* fs        = (const float*)d_in[4];
  const int*   has_left  = (const int*)d_in[5];
  const int*   seq_mask  = (const int*)d_in[6];
  const int*   mask_nums = (const int*)d_in[7];
  const float* emb_w     = (const float*)d_in[8];
  const float* Wcl  = (const float*)d_in[9];
  const float* bcl  = (const float*)d_in[10];
  const float* Wclg = (const float*)d_in[11];
  const float* bclg = (const float*)d_in[12];
  const float* Wcr  = (const float*)d_in[13];
  const float* bcr  = (const float*)d_in[14];
  const float* Wcrg = (const float*)d_in[15];
  const float* bcrg = (const float*)d_in[16];
  const float* Wops = (const float*)d_in[17];
  const float* bops = (const float*)d_in[18];
  const float* Wattn   = (const float*)d_in[19];
  const float* battn   = (const float*)d_in[20];
  const float* wattn_s = (const float*)d_in[21];
  const float* battn_s = (const float*)d_in[22];
  const float* Wfattn   = (const float*)d_in[23];
  const float* bfattn   = (const float*)d_in[24];
  const float* wfattn_s = (const float*)d_in[25];
  const float* bfattn_s = (const float*)d_in[26];
  const float* Wscore   = (const float*)d_in[27];
  const float* bscore   = (const float*)d_in[28];
  const float* wscore_s = (const float*)d_in[29];
  const float* Wfp1 = (const float*)d_in[30];
  const float* bfp1 = (const float*)d_in[31];
  const float* Wfp2 = (const float*)d_in[32];
  const float* bfp2 = (const float*)d_in[33];

  float* out = (float*)d_out;
  float* out_ns   = out + 0;
  float* out_op   = out + 640;
  float* out_cn   = out + 832;
  float* out_ctx  = out + 17216;
  float* out_embw = out + 33600;
  float* out_fp   = out + 361280;

  uint8_t* wsb = (uint8_t*)d_ws;
  u16*   encb = (u16*)(wsb + 0);              // 8,388,608 B (dead after k_ctxall)
  u16*   einb = (u16*)(wsb + 0);              // alias: 1,966,080 B (after ctxall)
  float* Tp   = (float*)(wsb + 2097152);      // alias: 5,242,880 B
  u16*   Wt   = (u16*)(wsb + 8388608);        // 1,048,576 B
  u16*   Wt2f = (u16*)(wsb + 9437184);        // 1,572,864 B
  u16*   Wt3  = (u16*)(wsb + 11010048);       // 524,288 B
  u16*   EW   = (u16*)(wsb + 11534336);       // 16,777,216 B
  float* T3p  = (float*)(wsb + 28311552);     // 2,097,152 B
  float* fb   = (float*)(wsb + 30408704);
  float* cur_node = fb + 0;          // 16384
  float* CW   = fb + 16384;          // 16384
  float* FW   = fb + 32768;          // 8192
  float* en   = fb + 40960;          // 8192
  float* fen  = fb + 49152;          // 131072
  float* leaf = fb + 180224;         // 32768
  u16*   fctxb= (u16*)(fb + 212992); // 262144 u16
  float* gp1  = fb + 344064;         // 131072
  float* gp2  = fb + 475136;         // 131072
  float* cwp  = fb + 606208;         // 98304  (end: 704512 f = 2.82 MB)

  // 1. prep: enc->bf16 + Wt / Wt2f / Wt3 transposes
  k_prep<<<2432, 256, 0, stream>>>(enc, encb, Wattn, Wfattn, Wt, Wscore, Wt2f, Wfp1, Wt3);
  // 2-4. gates + CW/FW chain
  k_p1<<<320, 256, 0, stream>>>(node_emb, left, has_left, Wcl, Wclg, Wcr, Wcrg,
                                fs, Wfattn, gp1, gp2, cwp);
  k_p2<<<128, 256, 0, stream>>>(gp1, gp2, has_left, bcl, bclg, bcr, bcrg, Wattn,
                                cur_node, out_cn, cwp);
  k_comb<<<48, 512, 0, stream>>>(cwp, battn, bfattn, CW, FW);
  // 5. G1: EW[8192][1024] = enc @ [We|Wfe]
  k_mfma<4, 4, true><<<dim3(64, 8, 1), 256, 0, stream>>>(encb, Wt, EW, nullptr, 512, 512, 1024, 16, 0);
  // 6-7. attention scores + softmaxes/contexts
  k_enfen<<<2048, 256, 0, stream>>>(EW, CW, FW, wattn_s, battn_s, wfattn_s, bfattn_s, seq_mask, en, fen);
  k_ctxall<<<544, 512, 0, stream>>>(en, fen, encb, cur_node, out_ctx, leaf, fctxb);
  // 8. out_embw + ein build
  k_post<<<640, 256, 0, stream>>>(emb_w, num_pades, leaf, out_embw, einb);
  // 9-10. num_score: T = ein @ Wscore (split-K=4), then reduce
  k_mfma<2, 2, false><<<dim3(10, 8, 4), 256, 0, stream>>>(einb, Wt2f, nullptr, Tp, 1536, 1536, 512, 12, 327680);
  k_ns<<<640, 64, 0, stream>>>(Tp, bscore, wscore_s, mask_nums, out_ns);
  // 11-12. formula prob: T3 = fctx @ Wfp1 (split-K=2), logits + softmax
  k_mfma<2, 2, false><<<dim3(8, 8, 2), 256, 0, stream>>>(fctxb, Wt3, nullptr, T3p, 512, 512, 512, 8, 262144);
  k_ffprob<<<32, 512, 0, stream>>>(T3p, bfp1, Wfp2, bfp2, out_fp);
  // 13. op
  k_op<<<192, 64, 0, stream>>>(leaf, Wops, bops, out_op);
}

// Round 5
// 117.951 us; speedup vs baseline: 3.4731x; 1.0763x over previous
//
#include <hip/hip_runtime.h>
#include <hip/hip_bf16.h>
#include <stdint.h>

#define H 512
#define S 256
#define B 32
#define R 16
#define NEG -1000000000000.0f

typedef unsigned short u16;
typedef short short8 __attribute__((ext_vector_type(8)));
typedef float f32x4 __attribute__((ext_vector_type(4)));

__device__ __forceinline__ float bf2f(u16 u) {
  unsigned int v = ((unsigned int)u) << 16;
  float f; __builtin_memcpy(&f, &v, 4); return f;
}
__device__ __forceinline__ u16 f2u(float x) {
  __hip_bfloat16 h = __float2bfloat16(x);
  u16 u; __builtin_memcpy(&u, &h, 2); return u;
}
__device__ __forceinline__ float ftanh(float x) {
  float e = __expf(2.f * x);
  return 1.f - 2.f * __builtin_amdgcn_rcpf(e + 1.f);
}
__device__ __forceinline__ float fsig(float x) {
  return __builtin_amdgcn_rcpf(1.f + __expf(-x));
}
__device__ __forceinline__ void gload16(const void* g, void* l) {
  __builtin_amdgcn_global_load_lds(
      (const __attribute__((address_space(1))) unsigned int*)g,
      (__attribute__((address_space(3))) unsigned int*)l, 16, 0, 0);
}

// ---------- trans tile helper ----------
__device__ __forceinline__ void trans_tile(const float* __restrict__ src, int nb, int k0,
                                           u16* __restrict__ dst, int n0, int Krows,
                                           float (*tile)[65], int t) {
  #pragma unroll
  for (int it = 0; it < 16; ++it) {
    int f = it * 256 + t; int r = f >> 6, c = f & 63;
    tile[r][c] = src[(size_t)(k0 + r) * 512 + nb + c];
  }
  __syncthreads();
  #pragma unroll
  for (int it = 0; it < 16; ++it) {
    int f = it * 256 + t; int r = f >> 6, c = f & 63;
    dst[(size_t)(n0 + r) * Krows + k0 + c] = f2u(tile[c][r]);
  }
}

// ---------- mega prep: enc->bf16, 3 transposes, gates partials, FW partials, embw/einb ----------
__global__ __launch_bounds__(256) void k_prep1(
    const float* __restrict__ enc, u16* __restrict__ encb,
    const float* __restrict__ Wattn, const float* __restrict__ Wfattn, u16* __restrict__ Wt,
    const float* __restrict__ Wscore, u16* __restrict__ Wt2f,
    const float* __restrict__ Wfp1, u16* __restrict__ Wt3,
    const float* __restrict__ node_emb, const float* __restrict__ left,
    const int* __restrict__ has_left,
    const float* __restrict__ Wcl, const float* __restrict__ Wclg,
    const float* __restrict__ Wcr, const float* __restrict__ Wcrg,
    const float* __restrict__ fs,
    float* __restrict__ gp1, float* __restrict__ gp2, float* __restrict__ cwp,
    const float* __restrict__ emb_w, const float* __restrict__ num_pades,
    float* __restrict__ out_embw, u16* __restrict__ einb) {
  __shared__ float tile[64][65];
  __shared__ float x[128];
  int id = blockIdx.x, t = threadIdx.x;
  if (id < 2048) {
    int i = (id * 256 + t) * 8;
    float4 a = *(const float4*)(enc + i);
    float4 b = *(const float4*)(enc + i + 4);
    short8 o;
    o[0] = (short)f2u(a.x); o[1] = (short)f2u(a.y); o[2] = (short)f2u(a.z); o[3] = (short)f2u(a.w);
    o[4] = (short)f2u(b.x); o[5] = (short)f2u(b.y); o[6] = (short)f2u(b.z); o[7] = (short)f2u(b.w);
    *(short8*)(encb + i) = o;
  } else if (id < 2176) {            // Wt: [We | Wfe] -> [1024][512]
    int f = id - 2048; int gx = f & 15, gy = f >> 4;
    int n0 = gx * 64, k0 = gy * 64;
    const float* src = (n0 < 512) ? (Wattn + 512 * 512) : Wfattn;
    int nb = (n0 < 512) ? n0 : n0 - 512;
    trans_tile(src, nb, k0, Wt, n0, 512, tile, t);
  } else if (id < 2368) {            // Wt2f: Wscore^T [512][1536]
    int f = id - 2176; int gx = f & 7, gy = f >> 3;
    trans_tile(Wscore, gx * 64, gy * 64, Wt2f, gx * 64, 1536, tile, t);
  } else if (id < 2432) {            // Wt3: Wfp1^T [512][512]
    int f = id - 2368; int gx = f & 7, gy = f >> 3;
    trans_tile(Wfp1, gx * 64, gy * 64, Wt3, gx * 64, 512, tile, t);
  } else if (id < 2688) {            // gates partials
    int f = id - 2432;
    int b = f >> 3, kc = f & 7;
    int hl = has_left[b];
    int k0 = kc * 128;
    float* o1 = gp1 + ((size_t)b * 8 + kc) * 512;
    float* o2 = gp2 + ((size_t)b * 8 + kc) * 512;
    if (!hl && kc >= 4) { o1[t] = 0.f; o1[t + 256] = 0.f; o2[t] = 0.f; o2[t + 256] = 0.f; return; }
    if (t < 128) {
      int k = k0 + t;
      x[t] = hl ? (k < 512 ? left[b * 512 + k] : node_emb[b * 512 + k - 512])
                : node_emb[b * 512 + k];
    }
    __syncthreads();
    const float* W1 = hl ? Wcr : Wcl;
    const float* W2 = hl ? Wcrg : Wclg;
    float a1 = 0.f, a2 = 0.f, a3 = 0.f, a4 = 0.f;
    for (int kk = 0; kk < 128; ++kk) {
      float xv = x[kk];
      const float* w1r = W1 + (size_t)(k0 + kk) * 512;
      const float* w2r = W2 + (size_t)(k0 + kk) * 512;
      a1 += xv * w1r[t]; a2 += xv * w1r[t + 256];
      a3 += xv * w2r[t]; a4 += xv * w2r[t + 256];
    }
    o1[t] = a1; o1[t + 256] = a2; o2[t] = a3; o2[t + 256] = a4;
  } else if (id < 2752) {            // FW partials: fs @ Wff
    int f = id - 2688; int row = f >> 2, kc = f & 3;
    int k0 = kc * 128;
    if (t < 128) x[t] = fs[row * 512 + k0 + t];
    __syncthreads();
    const float* W = Wfattn + (size_t)(512 + k0) * 512;
    float a1 = 0.f, a2 = 0.f;
    for (int kk = 0; kk < 128; ++kk) {
      float xv = x[kk];
      a1 += xv * W[(size_t)kk * 512 + t];
      a2 += xv * W[(size_t)kk * 512 + t + 256];
    }
    float* o = cwp + ((size_t)(32 + row) * 4 + kc) * 512;
    o[t] = a1; o[t + 256] = a2;
  } else {                           // out_embw + einb emb columns
    int f = id - 2752;
    #pragma unroll
    for (int rr = 0; rr < 2; ++rr) {
      int row = f * 2 + rr;
      int n = row % 20, b = row / 20;
      #pragma unroll
      for (int i = 0; i < 2; ++i) {
        int h = t + 256 * i;
        float v = (n < 4) ? emb_w[n * 512 + h] : num_pades[((size_t)b * 16 + n - 4) * 512 + h];
        out_embw[(size_t)row * 512 + h] = v;
        einb[(size_t)row * 1536 + 1024 + h] = f2u(v);
      }
    }
  }
}

// ---------- GEMM device body: C = A[M,K] @ Bt[N,K]^T ----------
template <int FM, int FN, bool OUT16>
__device__ __forceinline__ void gemm_body(
    const u16* __restrict__ A, const u16* __restrict__ Bt,
    u16* __restrict__ C16, float* __restrict__ C32,
    int lda, int ldb, int ldc, int ksteps,
    int bm, int bn, int kbase, long zoff,
    u16* As, u16* Bs) {
  constexpr int BM = FM * 32, BN = FN * 32;
  const int tid = threadIdx.x;
  const int lane = tid & 63;
  const int wid = tid >> 6;
  const int wr = (wid >> 1) * (FM * 16);
  const int wc = (wid & 1) * (FN * 16);
  f32x4 acc[FM][FN];
  #pragma unroll
  for (int m = 0; m < FM; ++m)
    #pragma unroll
    for (int n = 0; n < FN; ++n)
      #pragma unroll
      for (int q = 0; q < 4; ++q) acc[m][n][q] = 0.f;

  const int kb = (lane >> 4) * 8;
  const int rr = lane & 15;
  for (int ks = 0; ks < ksteps; ++ks) {
    int k0 = kbase + ks * 32;
    #pragma unroll
    for (int it = 0; it < BM / 64; ++it) {
      int c = it * 256 + tid;
      gload16(A + (size_t)(bm + (c >> 2)) * lda + k0 + (c & 3) * 8, As + c * 8);
    }
    #pragma unroll
    for (int it = 0; it < BN / 64; ++it) {
      int c = it * 256 + tid;
      gload16(Bt + (size_t)(bn + (c >> 2)) * ldb + k0 + (c & 3) * 8, Bs + c * 8);
    }
    __syncthreads();
    short8 af[FM], bf[FN];
    #pragma unroll
    for (int m = 0; m < FM; ++m)
      af[m] = *(const short8*)(As + (wr + m * 16 + rr) * 32 + kb);
    #pragma unroll
    for (int n = 0; n < FN; ++n)
      bf[n] = *(const short8*)(Bs + (wc + n * 16 + rr) * 32 + kb);
    #pragma unroll
    for (int m = 0; m < FM; ++m)
      #pragma unroll
      for (int n = 0; n < FN; ++n)
        acc[m][n] = __builtin_amdgcn_mfma_f32_16x16x32_bf16(af[m], bf[n], acc[m][n], 0, 0, 0);
    __syncthreads();
  }
  int r0 = (lane >> 4) * 4, cc = lane & 15;
  #pragma unroll
  for (int m = 0; m < FM; ++m)
    #pragma unroll
    for (int n = 0; n < FN; ++n)
      #pragma unroll
      for (int q = 0; q < 4; ++q) {
        long row = bm + wr + m * 16 + r0 + q;
        long col = bn + wc + n * 16 + cc;
        if (OUT16) C16[zoff + row * ldc + col] = f2u(acc[m][n][q]);
        else       C32[zoff + row * ldc + col] = acc[m][n][q];
      }
}

// ---------- G1: EW = enc @ [We|Wfe]  (+ inline CW/FW combine in first 48 blocks) ----------
__global__ __launch_bounds__(256) void k_g1(
    const u16* __restrict__ encb, const u16* __restrict__ Wt, u16* __restrict__ EW,
    const float* __restrict__ cwp, const float* __restrict__ battn,
    const float* __restrict__ bfattn, float* __restrict__ CW, float* __restrict__ FW) {
  __shared__ u16 As[128 * 32];
  __shared__ u16 Bs[128 * 32];
  if (blockIdx.y == 0 && blockIdx.x < 48) {
    int row = blockIdx.x, t = threadIdx.x;
    #pragma unroll
    for (int i = 0; i < 2; ++i) {
      int h = t + 256 * i;
      float s = cwp[((size_t)row * 4 + 0) * 512 + h] + cwp[((size_t)row * 4 + 1) * 512 + h] +
                cwp[((size_t)row * 4 + 2) * 512 + h] + cwp[((size_t)row * 4 + 3) * 512 + h];
      if (row < 32) CW[row * 512 + h] = s + battn[h];
      else          FW[(row - 32) * 512 + h] = s + bfattn[h];
    }
  }
  gemm_body<4, 4, true>(encb, Wt, EW, nullptr, 512, 512, 1024, 16,
                        blockIdx.x * 128, blockIdx.y * 128, 0, 0, As, Bs);
}

// ---------- combined T (ein@Wscore) + T3 (fctx@Wfp1) GEMMs ----------
__global__ __launch_bounds__(256) void k_tt(
    const u16* __restrict__ einb, const u16* __restrict__ Wt2f, float* __restrict__ Tp,
    const u16* __restrict__ fctxb, const u16* __restrict__ Wt3, float* __restrict__ T3p) {
  __shared__ u16 As[64 * 32];
  __shared__ u16 Bs[64 * 32];
  int q = blockIdx.x;
  if (q < 320) {
    int x = q % 10, y = (q / 10) % 8, z = q / 80;
    gemm_body<2, 2, false>(einb, Wt2f, nullptr, Tp, 1536, 1536, 512, 12,
                           x * 64, y * 64, z * 12 * 32, (long)z * 327680, As, Bs);
  } else {
    int q2 = q - 320;
    int x = q2 % 8, y = (q2 / 8) % 8, z = q2 / 64;
    gemm_body<2, 2, false>(fctxb, Wt3, nullptr, T3p, 512, 512, 512, 8,
                           x * 64, y * 64, z * 8 * 32, (long)z * 262144, As, Bs);
  }
}

// ---------- p2: finish gates (cur_node slice) + CW partials ----------
__global__ __launch_bounds__(256) void k_p2(
    const float* __restrict__ gp1, const float* __restrict__ gp2,
    const int* __restrict__ has_left,
    const float* __restrict__ bcl, const float* __restrict__ bclg,
    const float* __restrict__ bcr, const float* __restrict__ bcrg,
    const float* __restrict__ Wattn,
    float* __restrict__ cur_node, float* __restrict__ out_cn, float* __restrict__ cwp) {
  int id = blockIdx.x, t = threadIdx.x;
  int row = id >> 2, kc = id & 3;
  int k0 = kc * 128;
  __shared__ float x[128];
  int hl = has_left[row];
  if (t < 128) {
    int h = k0 + t;
    float s1 = 0.f, s2 = 0.f;
    #pragma unroll
    for (int c = 0; c < 8; ++c) {
      s1 += gp1[((size_t)row * 8 + c) * 512 + h];
      s2 += gp2[((size_t)row * 8 + c) * 512 + h];
    }
    float v = ftanh(s1 + (hl ? bcr[h] : bcl[h])) * fsig(s2 + (hl ? bcrg[h] : bclg[h]));
    x[t] = v;
    cur_node[row * 512 + h] = v;
    out_cn[row * 512 + h] = v;
  }
  __syncthreads();
  const float* W = Wattn + (size_t)k0 * 512;
  float a1 = 0.f, a2 = 0.f;
  for (int kk = 0; kk < 128; ++kk) {
    float xv = x[kk];
    a1 += xv * W[(size_t)kk * 512 + t];
    a2 += xv * W[(size_t)kk * 512 + t + 256];
  }
  float* o = cwp + ((size_t)row * 4 + kc) * 512;
  o[t] = a1; o[t + 256] = a2;
}

// ---------- en + fen fused ----------
__global__ __launch_bounds__(256) void k_enfen(
    const u16* __restrict__ EW, const float* __restrict__ CW,
    const float* __restrict__ FW,
    const float* __restrict__ wattn_s, const float* __restrict__ battn_s,
    const float* __restrict__ wfattn_s, const float* __restrict__ bfattn_s,
    const int* __restrict__ seq_mask, float* __restrict__ en, float* __restrict__ fen) {
  __shared__ float sFW[16 * 512];
  __shared__ float swf[512], swa[512], scw[512];
  int bid = blockIdx.x;
  int b = bid >> 6;
  int s0 = (bid & 63) * 4;
  int t = threadIdx.x;
  #pragma unroll
  for (int q = 0; q < 32; ++q) sFW[q * 256 + t] = FW[q * 256 + t];
  swf[t] = wfattn_s[t]; swf[256 + t] = wfattn_s[256 + t];
  swa[t] = wattn_s[t];  swa[256 + t] = wattn_s[256 + t];
  scw[t] = CW[b * 512 + t]; scw[256 + t] = CW[b * 512 + 256 + t];
  __syncthreads();
  int w = t >> 6, lane = t & 63;
  int s = s0 + w;
  const u16* ew = EW + (size_t)(s * 32 + b) * 1024;
  float ewf[8], wfv[8];
  float accE = 0.f;
  #pragma unroll
  for (int i = 0; i < 8; ++i) {
    int h = lane + 64 * i;
    accE += ftanh(scw[h] + bf2f(ew[h])) * swa[h];
    ewf[i] = bf2f(ew[512 + h]);
    wfv[i] = swf[h];
  }
  for (int o = 32; o >= 1; o >>= 1) accE += __shfl_down(accE, o);
  int msk = seq_mask[b * 256 + s];
  if (lane == 0) en[b * 256 + s] = msk ? NEG : (accE + battn_s[0]);
  for (int r = 0; r < 16; ++r) {
    float a = 0.f;
    #pragma unroll
    for (int i = 0; i < 8; ++i) {
      int h = lane + 64 * i;
      a += ftanh(sFW[r * 512 + h] + ewf[i]) * wfv[i];
    }
    for (int o = 32; o >= 1; o >>= 1) a += __shfl_down(a, o);
    if (lane == 0) fen[((size_t)b * 16 + r) * 256 + s] = msk ? NEG : (a + bfattn_s[0]);
  }
}

// ---------- softmaxes + contexts fused (+ einb leaf cols) ----------
__global__ __launch_bounds__(512) void k_ctxall(
    const float* __restrict__ en, const float* __restrict__ fen,
    const u16* __restrict__ encb, const float* __restrict__ cur_node,
    float* __restrict__ out_ctx, float* __restrict__ leaf, u16* __restrict__ fctxb,
    u16* __restrict__ einb) {
  int br = blockIdx.x;
  int b = br / 17, j = br % 17;
  int t = threadIdx.x;
  __shared__ float red[512];
  __shared__ float sa[256];
  float xe = (t < 256) ? en[b * 256 + t] : NEG;
  red[t] = xe; __syncthreads();
  for (int o = 256; o > 0; o >>= 1) { if (t < o) red[t] = fmaxf(red[t], red[t + o]); __syncthreads(); }
  float m = red[0]; __syncthreads();
  float ee = (t < 256) ? __expf(xe - m) : 0.f;
  red[t] = ee; __syncthreads();
  for (int o = 256; o > 0; o >>= 1) { if (t < o) red[t] += red[t + o]; __syncthreads(); }
  float attn_v = ee / red[0];
  __syncthreads();
  float coef = attn_v;
  if (j < 16) {
    float xf = (t < 256) ? fen[((size_t)b * 16 + j) * 256 + t] : NEG;
    red[t] = xf; __syncthreads();
    for (int o = 256; o > 0; o >>= 1) { if (t < o) red[t] = fmaxf(red[t], red[t + o]); __syncthreads(); }
    float mf = red[0]; __syncthreads();
    float ef = (t < 256) ? __expf(xf - mf) : 0.f;
    red[t] = ef; __syncthreads();
    for (int o = 256; o > 0; o >>= 1) { if (t < o) red[t] += red[t + o]; __syncthreads(); }
    coef = ef / red[0] + 0.2f * attn_v;
    __syncthreads();
  }
  if (t < 256) sa[t] = coef;
  __syncthreads();
  int h = t;
  float acc = 0.f;
  for (int s = 0; s < 256; ++s)
    acc += sa[s] * bf2f(encb[((size_t)s * 32 + b) * 512 + h]);
  if (j < 16) {
    fctxb[((size_t)b * 16 + j) * 512 + h] = f2u(acc);
  } else {
    float cn = cur_node[b * 512 + h];
    out_ctx[b * 512 + h] = acc;
    leaf[b * 1024 + 512 + h] = acc;
    leaf[b * 1024 + h] = cn;
    u16 v1 = f2u(cn), v2 = f2u(acc);
    for (int n = 0; n < 20; ++n) {
      einb[(size_t)(b * 20 + n) * 1536 + h] = v1;
      einb[(size_t)(b * 20 + n) * 1536 + 512 + h] = v2;
    }
  }
}

// ---------- epilogue: num_score + formula_prob + op ----------
__global__ __launch_bounds__(256) void k_epi(
    const float* __restrict__ Tp, const float* __restrict__ bscore,
    const float* __restrict__ wscore_s, const int* __restrict__ mask_nums,
    float* __restrict__ out_ns,
    const float* __restrict__ T3p, const float* __restrict__ bfp1,
    const float* __restrict__ Wfp2, const float* __restrict__ bfp2,
    float* __restrict__ out_fp,
    const float* __restrict__ leaf, const float* __restrict__ Wops,
    const float* __restrict__ bops, float* __restrict__ out_op) {
  int id = blockIdx.x, t = threadIdx.x;
  int w = t >> 6, lane = t & 63;
  __shared__ float red[16];
  if (id < 640) {
    int row = id;
    float acc = 0.f;
    #pragma unroll
    for (int i = 0; i < 2; ++i) {
      int h = t + 256 * i;
      float tv = Tp[(size_t)row * 512 + h] + Tp[327680 + (size_t)row * 512 + h] +
                 Tp[2L * 327680 + (size_t)row * 512 + h] + Tp[3L * 327680 + (size_t)row * 512 + h] +
                 bscore[h];
      acc += ftanh(tv) * wscore_s[h];
    }
    for (int o = 32; o >= 1; o >>= 1) acc += __shfl_down(acc, o);
    if (lane == 0) red[w] = acc;
    __syncthreads();
    if (t == 0) out_ns[row] = mask_nums[row] ? NEG : (red[0] + red[1] + red[2] + red[3]);
  } else if (id < 672) {
    int b = id - 640;
    #pragma unroll
    for (int j2 = 0; j2 < 4; ++j2) {
      int j = w * 4 + j2;
      int row = b * 16 + j;
      float acc = 0.f;
      #pragma unroll
      for (int i = 0; i < 8; ++i) {
        int h = lane + 64 * i;
        float v = T3p[(size_t)row * 512 + h] + T3p[262144 + (size_t)row * 512 + h] + bfp1[h];
        acc += ftanh(v) * Wfp2[h];
      }
      for (int o = 32; o >= 1; o >>= 1) acc += __shfl_down(acc, o);
      if (lane == 0) red[j] = acc + bfp2[0];
    }
    __syncthreads();
    if (t < 16) {
      float xx = red[t];
      float mm = xx;
      for (int o = 8; o >= 1; o >>= 1) mm = fmaxf(mm, __shfl_xor(mm, o, 16));
      float e = __expf(xx - mm);
      float s2 = e;
      for (int o = 8; o >= 1; o >>= 1) s2 += __shfl_xor(s2, o, 16);
      out_fp[b * 16 + t] = e / s2;
    }
  } else {
    int f = id - 672; int o = f % 6, b = f / 6;
    float acc = 0.f;
    #pragma unroll
    for (int i = 0; i < 4; ++i) {
      int k = t + 256 * i;
      acc += leaf[b * 1024 + k] * Wops[(size_t)k * 6 + o];
    }
    for (int off = 32; off >= 1; off >>= 1) acc += __shfl_down(acc, off);
    if (lane == 0) red[w] = acc;
    __syncthreads();
    if (t == 0) out_op[b * 6 + o] = red[0] + red[1] + red[2] + red[3] + bops[o];
  }
}

extern "C" void kernel_launch(void* const* d_in, const int* in_sizes, int n_in,
                              void* d_out, int out_size, void* d_ws, size_t ws_size,
                              hipStream_t stream) {
  const float* node_emb  = (const float*)d_in[0];
  const float* left      = (const float*)d_in[1];
  const float* enc       = (const float*)d_in[2];
  const float* num_pades = (const float*)d_in[3];
  const float* fs        = (const float*)d_in[4];
  const int*   has_left  = (const int*)d_in[5];
  const int*   seq_mask  = (const int*)d_in[6];
  const int*   mask_nums = (const int*)d_in[7];
  const float* emb_w     = (const float*)d_in[8];
  const float* Wcl  = (const float*)d_in[9];
  const float* bcl  = (const float*)d_in[10];
  const float* Wclg = (const float*)d_in[11];
  const float* bclg = (const float*)d_in[12];
  const float* Wcr  = (const float*)d_in[13];
  const float* bcr  = (const float*)d_in[14];
  const float* Wcrg = (const float*)d_in[15];
  const float* bcrg = (const float*)d_in[16];
  const float* Wops = (const float*)d_in[17];
  const float* bops = (const float*)d_in[18];
  const float* Wattn   = (const float*)d_in[19];
  const float* battn   = (const float*)d_in[20];
  const float* wattn_s = (const float*)d_in[21];
  const float* battn_s = (const float*)d_in[22];
  const float* Wfattn   = (const float*)d_in[23];
  const float* bfattn   = (const float*)d_in[24];
  const float* wfattn_s = (const float*)d_in[25];
  const float* bfattn_s = (const float*)d_in[26];
  const float* Wscore   = (const float*)d_in[27];
  const float* bscore   = (const float*)d_in[28];
  const float* wscore_s = (const float*)d_in[29];
  const float* Wfp1 = (const float*)d_in[30];
  const float* bfp1 = (const float*)d_in[31];
  const float* Wfp2 = (const float*)d_in[32];
  const float* bfp2 = (const float*)d_in[33];

  float* out = (float*)d_out;
  float* out_ns   = out + 0;
  float* out_op   = out + 640;
  float* out_cn   = out + 832;
  float* out_ctx  = out + 17216;
  float* out_embw = out + 33600;
  float* out_fp   = out + 361280;

  // ws is 256 MiB — no aliasing needed.
  uint8_t* wsb = (uint8_t*)d_ws;
  u16*   encb = (u16*)(wsb + 0);              //  8,388,608
  u16*   Wt   = (u16*)(wsb + 8388608);        //  1,048,576
  u16*   Wt2f = (u16*)(wsb + 9437184);        //  1,572,864
  u16*   Wt3  = (u16*)(wsb + 11010048);       //    524,288
  u16*   EW   = (u16*)(wsb + 11534336);       // 16,777,216
  u16*   einb = (u16*)(wsb + 28311552);       //  1,966,080
  float* Tp   = (float*)(wsb + 30277632);     //  5,242,880
  float* T3p  = (float*)(wsb + 35520512);     //  2,097,152
  float* fb   = (float*)(wsb + 37617664);
  float* cur_node = fb + 0;          // 16384
  float* CW   = fb + 16384;          // 16384
  float* FW   = fb + 32768;          // 8192
  float* en   = fb + 40960;          // 8192
  float* fen  = fb + 49152;          // 131072
  float* leaf = fb + 180224;         // 32768
  u16*   fctxb= (u16*)(fb + 212992); // 262144 u16
  float* gp1  = fb + 344064;         // 131072
  float* gp2  = fb + 475136;         // 131072
  float* cwp  = fb + 606208;         // 98304

  // 1. mega prep (inputs only)
  k_prep1<<<3072, 256, 0, stream>>>(enc, encb, Wattn, Wfattn, Wt, Wscore, Wt2f, Wfp1, Wt3,
                                    node_emb, left, has_left, Wcl, Wclg, Wcr, Wcrg, fs,
                                    gp1, gp2, cwp, emb_w, num_pades, out_embw, einb);
  // 2. finish gates + CW partials
  k_p2<<<128, 256, 0, stream>>>(gp1, gp2, has_left, bcl, bclg, bcr, bcrg, Wattn,
                                cur_node, out_cn, cwp);
  // 3. G1 GEMM + CW/FW combine
  k_g1<<<dim3(64, 8), 256, 0, stream>>>(encb, Wt, EW, cwp, battn, bfattn, CW, FW);
  // 4. attention scores
  k_enfen<<<2048, 256, 0, stream>>>(EW, CW, FW, wattn_s, battn_s, wfattn_s, bfattn_s, seq_mask, en, fen);
  // 5. softmaxes + contexts (+ einb leaf cols)
  k_ctxall<<<544, 512, 0, stream>>>(en, fen, encb, cur_node, out_ctx, leaf, fctxb, einb);
  // 6. T + T3 GEMMs
  k_tt<<<448, 256, 0, stream>>>(einb, Wt2f, Tp, fctxb, Wt3, T3p);
  // 7. epilogue: ns + ffprob + op
  k_epi<<<864, 256, 0, stream>>>(Tp, bscore, wscore_s, mask_nums, out_ns,
                                 T3p, bfp1, Wfp2, bfp2, out_fp,
                                 leaf, Wops, bops, out_op);
}

// Round 6
// 115.725 us; speedup vs baseline: 3.5399x; 1.0192x over previous
//
#include <hip/hip_runtime.h>
#include <hip/hip_bf16.h>
#include <stdint.h>

#define H 512
#define S 256
#define B 32
#define R 16
#define NEG -1000000000000.0f

typedef unsigned short u16;
typedef short short8 __attribute__((ext_vector_type(8)));
typedef float f32x4 __attribute__((ext_vector_type(4)));

__device__ __forceinline__ float bf2f(u16 u) {
  unsigned int v = ((unsigned int)u) << 16;
  float f; __builtin_memcpy(&f, &v, 4); return f;
}
__device__ __forceinline__ u16 f2u(float x) {
  __hip_bfloat16 h = __float2bfloat16(x);
  u16 u; __builtin_memcpy(&u, &h, 2); return u;
}
__device__ __forceinline__ float ftanh(float x) {
  float e = __expf(2.f * x);
  return 1.f - 2.f * __builtin_amdgcn_rcpf(e + 1.f);
}
__device__ __forceinline__ float fsig(float x) {
  return __builtin_amdgcn_rcpf(1.f + __expf(-x));
}
__device__ __forceinline__ void gload16(const void* g, void* l) {
  __builtin_amdgcn_global_load_lds(
      (const __attribute__((address_space(1))) unsigned int*)g,
      (__attribute__((address_space(3))) unsigned int*)l, 16, 0, 0);
}

// ---------- trans tile helper: dst[(n0+r)*Krows + k0+c] = bf16(src[(k0+c)*512 + nb+r]) ----------
__device__ __forceinline__ void trans_tile(const float* __restrict__ src, int nb, int k0,
                                           u16* __restrict__ dst, int n0, int Krows,
                                           float (*tile)[65], int t) {
  #pragma unroll
  for (int it = 0; it < 16; ++it) {
    int f = it * 256 + t; int r = f >> 6, c = f & 63;
    tile[r][c] = src[(size_t)(k0 + r) * 512 + nb + c];
  }
  __syncthreads();
  #pragma unroll
  for (int it = 0; it < 16; ++it) {
    int f = it * 256 + t; int r = f >> 6, c = f & 63;
    dst[(size_t)(n0 + r) * Krows + k0 + c] = f2u(tile[c][r]);
  }
}

// ---------- mega prep: enc->bf16, 4 transposes, gates partials, embw/einb ----------
__global__ __launch_bounds__(256) void k_prep1(
    const float* __restrict__ enc, u16* __restrict__ encb,
    const float* __restrict__ Wattn, const float* __restrict__ Wfattn, u16* __restrict__ Wt,
    const float* __restrict__ Wscore, u16* __restrict__ Wt2f,
    const float* __restrict__ Wfp1, u16* __restrict__ Wt3,
    u16* __restrict__ Wt4,
    const float* __restrict__ node_emb, const float* __restrict__ left,
    const int* __restrict__ has_left,
    const float* __restrict__ Wcl, const float* __restrict__ Wclg,
    const float* __restrict__ Wcr, const float* __restrict__ Wcrg,
    float* __restrict__ gp1, float* __restrict__ gp2,
    const float* __restrict__ emb_w, const float* __restrict__ num_pades,
    float* __restrict__ out_embw, u16* __restrict__ einb) {
  __shared__ float tile[64][65];
  __shared__ float x[128];
  int id = blockIdx.x, t = threadIdx.x;
  if (id < 2048) {
    int i = (id * 256 + t) * 8;
    float4 a = *(const float4*)(enc + i);
    float4 b = *(const float4*)(enc + i + 4);
    short8 o;
    o[0] = (short)f2u(a.x); o[1] = (short)f2u(a.y); o[2] = (short)f2u(a.z); o[3] = (short)f2u(a.w);
    o[4] = (short)f2u(b.x); o[5] = (short)f2u(b.y); o[6] = (short)f2u(b.z); o[7] = (short)f2u(b.w);
    *(short8*)(encb + i) = o;
  } else if (id < 2176) {            // Wt: [We | Wfe] -> [1024][512]
    int f = id - 2048; int gx = f & 15, gy = f >> 4;
    int n0 = gx * 64, k0 = gy * 64;
    const float* src = (n0 < 512) ? (Wattn + 512 * 512) : Wfattn;
    int nb = (n0 < 512) ? n0 : n0 - 512;
    trans_tile(src, nb, k0, Wt, n0, 512, tile, t);
  } else if (id < 2368) {            // Wt2f: Wscore^T [512][1536]
    int f = id - 2176; int gx = f & 7, gy = f >> 3;
    trans_tile(Wscore, gx * 64, gy * 64, Wt2f, gx * 64, 1536, tile, t);
  } else if (id < 2432) {            // Wt3: Wfp1^T [512][512]
    int f = id - 2368; int gx = f & 7, gy = f >> 3;
    trans_tile(Wfp1, gx * 64, gy * 64, Wt3, gx * 64, 512, tile, t);
  } else if (id < 2560) {            // Wt4: [Wh^T | Wff^T] -> [1024][512]
    int f = id - 2432; int gx = f & 15, gy = f >> 4;
    int n0 = gx * 64, k0 = gy * 64;
    const float* src = (n0 < 512) ? Wattn : (Wfattn + 512 * 512);
    int nb = (n0 < 512) ? n0 : n0 - 512;
    trans_tile(src, nb, k0, Wt4, n0, 512, tile, t);
  } else if (id < 2816) {            // gates partials
    int f = id - 2560;
    int b = f >> 3, kc = f & 7;
    int hl = has_left[b];
    int k0 = kc * 128;
    float* o1 = gp1 + ((size_t)b * 8 + kc) * 512;
    float* o2 = gp2 + ((size_t)b * 8 + kc) * 512;
    if (!hl && kc >= 4) { o1[t] = 0.f; o1[t + 256] = 0.f; o2[t] = 0.f; o2[t + 256] = 0.f; return; }
    if (t < 128) {
      int k = k0 + t;
      x[t] = hl ? (k < 512 ? left[b * 512 + k] : node_emb[b * 512 + k - 512])
                : node_emb[b * 512 + k];
    }
    __syncthreads();
    const float* W1 = hl ? Wcr : Wcl;
    const float* W2 = hl ? Wcrg : Wclg;
    float a1 = 0.f, a2 = 0.f, a3 = 0.f, a4 = 0.f;
    for (int kk = 0; kk < 128; ++kk) {
      float xv = x[kk];
      const float* w1r = W1 + (size_t)(k0 + kk) * 512;
      const float* w2r = W2 + (size_t)(k0 + kk) * 512;
      a1 += xv * w1r[t]; a2 += xv * w1r[t + 256];
      a3 += xv * w2r[t]; a4 += xv * w2r[t + 256];
    }
    o1[t] = a1; o1[t + 256] = a2; o2[t] = a3; o2[t + 256] = a4;
  } else {                           // out_embw + einb emb columns
    int f = id - 2816;
    #pragma unroll
    for (int rr = 0; rr < 2; ++rr) {
      int row = f * 2 + rr;
      int n = row % 20, b = row / 20;
      #pragma unroll
      for (int i = 0; i < 2; ++i) {
        int h = t + 256 * i;
        float v = (n < 4) ? emb_w[n * 512 + h] : num_pades[((size_t)b * 16 + n - 4) * 512 + h];
        out_embw[(size_t)row * 512 + h] = v;
        einb[(size_t)row * 1536 + 1024 + h] = f2u(v);
      }
    }
  }
}

// ---------- GEMM device body: C = A[M,K] @ Bt[N,K]^T (C16 xor C32 non-null) ----------
template <int FM, int FN>
__device__ __forceinline__ void gemm_body(
    const u16* __restrict__ A, const u16* __restrict__ Bt,
    u16* __restrict__ C16, float* __restrict__ C32,
    int lda, int ldb, int ldc, int ksteps,
    int bm, int bn, int kbase, long zoff,
    u16* As, u16* Bs) {
  constexpr int BM = FM * 32, BN = FN * 32;
  const int tid = threadIdx.x;
  const int lane = tid & 63;
  const int wid = tid >> 6;
  const int wr = (wid >> 1) * (FM * 16);
  const int wc = (wid & 1) * (FN * 16);
  f32x4 acc[FM][FN];
  #pragma unroll
  for (int m = 0; m < FM; ++m)
    #pragma unroll
    for (int n = 0; n < FN; ++n)
      #pragma unroll
      for (int q = 0; q < 4; ++q) acc[m][n][q] = 0.f;

  const int kb = (lane >> 4) * 8;
  const int rr = lane & 15;
  for (int ks = 0; ks < ksteps; ++ks) {
    int k0 = kbase + ks * 32;
    #pragma unroll
    for (int it = 0; it < BM / 64; ++it) {
      int c = it * 256 + tid;
      gload16(A + (size_t)(bm + (c >> 2)) * lda + k0 + (c & 3) * 8, As + c * 8);
    }
    #pragma unroll
    for (int it = 0; it < BN / 64; ++it) {
      int c = it * 256 + tid;
      gload16(Bt + (size_t)(bn + (c >> 2)) * ldb + k0 + (c & 3) * 8, Bs + c * 8);
    }
    __syncthreads();
    short8 af[FM], bf[FN];
    #pragma unroll
    for (int m = 0; m < FM; ++m)
      af[m] = *(const short8*)(As + (wr + m * 16 + rr) * 32 + kb);
    #pragma unroll
    for (int n = 0; n < FN; ++n)
      bf[n] = *(const short8*)(Bs + (wc + n * 16 + rr) * 32 + kb);
    #pragma unroll
    for (int m = 0; m < FM; ++m)
      #pragma unroll
      for (int n = 0; n < FN; ++n)
        acc[m][n] = __builtin_amdgcn_mfma_f32_16x16x32_bf16(af[m], bf[n], acc[m][n], 0, 0, 0);
    __syncthreads();
  }
  int r0 = (lane >> 4) * 4, cc = lane & 15;
  #pragma unroll
  for (int m = 0; m < FM; ++m)
    #pragma unroll
    for (int n = 0; n < FN; ++n)
      #pragma unroll
      for (int q = 0; q < 4; ++q) {
        long row = bm + wr + m * 16 + r0 + q;
        long col = bn + wc + n * 16 + cc;
        if (C16) C16[zoff + row * ldc + col] = f2u(acc[m][n][q]);
        else     C32[zoff + row * ldc + col] = acc[m][n][q];
      }
}

// ---------- G1: EW = enc @ [We|Wfe]; extra x==64 tile: CWFW = cnfs @ [Wh^T|Wff^T] ----------
__global__ __launch_bounds__(256) void k_g1(
    const u16* __restrict__ encb, const u16* __restrict__ Wt, u16* __restrict__ EW,
    const u16* __restrict__ cnfs, const u16* __restrict__ Wt4, float* __restrict__ CWFW) {
  __shared__ u16 As[128 * 32];
  __shared__ u16 Bs[128 * 32];
  int x = blockIdx.x, y = blockIdx.y;
  if (x < 64)
    gemm_body<4, 4>(encb, Wt, EW, nullptr, 512, 512, 1024, 16, x * 128, y * 128, 0, 0, As, Bs);
  else
    gemm_body<4, 4>(cnfs, Wt4, nullptr, CWFW, 512, 512, 1024, 16, 0, y * 128, 0, 0, As, Bs);
}

// ---------- combined T (ein@Wscore, z=8) + T3 (fctx@Wfp1, z=4) GEMMs ----------
__global__ __launch_bounds__(256) void k_tt(
    const u16* __restrict__ einb, const u16* __restrict__ Wt2f, float* __restrict__ Tp,
    const u16* __restrict__ fctxb, const u16* __restrict__ Wt3, float* __restrict__ T3p) {
  __shared__ u16 As[64 * 32];
  __shared__ u16 Bs[64 * 32];
  int q = blockIdx.x;
  if (q < 640) {
    int x = q % 10, y = (q / 10) % 8, z = q / 80;
    gemm_body<2, 2>(einb, Wt2f, nullptr, Tp, 1536, 1536, 512, 6,
                    x * 64, y * 64, z * 6 * 32, (long)z * 327680, As, Bs);
  } else {
    int q2 = q - 640;
    int x = q2 % 8, y = (q2 / 8) % 8, z = q2 / 64;
    gemm_body<2, 2>(fctxb, Wt3, nullptr, T3p, 512, 512, 512, 4,
                    x * 64, y * 64, z * 4 * 32, (long)z * 262144, As, Bs);
  }
}

// ---------- p2lite: finish gates -> cur_node/out_cn/cnfs; fs rows; zero pad ----------
__global__ __launch_bounds__(256) void k_p2(
    const float* __restrict__ gp1, const float* __restrict__ gp2,
    const int* __restrict__ has_left,
    const float* __restrict__ bcl, const float* __restrict__ bclg,
    const float* __restrict__ bcr, const float* __restrict__ bcrg,
    const float* __restrict__ fs,
    float* __restrict__ cur_node, float* __restrict__ out_cn, u16* __restrict__ cnfs) {
  int id = blockIdx.x, t = threadIdx.x;
  if (id < 32) {
    int b = id, hl = has_left[b];
    #pragma unroll
    for (int i = 0; i < 2; ++i) {
      int h = t + 256 * i;
      float s1 = 0.f, s2 = 0.f;
      #pragma unroll
      for (int c = 0; c < 8; ++c) {
        s1 += gp1[((size_t)b * 8 + c) * 512 + h];
        s2 += gp2[((size_t)b * 8 + c) * 512 + h];
      }
      float v = ftanh(s1 + (hl ? bcr[h] : bcl[h])) * fsig(s2 + (hl ? bcrg[h] : bclg[h]));
      cur_node[b * 512 + h] = v;
      out_cn[b * 512 + h] = v;
      cnfs[b * 512 + h] = f2u(v);
    }
  } else if (id < 48) {
    int r = id - 32;
    #pragma unroll
    for (int i = 0; i < 2; ++i) {
      int h = t + 256 * i;
      cnfs[id * 512 + h] = f2u(fs[r * 512 + h]);
    }
  } else {
    #pragma unroll
    for (int i = 0; i < 2; ++i) cnfs[id * 512 + t + 256 * i] = 0;
  }
}

// ---------- en + fen fused (reads CWFW + biases) ----------
__global__ __launch_bounds__(256) void k_enfen(
    const u16* __restrict__ EW, const float* __restrict__ CWFW,
    const float* __restrict__ battn, const float* __restrict__ bfattn,
    const float* __restrict__ wattn_s, const float* __restrict__ battn_s,
    const float* __restrict__ wfattn_s, const float* __restrict__ bfattn_s,
    const int* __restrict__ seq_mask, float* __restrict__ en, float* __restrict__ fen) {
  __shared__ float sFW[16 * 512];
  __shared__ float swf[512], swa[512], scw[512];
  int bid = blockIdx.x;
  int b = bid >> 6;
  int s0 = (bid & 63) * 4;
  int t = threadIdx.x;
  #pragma unroll
  for (int q = 0; q < 32; ++q) {
    int flat = q * 256 + t;
    int r = flat >> 9, h = flat & 511;
    sFW[flat] = CWFW[(size_t)(32 + r) * 1024 + 512 + h] + bfattn[h];
  }
  swf[t] = wfattn_s[t]; swf[256 + t] = wfattn_s[256 + t];
  swa[t] = wattn_s[t];  swa[256 + t] = wattn_s[256 + t];
  scw[t] = CWFW[(size_t)b * 1024 + t] + battn[t];
  scw[256 + t] = CWFW[(size_t)b * 1024 + 256 + t] + battn[256 + t];
  __syncthreads();
  int w = t >> 6, lane = t & 63;
  int s = s0 + w;
  const u16* ew = EW + (size_t)(s * 32 + b) * 1024;
  float ewf[8], wfv[8];
  float accE = 0.f;
  #pragma unroll
  for (int i = 0; i < 8; ++i) {
    int h = lane + 64 * i;
    accE += ftanh(scw[h] + bf2f(ew[h])) * swa[h];
    ewf[i] = bf2f(ew[512 + h]);
    wfv[i] = swf[h];
  }
  for (int o = 32; o >= 1; o >>= 1) accE += __shfl_down(accE, o);
  int msk = seq_mask[b * 256 + s];
  if (lane == 0) en[b * 256 + s] = msk ? NEG : (accE + battn_s[0]);
  for (int r = 0; r < 16; ++r) {
    float a = 0.f;
    #pragma unroll
    for (int i = 0; i < 8; ++i) {
      int h = lane + 64 * i;
      a += ftanh(sFW[r * 512 + h] + ewf[i]) * wfv[i];
    }
    for (int o = 32; o >= 1; o >>= 1) a += __shfl_down(a, o);
    if (lane == 0) fen[((size_t)b * 16 + r) * 256 + s] = msk ? NEG : (a + bfattn_s[0]);
  }
}

// ---------- softmaxes + contexts fused (+ einb leaf cols) ----------
__global__ __launch_bounds__(512) void k_ctxall(
    const float* __restrict__ en, const float* __restrict__ fen,
    const u16* __restrict__ encb, const float* __restrict__ cur_node,
    float* __restrict__ out_ctx, float* __restrict__ leaf, u16* __restrict__ fctxb,
    u16* __restrict__ einb) {
  int br = blockIdx.x;
  int b = br / 17, j = br % 17;
  int t = threadIdx.x;
  __shared__ float red[512];
  __shared__ float sa[256];
  float xe = (t < 256) ? en[b * 256 + t] : NEG;
  red[t] = xe; __syncthreads();
  for (int o = 256; o > 0; o >>= 1) { if (t < o) red[t] = fmaxf(red[t], red[t + o]); __syncthreads(); }
  float m = red[0]; __syncthreads();
  float ee = (t < 256) ? __expf(xe - m) : 0.f;
  red[t] = ee; __syncthreads();
  for (int o = 256; o > 0; o >>= 1) { if (t < o) red[t] += red[t + o]; __syncthreads(); }
  float attn_v = ee / red[0];
  __syncthreads();
  float coef = attn_v;
  if (j < 16) {
    float xf = (t < 256) ? fen[((size_t)b * 16 + j) * 256 + t] : NEG;
    red[t] = xf; __syncthreads();
    for (int o = 256; o > 0; o >>= 1) { if (t < o) red[t] = fmaxf(red[t], red[t + o]); __syncthreads(); }
    float mf = red[0]; __syncthreads();
    float ef = (t < 256) ? __expf(xf - mf) : 0.f;
    red[t] = ef; __syncthreads();
    for (int o = 256; o > 0; o >>= 1) { if (t < o) red[t] += red[t + o]; __syncthreads(); }
    coef = ef / red[0] + 0.2f * attn_v;
    __syncthreads();
  }
  if (t < 256) sa[t] = coef;
  __syncthreads();
  int h = t;
  float acc = 0.f;
  #pragma unroll 8
  for (int s = 0; s < 256; ++s)
    acc += sa[s] * bf2f(encb[((size_t)s * 32 + b) * 512 + h]);
  if (j < 16) {
    fctxb[((size_t)b * 16 + j) * 512 + h] = f2u(acc);
  } else {
    float cn = cur_node[b * 512 + h];
    out_ctx[b * 512 + h] = acc;
    leaf[b * 1024 + 512 + h] = acc;
    leaf[b * 1024 + h] = cn;
    u16 v1 = f2u(cn), v2 = f2u(acc);
    for (int n = 0; n < 20; ++n) {
      einb[(size_t)(b * 20 + n) * 1536 + h] = v1;
      einb[(size_t)(b * 20 + n) * 1536 + 512 + h] = v2;
    }
  }
}

// ---------- epilogue: num_score + formula_prob + op ----------
__global__ __launch_bounds__(256) void k_epi(
    const float* __restrict__ Tp, const float* __restrict__ bscore,
    const float* __restrict__ wscore_s, const int* __restrict__ mask_nums,
    float* __restrict__ out_ns,
    const float* __restrict__ T3p, const float* __restrict__ bfp1,
    const float* __restrict__ Wfp2, const float* __restrict__ bfp2,
    float* __restrict__ out_fp,
    const float* __restrict__ leaf, const float* __restrict__ Wops,
    const float* __restrict__ bops, float* __restrict__ out_op) {
  int id = blockIdx.x, t = threadIdx.x;
  int w = t >> 6, lane = t & 63;
  __shared__ float red[16];
  if (id < 640) {
    int row = id;
    float acc = 0.f;
    #pragma unroll
    for (int i = 0; i < 2; ++i) {
      int h = t + 256 * i;
      float tv = bscore[h];
      #pragma unroll
      for (int z = 0; z < 8; ++z) tv += Tp[(size_t)z * 327680 + (size_t)row * 512 + h];
      acc += ftanh(tv) * wscore_s[h];
    }
    for (int o = 32; o >= 1; o >>= 1) acc += __shfl_down(acc, o);
    if (lane == 0) red[w] = acc;
    __syncthreads();
    if (t == 0) out_ns[row] = mask_nums[row] ? NEG : (red[0] + red[1] + red[2] + red[3]);
  } else if (id < 672) {
    int b = id - 640;
    #pragma unroll
    for (int j2 = 0; j2 < 4; ++j2) {
      int j = w * 4 + j2;
      int row = b * 16 + j;
      float acc = 0.f;
      #pragma unroll
      for (int i = 0; i < 8; ++i) {
        int h = lane + 64 * i;
        float v = bfp1[h];
        #pragma unroll
        for (int z = 0; z < 4; ++z) v += T3p[(size_t)z * 262144 + (size_t)row * 512 + h];
        acc += ftanh(v) * Wfp2[h];
      }
      for (int o = 32; o >= 1; o >>= 1) acc += __shfl_down(acc, o);
      if (lane == 0) red[j] = acc + bfp2[0];
    }
    __syncthreads();
    if (t < 16) {
      float xx = red[t];
      float mm = xx;
      for (int o = 8; o >= 1; o >>= 1) mm = fmaxf(mm, __shfl_xor(mm, o, 16));
      float e = __expf(xx - mm);
      float s2 = e;
      for (int o = 8; o >= 1; o >>= 1) s2 += __shfl_xor(s2, o, 16);
      out_fp[b * 16 + t] = e / s2;
    }
  } else {
    int f = id - 672; int o = f % 6, b = f / 6;
    float acc = 0.f;
    #pragma unroll
    for (int i = 0; i < 4; ++i) {
      int k = t + 256 * i;
      acc += leaf[b * 1024 + k] * Wops[(size_t)k * 6 + o];
    }
    for (int off = 32; off >= 1; off >>= 1) acc += __shfl_down(acc, off);
    if (lane == 0) red[w] = acc;
    __syncthreads();
    if (t == 0) out_op[b * 6 + o] = red[0] + red[1] + red[2] + red[3] + bops[o];
  }
}

extern "C" void kernel_launch(void* const* d_in, const int* in_sizes, int n_in,
                              void* d_out, int out_size, void* d_ws, size_t ws_size,
                              hipStream_t stream) {
  const float* node_emb  = (const float*)d_in[0];
  const float* left      = (const float*)d_in[1];
  const float* enc       = (const float*)d_in[2];
  const float* num_pades = (const float*)d_in[3];
  const float* fs        = (const float*)d_in[4];
  const int*   has_left  = (const int*)d_in[5];
  const int*   seq_mask  = (const int*)d_in[6];
  const int*   mask_nums = (const int*)d_in[7];
  const float* emb_w     = (const float*)d_in[8];
  const float* Wcl  = (const float*)d_in[9];
  const float* bcl  = (const float*)d_in[10];
  const float* Wclg = (const float*)d_in[11];
  const float* bclg = (const float*)d_in[12];
  const float* Wcr  = (const float*)d_in[13];
  const float* bcr  = (const float*)d_in[14];
  const float* Wcrg = (const float*)d_in[15];
  const float* bcrg = (const float*)d_in[16];
  const float* Wops = (const float*)d_in[17];
  const float* bops = (const float*)d_in[18];
  const float* Wattn   = (const float*)d_in[19];
  const float* battn   = (const float*)d_in[20];
  const float* wattn_s = (const float*)d_in[21];
  const float* battn_s = (const float*)d_in[22];
  const float* Wfattn   = (const float*)d_in[23];
  const float* bfattn   = (const float*)d_in[24];
  const float* wfattn_s = (const float*)d_in[25];
  const float* bfattn_s = (const float*)d_in[26];
  const float* Wscore   = (const float*)d_in[27];
  const float* bscore   = (const float*)d_in[28];
  const float* wscore_s = (const float*)d_in[29];
  const float* Wfp1 = (const float*)d_in[30];
  const float* bfp1 = (const float*)d_in[31];
  const float* Wfp2 = (const float*)d_in[32];
  const float* bfp2 = (const float*)d_in[33];

  float* out = (float*)d_out;
  float* out_ns   = out + 0;
  float* out_op   = out + 640;
  float* out_cn   = out + 832;
  float* out_ctx  = out + 17216;
  float* out_embw = out + 33600;
  float* out_fp   = out + 361280;

  // ws is 256 MiB
  uint8_t* wsb = (uint8_t*)d_ws;
  u16*   encb = (u16*)(wsb + 0);              //  8,388,608
  u16*   Wt   = (u16*)(wsb + 8388608);        //  1,048,576
  u16*   Wt2f = (u16*)(wsb + 9437184);        //  1,572,864
  u16*   Wt3  = (u16*)(wsb + 11010048);       //    524,288
  u16*   Wt4  = (u16*)(wsb + 11534336);       //  1,048,576
  u16*   EW   = (u16*)(wsb + 12582912);       // 16,777,216
  u16*   einb = (u16*)(wsb + 29360128);       //  1,966,080
  u16*   cnfs = (u16*)(wsb + 31326208);       //    131,072
  float* CWFW = (float*)(wsb + 31457280);     //    524,288
  float* Tp   = (float*)(wsb + 31981568);     // 10,485,760
  float* T3p  = (float*)(wsb + 42467328);     //  4,194,304
  float* fb   = (float*)(wsb + 46661632);
  float* cur_node = fb + 0;          // 16384
  float* en   = fb + 16384;          // 8192
  float* fen  = fb + 24576;          // 131072
  float* leaf = fb + 155648;         // 32768
  u16*   fctxb= (u16*)(fb + 188416); // 262144 u16
  float* gp1  = fb + 319488;         // 131072
  float* gp2  = fb + 450560;         // 131072

  // 1. mega prep (inputs only)
  k_prep1<<<3136, 256, 0, stream>>>(enc, encb, Wattn, Wfattn, Wt, Wscore, Wt2f, Wfp1, Wt3, Wt4,
                                    node_emb, left, has_left, Wcl, Wclg, Wcr, Wcrg,
                                    gp1, gp2, emb_w, num_pades, out_embw, einb);
  // 2. finish gates -> cur_node + cnfs
  k_p2<<<128, 256, 0, stream>>>(gp1, gp2, has_left, bcl, bclg, bcr, bcrg, fs,
                                cur_node, out_cn, cnfs);
  // 3. G1 GEMM (EW) + CWFW GEMM tile
  k_g1<<<dim3(65, 8), 256, 0, stream>>>(encb, Wt, EW, cnfs, Wt4, CWFW);
  // 4. attention scores
  k_enfen<<<2048, 256, 0, stream>>>(EW, CWFW, battn, bfattn, wattn_s, battn_s,
                                    wfattn_s, bfattn_s, seq_mask, en, fen);
  // 5. softmaxes + contexts (+ einb leaf cols)
  k_ctxall<<<544, 512, 0, stream>>>(en, fen, encb, cur_node, out_ctx, leaf, fctxb, einb);
  // 6. T + T3 GEMMs (split-K 8 / 4)
  k_tt<<<896, 256, 0, stream>>>(einb, Wt2f, Tp, fctxb, Wt3, T3p);
  // 7. epilogue: ns + ffprob + op
  k_epi<<<864, 256, 0, stream>>>(Tp, bscore, wscore_s, mask_nums, out_ns,
                                 T3p, bfp1, Wfp2, bfp2, out_fp,
                                 leaf, Wops, bops, out_op);
}

// Round 7
// 112.702 us; speedup vs baseline: 3.6349x; 1.0268x over previous
//
#include <hip/hip_runtime.h>
#include <hip/hip_bf16.h>
#include <stdint.h>

#define H 512
#define S 256
#define B 32
#define R 16
#define NEG -1000000000000.0f

typedef unsigned short u16;
typedef short short8 __attribute__((ext_vector_type(8)));
typedef float f32x4 __attribute__((ext_vector_type(4)));

__device__ __forceinline__ float bf2f(u16 u) {
  unsigned int v = ((unsigned int)u) << 16;
  float f; __builtin_memcpy(&f, &v, 4); return f;
}
__device__ __forceinline__ u16 f2u(float x) {
  __hip_bfloat16 h = __float2bfloat16(x);
  u16 u; __builtin_memcpy(&u, &h, 2); return u;
}
__device__ __forceinline__ float ftanh(float x) {
  float e = __expf(2.f * x);
  return 1.f - 2.f * __builtin_amdgcn_rcpf(e + 1.f);
}
__device__ __forceinline__ float fsig(float x) {
  return __builtin_amdgcn_rcpf(1.f + __expf(-x));
}
__device__ __forceinline__ void gload16(const void* g, void* l) {
  __builtin_amdgcn_global_load_lds(
      (const __attribute__((address_space(1))) unsigned int*)g,
      (__attribute__((address_space(3))) unsigned int*)l, 16, 0, 0);
}

// ---------- trans tile helper ----------
__device__ __forceinline__ void trans_tile(const float* __restrict__ src, int nb, int k0,
                                           u16* __restrict__ dst, int n0, int Krows,
                                           float (*tile)[65], int t) {
  #pragma unroll
  for (int it = 0; it < 16; ++it) {
    int f = it * 256 + t; int r = f >> 6, c = f & 63;
    tile[r][c] = src[(size_t)(k0 + r) * 512 + nb + c];
  }
  __syncthreads();
  #pragma unroll
  for (int it = 0; it < 16; ++it) {
    int f = it * 256 + t; int r = f >> 6, c = f & 63;
    dst[(size_t)(n0 + r) * Krows + k0 + c] = f2u(tile[c][r]);
  }
}

// ---------- mega prep ----------
__global__ __launch_bounds__(256) void k_prep1(
    const float* __restrict__ enc, u16* __restrict__ encb,
    const float* __restrict__ Wattn, const float* __restrict__ Wfattn, u16* __restrict__ Wt,
    const float* __restrict__ Wscore, u16* __restrict__ Wt2a, u16* __restrict__ Wt2b,
    const float* __restrict__ Wfp1, u16* __restrict__ Wt3,
    u16* __restrict__ Wt4,
    const float* __restrict__ node_emb, const float* __restrict__ left,
    const int* __restrict__ has_left,
    const float* __restrict__ Wcl, const float* __restrict__ Wclg,
    const float* __restrict__ Wcr, const float* __restrict__ Wcrg,
    float* __restrict__ gp1, float* __restrict__ gp2,
    const float* __restrict__ emb_w, const float* __restrict__ num_pades,
    float* __restrict__ out_embw, u16* __restrict__ embb, u16* __restrict__ leafb) {
  __shared__ float tile[64][65];
  __shared__ float x[128];
  int id = blockIdx.x, t = threadIdx.x;
  if (id < 2048) {
    int i = (id * 256 + t) * 8;
    float4 a = *(const float4*)(enc + i);
    float4 b = *(const float4*)(enc + i + 4);
    short8 o;
    o[0] = (short)f2u(a.x); o[1] = (short)f2u(a.y); o[2] = (short)f2u(a.z); o[3] = (short)f2u(a.w);
    o[4] = (short)f2u(b.x); o[5] = (short)f2u(b.y); o[6] = (short)f2u(b.z); o[7] = (short)f2u(b.w);
    *(short8*)(encb + i) = o;
  } else if (id < 2176) {            // Wt: [We | Wfe] -> [1024][512]
    int f = id - 2048; int gx = f & 15, gy = f >> 4;
    int n0 = gx * 64, k0 = gy * 64;
    const float* src = (n0 < 512) ? (Wattn + 512 * 512) : Wfattn;
    int nb = (n0 < 512) ? n0 : n0 - 512;
    trans_tile(src, nb, k0, Wt, n0, 512, tile, t);
  } else if (id < 2240) {            // Wt2a: Wscore[1024:]^T [512][512]
    int f = id - 2176; int gx = f & 7, gy = f >> 3;
    trans_tile(Wscore + 1024 * 512, gx * 64, gy * 64, Wt2a, gx * 64, 512, tile, t);
  } else if (id < 2368) {            // Wt2b: Wscore[:1024]^T [512][1024]
    int f = id - 2240; int gx = f & 7, gy = f >> 3;
    trans_tile(Wscore, gx * 64, gy * 64, Wt2b, gx * 64, 1024, tile, t);
  } else if (id < 2432) {            // Wt3: Wfp1^T [512][512]
    int f = id - 2368; int gx = f & 7, gy = f >> 3;
    trans_tile(Wfp1, gx * 64, gy * 64, Wt3, gx * 64, 512, tile, t);
  } else if (id < 2560) {            // Wt4: [Wh^T | Wff^T] -> [1024][512]
    int f = id - 2432; int gx = f & 15, gy = f >> 4;
    int n0 = gx * 64, k0 = gy * 64;
    const float* src = (n0 < 512) ? Wattn : (Wfattn + 512 * 512);
    int nb = (n0 < 512) ? n0 : n0 - 512;
    trans_tile(src, nb, k0, Wt4, n0, 512, tile, t);
  } else if (id < 2816) {            // gates partials
    int f = id - 2560;
    int b = f >> 3, kc = f & 7;
    int hl = has_left[b];
    int k0 = kc * 128;
    float* o1 = gp1 + ((size_t)b * 8 + kc) * 512;
    float* o2 = gp2 + ((size_t)b * 8 + kc) * 512;
    if (!hl && kc >= 4) { o1[t] = 0.f; o1[t + 256] = 0.f; o2[t] = 0.f; o2[t + 256] = 0.f; return; }
    if (t < 128) {
      int k = k0 + t;
      x[t] = hl ? (k < 512 ? left[b * 512 + k] : node_emb[b * 512 + k - 512])
                : node_emb[b * 512 + k];
    }
    __syncthreads();
    const float* W1 = hl ? Wcr : Wcl;
    const float* W2 = hl ? Wcrg : Wclg;
    float a1 = 0.f, a2 = 0.f, a3 = 0.f, a4 = 0.f;
    for (int kk = 0; kk < 128; ++kk) {
      float xv = x[kk];
      const float* w1r = W1 + (size_t)(k0 + kk) * 512;
      const float* w2r = W2 + (size_t)(k0 + kk) * 512;
      a1 += xv * w1r[t]; a2 += xv * w1r[t + 256];
      a3 += xv * w2r[t]; a4 += xv * w2r[t + 256];
    }
    o1[t] = a1; o1[t + 256] = a2; o2[t] = a3; o2[t + 256] = a4;
  } else if (id < 3136) {            // out_embw + embb
    int f = id - 2816;
    #pragma unroll
    for (int rr = 0; rr < 2; ++rr) {
      int row = f * 2 + rr;
      int n = row % 20, b = row / 20;
      #pragma unroll
      for (int i = 0; i < 2; ++i) {
        int h = t + 256 * i;
        float v = (n < 4) ? emb_w[n * 512 + h] : num_pades[((size_t)b * 16 + n - 4) * 512 + h];
        out_embw[(size_t)row * 512 + h] = v;
        embb[(size_t)row * 512 + h] = f2u(v);
      }
    }
  } else {                           // leafb zero-pad rows 32..63
    int f = id - 3136;               // f < 8
    int base = 32 * 1024 + (f * 256 + t) * 16;
    short8 z8 = {0,0,0,0,0,0,0,0};
    *(short8*)(leafb + base) = z8;
    *(short8*)(leafb + base + 8) = z8;
  }
}

// ---------- GEMM device body ----------
template <int FM, int FN>
__device__ __forceinline__ void gemm_body(
    const u16* __restrict__ A, const u16* __restrict__ Bt,
    u16* __restrict__ C16, float* __restrict__ C32,
    int lda, int ldb, int ldc, int ksteps,
    int bm, int bn, int kbase, long zoff,
    u16* As, u16* Bs) {
  constexpr int BM = FM * 32, BN = FN * 32;
  const int tid = threadIdx.x;
  const int lane = tid & 63;
  const int wid = tid >> 6;
  const int wr = (wid >> 1) * (FM * 16);
  const int wc = (wid & 1) * (FN * 16);
  f32x4 acc[FM][FN];
  #pragma unroll
  for (int m = 0; m < FM; ++m)
    #pragma unroll
    for (int n = 0; n < FN; ++n)
      #pragma unroll
      for (int q = 0; q < 4; ++q) acc[m][n][q] = 0.f;

  const int kb = (lane >> 4) * 8;
  const int rr = lane & 15;
  for (int ks = 0; ks < ksteps; ++ks) {
    int k0 = kbase + ks * 32;
    #pragma unroll
    for (int it = 0; it < BM / 64; ++it) {
      int c = it * 256 + tid;
      gload16(A + (size_t)(bm + (c >> 2)) * lda + k0 + (c & 3) * 8, As + c * 8);
    }
    #pragma unroll
    for (int it = 0; it < BN / 64; ++it) {
      int c = it * 256 + tid;
      gload16(Bt + (size_t)(bn + (c >> 2)) * ldb + k0 + (c & 3) * 8, Bs + c * 8);
    }
    __syncthreads();
    short8 af[FM], bf[FN];
    #pragma unroll
    for (int m = 0; m < FM; ++m)
      af[m] = *(const short8*)(As + (wr + m * 16 + rr) * 32 + kb);
    #pragma unroll
    for (int n = 0; n < FN; ++n)
      bf[n] = *(const short8*)(Bs + (wc + n * 16 + rr) * 32 + kb);
    #pragma unroll
    for (int m = 0; m < FM; ++m)
      #pragma unroll
      for (int n = 0; n < FN; ++n)
        acc[m][n] = __builtin_amdgcn_mfma_f32_16x16x32_bf16(af[m], bf[n], acc[m][n], 0, 0, 0);
    __syncthreads();
  }
  int r0 = (lane >> 4) * 4, cc = lane & 15;
  #pragma unroll
  for (int m = 0; m < FM; ++m)
    #pragma unroll
    for (int n = 0; n < FN; ++n)
      #pragma unroll
      for (int q = 0; q < 4; ++q) {
        long row = bm + wr + m * 16 + r0 + q;
        long col = bn + wc + n * 16 + cc;
        if (C16) C16[zoff + row * ldc + col] = f2u(acc[m][n][q]);
        else     C32[zoff + row * ldc + col] = acc[m][n][q];
      }
}

// ---------- G1: EW = enc @ [We|Wfe]; x==64: CWFW = cnfs @ [Wh^T|Wff^T] ----------
__global__ __launch_bounds__(256) void k_g1(
    const u16* __restrict__ encb, const u16* __restrict__ Wt, u16* __restrict__ EW,
    const u16* __restrict__ cnfs, const u16* __restrict__ Wt4, float* __restrict__ CWFW) {
  __shared__ u16 As[128 * 32];
  __shared__ u16 Bs[128 * 32];
  int x = blockIdx.x, y = blockIdx.y;
  if (x < 64)
    gemm_body<4, 4>(encb, Wt, EW, nullptr, 512, 512, 1024, 16, x * 128, y * 128, 0, 0, As, Bs);
  else
    gemm_body<4, 4>(cnfs, Wt4, nullptr, CWFW, 512, 512, 1024, 16, 0, y * 128, 0, 0, As, Bs);
}

// ---------- combined T_emb + T_leaf + T3 GEMMs ----------
__global__ __launch_bounds__(256) void k_tt(
    const u16* __restrict__ embb, const u16* __restrict__ Wt2a, float* __restrict__ Tep,
    const u16* __restrict__ leafb, const u16* __restrict__ Wt2b, float* __restrict__ Tlp,
    const u16* __restrict__ fctxb, const u16* __restrict__ Wt3, float* __restrict__ T3p) {
  __shared__ u16 As[64 * 32];
  __shared__ u16 Bs[64 * 32];
  int q = blockIdx.x;
  if (q < 320) {                 // T_emb: 640x512 @ K=512, z=4
    int x = q % 10, y = (q / 10) % 8, z = q / 80;
    gemm_body<2, 2>(embb, Wt2a, nullptr, Tep, 512, 512, 512, 4,
                    x * 64, y * 64, z * 4 * 32, (long)z * 327680, As, Bs);
  } else if (q < 352) {          // T_leaf: 64x512 @ K=1024, z=4
    int q2 = q - 320; int y = q2 % 8, z = q2 / 8;
    gemm_body<2, 2>(leafb, Wt2b, nullptr, Tlp, 1024, 1024, 512, 8,
                    0, y * 64, z * 8 * 32, (long)z * 32768, As, Bs);
  } else {                       // T3: 512x512 @ K=512, z=4
    int q2 = q - 352;
    int x = q2 % 8, y = (q2 / 8) % 8, z = q2 / 64;
    gemm_body<2, 2>(fctxb, Wt3, nullptr, T3p, 512, 512, 512, 4,
                    x * 64, y * 64, z * 4 * 32, (long)z * 262144, As, Bs);
  }
}

// ---------- p2lite: finish gates -> cur_node/out_cn/cnfs; fs rows; zero pad ----------
__global__ __launch_bounds__(256) void k_p2(
    const float* __restrict__ gp1, const float* __restrict__ gp2,
    const int* __restrict__ has_left,
    const float* __restrict__ bcl, const float* __restrict__ bclg,
    const float* __restrict__ bcr, const float* __restrict__ bcrg,
    const float* __restrict__ fs,
    float* __restrict__ cur_node, float* __restrict__ out_cn, u16* __restrict__ cnfs) {
  int id = blockIdx.x, t = threadIdx.x;
  if (id < 32) {
    int b = id, hl = has_left[b];
    #pragma unroll
    for (int i = 0; i < 2; ++i) {
      int h = t + 256 * i;
      float s1 = 0.f, s2 = 0.f;
      #pragma unroll
      for (int c = 0; c < 8; ++c) {
        s1 += gp1[((size_t)b * 8 + c) * 512 + h];
        s2 += gp2[((size_t)b * 8 + c) * 512 + h];
      }
      float v = ftanh(s1 + (hl ? bcr[h] : bcl[h])) * fsig(s2 + (hl ? bcrg[h] : bclg[h]));
      cur_node[b * 512 + h] = v;
      out_cn[b * 512 + h] = v;
      cnfs[b * 512 + h] = f2u(v);
    }
  } else if (id < 48) {
    int r = id - 32;
    #pragma unroll
    for (int i = 0; i < 2; ++i) {
      int h = t + 256 * i;
      cnfs[id * 512 + h] = f2u(fs[r * 512 + h]);
    }
  } else {
    #pragma unroll
    for (int i = 0; i < 2; ++i) cnfs[id * 512 + t + 256 * i] = 0;
  }
}

// ---------- en + fen fused (mask-skip) ----------
__global__ __launch_bounds__(256) void k_enfen(
    const u16* __restrict__ EW, const float* __restrict__ CWFW,
    const float* __restrict__ battn, const float* __restrict__ bfattn,
    const float* __restrict__ wattn_s, const float* __restrict__ battn_s,
    const float* __restrict__ wfattn_s, const float* __restrict__ bfattn_s,
    const int* __restrict__ seq_mask, float* __restrict__ en, float* __restrict__ fen) {
  __shared__ float sFW[16 * 512];
  __shared__ float swf[512], swa[512], scw[512];
  int bid = blockIdx.x;
  int b = bid >> 6;
  int s0 = (bid & 63) * 4;
  int t = threadIdx.x;
  #pragma unroll
  for (int q = 0; q < 32; ++q) {
    int flat = q * 256 + t;
    int r = flat >> 9, h = flat & 511;
    sFW[flat] = CWFW[(size_t)(32 + r) * 1024 + 512 + h] + bfattn[h];
  }
  swf[t] = wfattn_s[t]; swf[256 + t] = wfattn_s[256 + t];
  swa[t] = wattn_s[t];  swa[256 + t] = wattn_s[256 + t];
  scw[t] = CWFW[(size_t)b * 1024 + t] + battn[t];
  scw[256 + t] = CWFW[(size_t)b * 1024 + 256 + t] + battn[256 + t];
  __syncthreads();
  int w = t >> 6, lane = t & 63;
  int s = s0 + w;
  int msk = seq_mask[b * 256 + s];
  if (msk) {
    if (lane == 0) {
      en[b * 256 + s] = NEG;
      for (int r = 0; r < 16; ++r) fen[((size_t)b * 16 + r) * 256 + s] = NEG;
    }
    return;
  }
  const u16* ew = EW + (size_t)(s * 32 + b) * 1024;
  float ewf[8], wfv[8];
  float accE = 0.f;
  #pragma unroll
  for (int i = 0; i < 8; ++i) {
    int h = lane + 64 * i;
    accE += ftanh(scw[h] + bf2f(ew[h])) * swa[h];
    ewf[i] = bf2f(ew[512 + h]);
    wfv[i] = swf[h];
  }
  for (int o = 32; o >= 1; o >>= 1) accE += __shfl_down(accE, o);
  if (lane == 0) en[b * 256 + s] = accE + battn_s[0];
  for (int r = 0; r < 16; ++r) {
    float a = 0.f;
    #pragma unroll
    for (int i = 0; i < 8; ++i) {
      int h = lane + 64 * i;
      a += ftanh(sFW[r * 512 + h] + ewf[i]) * wfv[i];
    }
    for (int o = 32; o >= 1; o >>= 1) a += __shfl_down(a, o);
    if (lane == 0) fen[((size_t)b * 16 + r) * 256 + s] = a + bfattn_s[0];
  }
}

// ---------- softmaxes + contexts fused (+ leafb) ----------
__global__ __launch_bounds__(512) void k_ctxall(
    const float* __restrict__ en, const float* __restrict__ fen,
    const u16* __restrict__ encb, const float* __restrict__ cur_node,
    float* __restrict__ out_ctx, float* __restrict__ leaf, u16* __restrict__ fctxb,
    u16* __restrict__ leafb) {
  int br = blockIdx.x;
  int b = br / 17, j = br % 17;
  int t = threadIdx.x;
  __shared__ float red[512];
  __shared__ float sa[256];
  float xe = (t < 256) ? en[b * 256 + t] : NEG;
  red[t] = xe; __syncthreads();
  for (int o = 256; o > 0; o >>= 1) { if (t < o) red[t] = fmaxf(red[t], red[t + o]); __syncthreads(); }
  float m = red[0]; __syncthreads();
  float ee = (t < 256) ? __expf(xe - m) : 0.f;
  red[t] = ee; __syncthreads();
  for (int o = 256; o > 0; o >>= 1) { if (t < o) red[t] += red[t + o]; __syncthreads(); }
  float attn_v = ee / red[0];
  __syncthreads();
  float coef = attn_v;
  if (j < 16) {
    float xf = (t < 256) ? fen[((size_t)b * 16 + j) * 256 + t] : NEG;
    red[t] = xf; __syncthreads();
    for (int o = 256; o > 0; o >>= 1) { if (t < o) red[t] = fmaxf(red[t], red[t + o]); __syncthreads(); }
    float mf = red[0]; __syncthreads();
    float ef = (t < 256) ? __expf(xf - mf) : 0.f;
    red[t] = ef; __syncthreads();
    for (int o = 256; o > 0; o >>= 1) { if (t < o) red[t] += red[t + o]; __syncthreads(); }
    coef = ef / red[0] + 0.2f * attn_v;
    __syncthreads();
  }
  if (t < 256) sa[t] = coef;
  __syncthreads();
  int h = t;
  float acc = 0.f;
  #pragma unroll 8
  for (int s = 0; s < 256; ++s)
    acc += sa[s] * bf2f(encb[((size_t)s * 32 + b) * 512 + h]);
  if (j < 16) {
    fctxb[((size_t)b * 16 + j) * 512 + h] = f2u(acc);
  } else {
    float cn = cur_node[b * 512 + h];
    out_ctx[b * 512 + h] = acc;
    leaf[b * 1024 + 512 + h] = acc;
    leaf[b * 1024 + h] = cn;
    leafb[b * 1024 + h] = f2u(cn);
    leafb[b * 1024 + 512 + h] = f2u(acc);
  }
}

// ---------- epilogue: num_score + formula_prob + op ----------
__global__ __launch_bounds__(256) void k_epi(
    const float* __restrict__ Tep, const float* __restrict__ Tlp,
    const float* __restrict__ bscore,
    const float* __restrict__ wscore_s, const int* __restrict__ mask_nums,
    float* __restrict__ out_ns,
    const float* __restrict__ T3p, const float* __restrict__ bfp1,
    const float* __restrict__ Wfp2, const float* __restrict__ bfp2,
    float* __restrict__ out_fp,
    const float* __restrict__ leaf, const float* __restrict__ Wops,
    const float* __restrict__ bops, float* __restrict__ out_op) {
  int id = blockIdx.x, t = threadIdx.x;
  int w = t >> 6, lane = t & 63;
  __shared__ float red[16];
  if (id < 640) {
    int row = id;
    int b = row / 20;
    float acc = 0.f;
    #pragma unroll
    for (int i = 0; i < 2; ++i) {
      int h = t + 256 * i;
      float tv = bscore[h];
      #pragma unroll
      for (int z = 0; z < 4; ++z) tv += Tep[(size_t)z * 327680 + (size_t)row * 512 + h];
      #pragma unroll
      for (int z = 0; z < 4; ++z) tv += Tlp[(size_t)z * 32768 + (size_t)b * 512 + h];
      acc += ftanh(tv) * wscore_s[h];
    }
    for (int o = 32; o >= 1; o >>= 1) acc += __shfl_down(acc, o);
    if (lane == 0) red[w] = acc;
    __syncthreads();
    if (t == 0) out_ns[row] = mask_nums[row] ? NEG : (red[0] + red[1] + red[2] + red[3]);
  } else if (id < 672) {
    int b = id - 640;
    #pragma unroll
    for (int j2 = 0; j2 < 4; ++j2) {
      int j = w * 4 + j2;
      int row = b * 16 + j;
      float acc = 0.f;
      #pragma unroll
      for (int i = 0; i < 8; ++i) {
        int h = lane + 64 * i;
        float v = bfp1[h];
        #pragma unroll
        for (int z = 0; z < 4; ++z) v += T3p[(size_t)z * 262144 + (size_t)row * 512 + h];
        acc += ftanh(v) * Wfp2[h];
      }
      for (int o = 32; o >= 1; o >>= 1) acc += __shfl_down(acc, o);
      if (lane == 0) red[j] = acc + bfp2[0];
    }
    __syncthreads();
    if (t < 16) {
      float xx = red[t];
      float mm = xx;
      for (int o = 8; o >= 1; o >>= 1) mm = fmaxf(mm, __shfl_xor(mm, o, 16));
      float e = __expf(xx - mm);
      float s2 = e;
      for (int o = 8; o >= 1; o >>= 1) s2 += __shfl_xor(s2, o, 16);
      out_fp[b * 16 + t] = e / s2;
    }
  } else {
    int f = id - 672; int o = f % 6, b = f / 6;
    float acc = 0.f;
    #pragma unroll
    for (int i = 0; i < 4; ++i) {
      int k = t + 256 * i;
      acc += leaf[b * 1024 + k] * Wops[(size_t)k * 6 + o];
    }
    for (int off = 32; off >= 1; off >>= 1) acc += __shfl_down(acc, off);
    if (lane == 0) red[w] = acc;
    __syncthreads();
    if (t == 0) out_op[b * 6 + o] = red[0] + red[1] + red[2] + red[3] + bops[o];
  }
}

extern "C" void kernel_launch(void* const* d_in, const int* in_sizes, int n_in,
                              void* d_out, int out_size, void* d_ws, size_t ws_size,
                              hipStream_t stream) {
  const float* node_emb  = (const float*)d_in[0];
  const float* left      = (const float*)d_in[1];
  const float* enc       = (const float*)d_in[2];
  const float* num_pades = (const float*)d_in[3];
  const float* fs        = (const float*)d_in[4];
  const int*   has_left  = (const int*)d_in[5];
  const int*   seq_mask  = (const int*)d_in[6];
  const int*   mask_nums = (const int*)d_in[7];
  const float* emb_w     = (const float*)d_in[8];
  const float* Wcl  = (const float*)d_in[9];
  const float* bcl  = (const float*)d_in[10];
  const float* Wclg = (const float*)d_in[11];
  const float* bclg = (const float*)d_in[12];
  const float* Wcr  = (const float*)d_in[13];
  const float* bcr  = (const float*)d_in[14];
  const float* Wcrg = (const float*)d_in[15];
  const float* bcrg = (const float*)d_in[16];
  const float* Wops = (const float*)d_in[17];
  const float* bops = (const float*)d_in[18];
  const float* Wattn   = (const float*)d_in[19];
  const float* battn   = (const float*)d_in[20];
  const float* wattn_s = (const float*)d_in[21];
  const float* battn_s = (const float*)d_in[22];
  const float* Wfattn   = (const float*)d_in[23];
  const float* bfattn   = (const float*)d_in[24];
  const float* wfattn_s = (const float*)d_in[25];
  const float* bfattn_s = (const float*)d_in[26];
  const float* Wscore   = (const float*)d_in[27];
  const float* bscore   = (const float*)d_in[28];
  const float* wscore_s = (const float*)d_in[29];
  const float* Wfp1 = (const float*)d_in[30];
  const float* bfp1 = (const float*)d_in[31];
  const float* Wfp2 = (const float*)d_in[32];
  const float* bfp2 = (const float*)d_in[33];

  float* out = (float*)d_out;
  float* out_ns   = out + 0;
  float* out_op   = out + 640;
  float* out_cn   = out + 832;
  float* out_ctx  = out + 17216;
  float* out_embw = out + 33600;
  float* out_fp   = out + 361280;

  // ws is 256 MiB
  uint8_t* wsb = (uint8_t*)d_ws;
  u16*   encb = (u16*)(wsb + 0);              //  8,388,608
  u16*   Wt   = (u16*)(wsb + 8388608);        //  1,048,576
  u16*   Wt2a = (u16*)(wsb + 9437184);        //    524,288
  u16*   Wt2b = (u16*)(wsb + 9961472);        //  1,048,576
  u16*   Wt3  = (u16*)(wsb + 11010048);       //    524,288
  u16*   Wt4  = (u16*)(wsb + 11534336);       //  1,048,576
  u16*   EW   = (u16*)(wsb + 12582912);       // 16,777,216
  u16*   embb = (u16*)(wsb + 29360128);       //    655,360
  u16*   leafb= (u16*)(wsb + 30015488);       //    131,072
  u16*   cnfs = (u16*)(wsb + 30146560);       //    131,072
  float* CWFW = (float*)(wsb + 30277632);     //    524,288
  float* Tep  = (float*)(wsb + 30801920);     //  5,242,880
  float* Tlp  = (float*)(wsb + 36044800);     //    524,288
  float* T3p  = (float*)(wsb + 36569088);     //  4,194,304
  float* fb   = (float*)(wsb + 40763392);
  float* cur_node = fb + 0;          // 16384
  float* en   = fb + 16384;          // 8192
  float* fen  = fb + 24576;          // 131072
  float* leaf = fb + 155648;         // 32768
  u16*   fctxb= (u16*)(fb + 188416); // 262144 u16
  float* gp1  = fb + 319488;         // 131072
  float* gp2  = fb + 450560;         // 131072

  // 1. mega prep (inputs only)
  k_prep1<<<3144, 256, 0, stream>>>(enc, encb, Wattn, Wfattn, Wt, Wscore, Wt2a, Wt2b,
                                    Wfp1, Wt3, Wt4,
                                    node_emb, left, has_left, Wcl, Wclg, Wcr, Wcrg,
                                    gp1, gp2, emb_w, num_pades, out_embw, embb, leafb);
  // 2. finish gates -> cur_node + cnfs
  k_p2<<<128, 256, 0, stream>>>(gp1, gp2, has_left, bcl, bclg, bcr, bcrg, fs,
                                cur_node, out_cn, cnfs);
  // 3. G1 GEMM (EW) + CWFW GEMM tile
  k_g1<<<dim3(65, 8), 256, 0, stream>>>(encb, Wt, EW, cnfs, Wt4, CWFW);
  // 4. attention scores (mask-skip)
  k_enfen<<<2048, 256, 0, stream>>>(EW, CWFW, battn, bfattn, wattn_s, battn_s,
                                    wfattn_s, bfattn_s, seq_mask, en, fen);
  // 5. softmaxes + contexts (+ leafb)
  k_ctxall<<<544, 512, 0, stream>>>(en, fen, encb, cur_node, out_ctx, leaf, fctxb, leafb);
  // 6. T_emb + T_leaf + T3 GEMMs
  k_tt<<<608, 256, 0, stream>>>(embb, Wt2a, Tep, leafb, Wt2b, Tlp, fctxb, Wt3, T3p);
  // 7. epilogue: ns + ffprob + op
  k_epi<<<864, 256, 0, stream>>>(Tep, Tlp, bscore, wscore_s, mask_nums, out_ns,
                                 T3p, bfp1, Wfp2, bfp2, out_fp,
                                 leaf, Wops, bops, out_op);
}

// Round 8
// 110.868 us; speedup vs baseline: 3.6950x; 1.0165x over previous
//
#include <hip/hip_runtime.h>
#include <hip/hip_bf16.h>
#include <stdint.h>

#define H 512
#define S 256
#define B 32
#define R 16
#define NEG -1000000000000.0f

typedef unsigned short u16;
typedef short short8 __attribute__((ext_vector_type(8)));
typedef float f32x4 __attribute__((ext_vector_type(4)));

__device__ __forceinline__ float bf2f(u16 u) {
  unsigned int v = ((unsigned int)u) << 16;
  float f; __builtin_memcpy(&f, &v, 4); return f;
}
__device__ __forceinline__ u16 f2u(float x) {
  __hip_bfloat16 h = __float2bfloat16(x);
  u16 u; __builtin_memcpy(&u, &h, 2); return u;
}
__device__ __forceinline__ float ftanh(float x) {
  float e = __expf(2.f * x);
  return 1.f - 2.f * __builtin_amdgcn_rcpf(e + 1.f);
}
// Pade(5,4) tanh: 1 rcp instead of exp+rcp; |err| < 2.3e-3 on clamp range
__device__ __forceinline__ float ptanh(float x) {
  float xc = fminf(4.f, fmaxf(-4.f, x));
  float x2 = xc * xc;
  float num = xc * (945.f + x2 * (105.f + x2));
  float den = 945.f + x2 * (420.f + 15.f * x2);
  return num * __builtin_amdgcn_rcpf(den);
}
__device__ __forceinline__ float fsig(float x) {
  return __builtin_amdgcn_rcpf(1.f + __expf(-x));
}
__device__ __forceinline__ void gload16(const void* g, void* l) {
  __builtin_amdgcn_global_load_lds(
      (const __attribute__((address_space(1))) unsigned int*)g,
      (__attribute__((address_space(3))) unsigned int*)l, 16, 0, 0);
}

// ---------- trans tile helper ----------
__device__ __forceinline__ void trans_tile(const float* __restrict__ src, int nb, int k0,
                                           u16* __restrict__ dst, int n0, int Krows,
                                           float (*tile)[65], int t) {
  #pragma unroll
  for (int it = 0; it < 16; ++it) {
    int f = it * 256 + t; int r = f >> 6, c = f & 63;
    tile[r][c] = src[(size_t)(k0 + r) * 512 + nb + c];
  }
  __syncthreads();
  #pragma unroll
  for (int it = 0; it < 16; ++it) {
    int f = it * 256 + t; int r = f >> 6, c = f & 63;
    dst[(size_t)(n0 + r) * Krows + k0 + c] = f2u(tile[c][r]);
  }
}

// ---------- mega prep ----------
__global__ __launch_bounds__(256) void k_prep1(
    const float* __restrict__ enc, u16* __restrict__ encb,
    const float* __restrict__ Wattn, const float* __restrict__ Wfattn, u16* __restrict__ Wt,
    const float* __restrict__ Wscore, u16* __restrict__ Wt2a, u16* __restrict__ Wt2b,
    const float* __restrict__ Wfp1, u16* __restrict__ Wt3,
    u16* __restrict__ Wt4,
    const float* __restrict__ node_emb, const float* __restrict__ left,
    const int* __restrict__ has_left,
    const float* __restrict__ Wcl, const float* __restrict__ Wclg,
    const float* __restrict__ Wcr, const float* __restrict__ Wcrg,
    float* __restrict__ gp1, float* __restrict__ gp2,
    const float* __restrict__ emb_w, const float* __restrict__ num_pades,
    float* __restrict__ out_embw, u16* __restrict__ embb, u16* __restrict__ leafb) {
  __shared__ float tile[64][65];
  __shared__ float x[128];
  int id = blockIdx.x, t = threadIdx.x;
  if (id < 2048) {
    int i = (id * 256 + t) * 8;
    float4 a = *(const float4*)(enc + i);
    float4 b = *(const float4*)(enc + i + 4);
    short8 o;
    o[0] = (short)f2u(a.x); o[1] = (short)f2u(a.y); o[2] = (short)f2u(a.z); o[3] = (short)f2u(a.w);
    o[4] = (short)f2u(b.x); o[5] = (short)f2u(b.y); o[6] = (short)f2u(b.z); o[7] = (short)f2u(b.w);
    *(short8*)(encb + i) = o;
  } else if (id < 2176) {            // Wt: [We | Wfe] -> [1024][512]
    int f = id - 2048; int gx = f & 15, gy = f >> 4;
    int n0 = gx * 64, k0 = gy * 64;
    const float* src = (n0 < 512) ? (Wattn + 512 * 512) : Wfattn;
    int nb = (n0 < 512) ? n0 : n0 - 512;
    trans_tile(src, nb, k0, Wt, n0, 512, tile, t);
  } else if (id < 2240) {            // Wt2a: Wscore[1024:]^T [512][512]
    int f = id - 2176; int gx = f & 7, gy = f >> 3;
    trans_tile(Wscore + 1024 * 512, gx * 64, gy * 64, Wt2a, gx * 64, 512, tile, t);
  } else if (id < 2368) {            // Wt2b: Wscore[:1024]^T [512][1024]
    int f = id - 2240; int gx = f & 7, gy = f >> 3;
    trans_tile(Wscore, gx * 64, gy * 64, Wt2b, gx * 64, 1024, tile, t);
  } else if (id < 2432) {            // Wt3: Wfp1^T [512][512]
    int f = id - 2368; int gx = f & 7, gy = f >> 3;
    trans_tile(Wfp1, gx * 64, gy * 64, Wt3, gx * 64, 512, tile, t);
  } else if (id < 2560) {            // Wt4: [Wh^T | Wff^T] -> [1024][512]
    int f = id - 2432; int gx = f & 15, gy = f >> 4;
    int n0 = gx * 64, k0 = gy * 64;
    const float* src = (n0 < 512) ? Wattn : (Wfattn + 512 * 512);
    int nb = (n0 < 512) ? n0 : n0 - 512;
    trans_tile(src, nb, k0, Wt4, n0, 512, tile, t);
  } else if (id < 2816) {            // gates partials
    int f = id - 2560;
    int b = f >> 3, kc = f & 7;
    int hl = has_left[b];
    int k0 = kc * 128;
    float* o1 = gp1 + ((size_t)b * 8 + kc) * 512;
    float* o2 = gp2 + ((size_t)b * 8 + kc) * 512;
    if (!hl && kc >= 4) { o1[t] = 0.f; o1[t + 256] = 0.f; o2[t] = 0.f; o2[t + 256] = 0.f; return; }
    if (t < 128) {
      int k = k0 + t;
      x[t] = hl ? (k < 512 ? left[b * 512 + k] : node_emb[b * 512 + k - 512])
                : node_emb[b * 512 + k];
    }
    __syncthreads();
    const float* W1 = hl ? Wcr : Wcl;
    const float* W2 = hl ? Wcrg : Wclg;
    float a1 = 0.f, a2 = 0.f, a3 = 0.f, a4 = 0.f;
    for (int kk = 0; kk < 128; ++kk) {
      float xv = x[kk];
      const float* w1r = W1 + (size_t)(k0 + kk) * 512;
      const float* w2r = W2 + (size_t)(k0 + kk) * 512;
      a1 += xv * w1r[t]; a2 += xv * w1r[t + 256];
      a3 += xv * w2r[t]; a4 += xv * w2r[t + 256];
    }
    o1[t] = a1; o1[t + 256] = a2; o2[t] = a3; o2[t + 256] = a4;
  } else if (id < 3136) {            // out_embw + embb
    int f = id - 2816;
    #pragma unroll
    for (int rr = 0; rr < 2; ++rr) {
      int row = f * 2 + rr;
      int n = row % 20, b = row / 20;
      #pragma unroll
      for (int i = 0; i < 2; ++i) {
        int h = t + 256 * i;
        float v = (n < 4) ? emb_w[n * 512 + h] : num_pades[((size_t)b * 16 + n - 4) * 512 + h];
        out_embw[(size_t)row * 512 + h] = v;
        embb[(size_t)row * 512 + h] = f2u(v);
      }
    }
  } else {                           // leafb zero-pad rows 32..63
    int f = id - 3136;               // f < 8
    int base = 32 * 1024 + (f * 256 + t) * 16;
    short8 z8 = {0,0,0,0,0,0,0,0};
    *(short8*)(leafb + base) = z8;
    *(short8*)(leafb + base + 8) = z8;
  }
}

// ---------- GEMM device body ----------
template <int FM, int FN>
__device__ __forceinline__ void gemm_body(
    const u16* __restrict__ A, const u16* __restrict__ Bt,
    u16* __restrict__ C16, float* __restrict__ C32,
    int lda, int ldb, int ldc, int ksteps,
    int bm, int bn, int kbase, long zoff,
    u16* As, u16* Bs) {
  constexpr int BM = FM * 32, BN = FN * 32;
  const int tid = threadIdx.x;
  const int lane = tid & 63;
  const int wid = tid >> 6;
  const int wr = (wid >> 1) * (FM * 16);
  const int wc = (wid & 1) * (FN * 16);
  f32x4 acc[FM][FN];
  #pragma unroll
  for (int m = 0; m < FM; ++m)
    #pragma unroll
    for (int n = 0; n < FN; ++n)
      #pragma unroll
      for (int q = 0; q < 4; ++q) acc[m][n][q] = 0.f;

  const int kb = (lane >> 4) * 8;
  const int rr = lane & 15;
  for (int ks = 0; ks < ksteps; ++ks) {
    int k0 = kbase + ks * 32;
    #pragma unroll
    for (int it = 0; it < BM / 64; ++it) {
      int c = it * 256 + tid;
      gload16(A + (size_t)(bm + (c >> 2)) * lda + k0 + (c & 3) * 8, As + c * 8);
    }
    #pragma unroll
    for (int it = 0; it < BN / 64; ++it) {
      int c = it * 256 + tid;
      gload16(Bt + (size_t)(bn + (c >> 2)) * ldb + k0 + (c & 3) * 8, Bs + c * 8);
    }
    __syncthreads();
    short8 af[FM], bf[FN];
    #pragma unroll
    for (int m = 0; m < FM; ++m)
      af[m] = *(const short8*)(As + (wr + m * 16 + rr) * 32 + kb);
    #pragma unroll
    for (int n = 0; n < FN; ++n)
      bf[n] = *(const short8*)(Bs + (wc + n * 16 + rr) * 32 + kb);
    #pragma unroll
    for (int m = 0; m < FM; ++m)
      #pragma unroll
      for (int n = 0; n < FN; ++n)
        acc[m][n] = __builtin_amdgcn_mfma_f32_16x16x32_bf16(af[m], bf[n], acc[m][n], 0, 0, 0);
    __syncthreads();
  }
  int r0 = (lane >> 4) * 4, cc = lane & 15;
  #pragma unroll
  for (int m = 0; m < FM; ++m)
    #pragma unroll
    for (int n = 0; n < FN; ++n)
      #pragma unroll
      for (int q = 0; q < 4; ++q) {
        long row = bm + wr + m * 16 + r0 + q;
        long col = bn + wc + n * 16 + cc;
        if (C16) C16[zoff + row * ldc + col] = f2u(acc[m][n][q]);
        else     C32[zoff + row * ldc + col] = acc[m][n][q];
      }
}

// ---------- G1: EW = enc @ [We|Wfe]; x==64: CWFW = cnfs @ [Wh^T|Wff^T] ----------
__global__ __launch_bounds__(256) void k_g1(
    const u16* __restrict__ encb, const u16* __restrict__ Wt, u16* __restrict__ EW,
    const u16* __restrict__ cnfs, const u16* __restrict__ Wt4, float* __restrict__ CWFW) {
  __shared__ u16 As[128 * 32];
  __shared__ u16 Bs[128 * 32];
  int x = blockIdx.x, y = blockIdx.y;
  if (x < 64)
    gemm_body<4, 4>(encb, Wt, EW, nullptr, 512, 512, 1024, 16, x * 128, y * 128, 0, 0, As, Bs);
  else
    gemm_body<4, 4>(cnfs, Wt4, nullptr, CWFW, 512, 512, 1024, 16, 0, y * 128, 0, 0, As, Bs);
}

// ---------- combined T_emb + T_leaf + T3 GEMMs ----------
__global__ __launch_bounds__(256) void k_tt(
    const u16* __restrict__ embb, const u16* __restrict__ Wt2a, float* __restrict__ Tep,
    const u16* __restrict__ leafb, const u16* __restrict__ Wt2b, float* __restrict__ Tlp,
    const u16* __restrict__ fctxb, const u16* __restrict__ Wt3, float* __restrict__ T3p) {
  __shared__ u16 As[64 * 32];
  __shared__ u16 Bs[64 * 32];
  int q = blockIdx.x;
  if (q < 320) {                 // T_emb: 640x512 @ K=512, z=4
    int x = q % 10, y = (q / 10) % 8, z = q / 80;
    gemm_body<2, 2>(embb, Wt2a, nullptr, Tep, 512, 512, 512, 4,
                    x * 64, y * 64, z * 4 * 32, (long)z * 327680, As, Bs);
  } else if (q < 352) {          // T_leaf: 64x512 @ K=1024, z=4
    int q2 = q - 320; int y = q2 % 8, z = q2 / 8;
    gemm_body<2, 2>(leafb, Wt2b, nullptr, Tlp, 1024, 1024, 512, 8,
                    0, y * 64, z * 8 * 32, (long)z * 32768, As, Bs);
  } else {                       // T3: 512x512 @ K=512, z=4
    int q2 = q - 352;
    int x = q2 % 8, y = (q2 / 8) % 8, z = q2 / 64;
    gemm_body<2, 2>(fctxb, Wt3, nullptr, T3p, 512, 512, 512, 4,
                    x * 64, y * 64, z * 4 * 32, (long)z * 262144, As, Bs);
  }
}

// ---------- p2lite: finish gates -> cur_node/out_cn/cnfs; fs rows; zero pad ----------
__global__ __launch_bounds__(256) void k_p2(
    const float* __restrict__ gp1, const float* __restrict__ gp2,
    const int* __restrict__ has_left,
    const float* __restrict__ bcl, const float* __restrict__ bclg,
    const float* __restrict__ bcr, const float* __restrict__ bcrg,
    const float* __restrict__ fs,
    float* __restrict__ cur_node, float* __restrict__ out_cn, u16* __restrict__ cnfs) {
  int id = blockIdx.x, t = threadIdx.x;
  if (id < 32) {
    int b = id, hl = has_left[b];
    #pragma unroll
    for (int i = 0; i < 2; ++i) {
      int h = t + 256 * i;
      float s1 = 0.f, s2 = 0.f;
      #pragma unroll
      for (int c = 0; c < 8; ++c) {
        s1 += gp1[((size_t)b * 8 + c) * 512 + h];
        s2 += gp2[((size_t)b * 8 + c) * 512 + h];
      }
      float v = ftanh(s1 + (hl ? bcr[h] : bcl[h])) * fsig(s2 + (hl ? bcrg[h] : bclg[h]));
      cur_node[b * 512 + h] = v;
      out_cn[b * 512 + h] = v;
      cnfs[b * 512 + h] = f2u(v);
    }
  } else if (id < 48) {
    int r = id - 32;
    #pragma unroll
    for (int i = 0; i < 2; ++i) {
      int h = t + 256 * i;
      cnfs[id * 512 + h] = f2u(fs[r * 512 + h]);
    }
  } else {
    #pragma unroll
    for (int i = 0; i < 2; ++i) cnfs[id * 512 + t + 256 * i] = 0;
  }
}

// ---------- en + fen fused (mask-skip, Pade tanh) ----------
__global__ __launch_bounds__(256) void k_enfen(
    const u16* __restrict__ EW, const float* __restrict__ CWFW,
    const float* __restrict__ battn, const float* __restrict__ bfattn,
    const float* __restrict__ wattn_s, const float* __restrict__ battn_s,
    const float* __restrict__ wfattn_s, const float* __restrict__ bfattn_s,
    const int* __restrict__ seq_mask, float* __restrict__ en, float* __restrict__ fen) {
  __shared__ float sFW[16 * 512];
  __shared__ float swf[512], swa[512], scw[512];
  int bid = blockIdx.x;
  int b = bid >> 6;
  int s0 = (bid & 63) * 4;
  int t = threadIdx.x;
  #pragma unroll
  for (int q = 0; q < 32; ++q) {
    int flat = q * 256 + t;
    int r = flat >> 9, h = flat & 511;
    sFW[flat] = CWFW[(size_t)(32 + r) * 1024 + 512 + h] + bfattn[h];
  }
  swf[t] = wfattn_s[t]; swf[256 + t] = wfattn_s[256 + t];
  swa[t] = wattn_s[t];  swa[256 + t] = wattn_s[256 + t];
  scw[t] = CWFW[(size_t)b * 1024 + t] + battn[t];
  scw[256 + t] = CWFW[(size_t)b * 1024 + 256 + t] + battn[256 + t];
  __syncthreads();
  int w = t >> 6, lane = t & 63;
  int s = s0 + w;
  int msk = seq_mask[b * 256 + s];
  if (msk) {
    if (lane == 0) {
      en[b * 256 + s] = NEG;
      for (int r = 0; r < 16; ++r) fen[((size_t)b * 16 + r) * 256 + s] = NEG;
    }
    return;
  }
  const u16* ew = EW + (size_t)(s * 32 + b) * 1024;
  float ewf[8], wfv[8];
  float accE = 0.f;
  #pragma unroll
  for (int i = 0; i < 8; ++i) {
    int h = lane + 64 * i;
    accE += ptanh(scw[h] + bf2f(ew[h])) * swa[h];
    ewf[i] = bf2f(ew[512 + h]);
    wfv[i] = swf[h];
  }
  for (int o = 32; o >= 1; o >>= 1) accE += __shfl_down(accE, o);
  if (lane == 0) en[b * 256 + s] = accE + battn_s[0];
  for (int r = 0; r < 16; ++r) {
    float a = 0.f;
    #pragma unroll
    for (int i = 0; i < 8; ++i) {
      int h = lane + 64 * i;
      a += ptanh(sFW[r * 512 + h] + ewf[i]) * wfv[i];
    }
    for (int o = 32; o >= 1; o >>= 1) a += __shfl_down(a, o);
    if (lane == 0) fen[((size_t)b * 16 + r) * 256 + s] = a + bfattn_s[0];
  }
}

// ---------- softmaxes + contexts, j-paired (9 blocks per b) ----------
__global__ __launch_bounds__(512) void k_ctxall(
    const float* __restrict__ en, const float* __restrict__ fen,
    const u16* __restrict__ encb, const float* __restrict__ cur_node,
    float* __restrict__ out_ctx, float* __restrict__ leaf, u16* __restrict__ fctxb,
    u16* __restrict__ leafb) {
  int br = blockIdx.x;           // 288 = 32 * 9
  int b = br / 9, k = br % 9;
  int t = threadIdx.x;
  __shared__ float red[512];
  __shared__ float sa0[256], sa1[256];
  // en softmax -> attn_v
  float xe = (t < 256) ? en[b * 256 + t] : NEG;
  red[t] = xe; __syncthreads();
  for (int o = 256; o > 0; o >>= 1) { if (t < o) red[t] = fmaxf(red[t], red[t + o]); __syncthreads(); }
  float m = red[0]; __syncthreads();
  float ee = (t < 256) ? __expf(xe - m) : 0.f;
  red[t] = ee; __syncthreads();
  for (int o = 256; o > 0; o >>= 1) { if (t < o) red[t] += red[t + o]; __syncthreads(); }
  float attn_v = ee / red[0];
  __syncthreads();
  if (k < 8) {
    // two fen softmaxes: j0 = k, j1 = k + 8
    #pragma unroll
    for (int p = 0; p < 2; ++p) {
      int j = k + p * 8;
      float xf = (t < 256) ? fen[((size_t)b * 16 + j) * 256 + t] : NEG;
      red[t] = xf; __syncthreads();
      for (int o = 256; o > 0; o >>= 1) { if (t < o) red[t] = fmaxf(red[t], red[t + o]); __syncthreads(); }
      float mf = red[0]; __syncthreads();
      float ef = (t < 256) ? __expf(xf - mf) : 0.f;
      red[t] = ef; __syncthreads();
      for (int o = 256; o > 0; o >>= 1) { if (t < o) red[t] += red[t + o]; __syncthreads(); }
      float coef = ef / red[0] + 0.2f * attn_v;
      __syncthreads();
      if (t < 256) { if (p == 0) sa0[t] = coef; else sa1[t] = coef; }
    }
    __syncthreads();
    int h = t;
    float acc0 = 0.f, acc1 = 0.f;
    #pragma unroll 8
    for (int s = 0; s < 256; ++s) {
      float ev = bf2f(encb[((size_t)s * 32 + b) * 512 + h]);
      acc0 += sa0[s] * ev;
      acc1 += sa1[s] * ev;
    }
    fctxb[((size_t)b * 16 + k) * 512 + h] = f2u(acc0);
    fctxb[((size_t)b * 16 + k + 8) * 512 + h] = f2u(acc1);
  } else {
    // attn-only context (j==16 slice): coef = attn_v
    if (t < 256) sa0[t] = attn_v;
    __syncthreads();
    int h = t;
    float acc = 0.f;
    #pragma unroll 8
    for (int s = 0; s < 256; ++s)
      acc += sa0[s] * bf2f(encb[((size_t)s * 32 + b) * 512 + h]);
    float cn = cur_node[b * 512 + h];
    out_ctx[b * 512 + h] = acc;
    leaf[b * 1024 + 512 + h] = acc;
    leaf[b * 1024 + h] = cn;
    leafb[b * 1024 + h] = f2u(cn);
    leafb[b * 1024 + 512 + h] = f2u(acc);
  }
}

// ---------- epilogue: num_score + formula_prob + op ----------
__global__ __launch_bounds__(256) void k_epi(
    const float* __restrict__ Tep, const float* __restrict__ Tlp,
    const float* __restrict__ bscore,
    const float* __restrict__ wscore_s, const int* __restrict__ mask_nums,
    float* __restrict__ out_ns,
    const float* __restrict__ T3p, const float* __restrict__ bfp1,
    const float* __restrict__ Wfp2, const float* __restrict__ bfp2,
    float* __restrict__ out_fp,
    const float* __restrict__ leaf, const float* __restrict__ Wops,
    const float* __restrict__ bops, float* __restrict__ out_op) {
  int id = blockIdx.x, t = threadIdx.x;
  int w = t >> 6, lane = t & 63;
  __shared__ float red[16];
  if (id < 640) {
    int row = id;
    int b = row / 20;
    float acc = 0.f;
    #pragma unroll
    for (int i = 0; i < 2; ++i) {
      int h = t + 256 * i;
      float tv = bscore[h];
      #pragma unroll
      for (int z = 0; z < 4; ++z) tv += Tep[(size_t)z * 327680 + (size_t)row * 512 + h];
      #pragma unroll
      for (int z = 0; z < 4; ++z) tv += Tlp[(size_t)z * 32768 + (size_t)b * 512 + h];
      acc += ftanh(tv) * wscore_s[h];
    }
    for (int o = 32; o >= 1; o >>= 1) acc += __shfl_down(acc, o);
    if (lane == 0) red[w] = acc;
    __syncthreads();
    if (t == 0) out_ns[row] = mask_nums[row] ? NEG : (red[0] + red[1] + red[2] + red[3]);
  } else if (id < 672) {
    int b = id - 640;
    #pragma unroll
    for (int j2 = 0; j2 < 4; ++j2) {
      int j = w * 4 + j2;
      int row = b * 16 + j;
      float acc = 0.f;
      #pragma unroll
      for (int i = 0; i < 8; ++i) {
        int h = lane + 64 * i;
        float v = bfp1[h];
        #pragma unroll
        for (int z = 0; z < 4; ++z) v += T3p[(size_t)z * 262144 + (size_t)row * 512 + h];
        acc += ftanh(v) * Wfp2[h];
      }
      for (int o = 32; o >= 1; o >>= 1) acc += __shfl_down(acc, o);
      if (lane == 0) red[j] = acc + bfp2[0];
    }
    __syncthreads();
    if (t < 16) {
      float xx = red[t];
      float mm = xx;
      for (int o = 8; o >= 1; o >>= 1) mm = fmaxf(mm, __shfl_xor(mm, o, 16));
      float e = __expf(xx - mm);
      float s2 = e;
      for (int o = 8; o >= 1; o >>= 1) s2 += __shfl_xor(s2, o, 16);
      out_fp[b * 16 + t] = e / s2;
    }
  } else {
    int f = id - 672; int o = f % 6, b = f / 6;
    float acc = 0.f;
    #pragma unroll
    for (int i = 0; i < 4; ++i) {
      int k = t + 256 * i;
      acc += leaf[b * 1024 + k] * Wops[(size_t)k * 6 + o];
    }
    for (int off = 32; off >= 1; off >>= 1) acc += __shfl_down(acc, off);
    if (lane == 0) red[w] = acc;
    __syncthreads();
    if (t == 0) out_op[b * 6 + o] = red[0] + red[1] + red[2] + red[3] + bops[o];
  }
}

extern "C" void kernel_launch(void* const* d_in, const int* in_sizes, int n_in,
                              void* d_out, int out_size, void* d_ws, size_t ws_size,
                              hipStream_t stream) {
  const float* node_emb  = (const float*)d_in[0];
  const float* left      = (const float*)d_in[1];
  const float* enc       = (const float*)d_in[2];
  const float* num_pades = (const float*)d_in[3];
  const float* fs        = (const float*)d_in[4];
  const int*   has_left  = (const int*)d_in[5];
  const int*   seq_mask  = (const int*)d_in[6];
  const int*   mask_nums = (const int*)d_in[7];
  const float* emb_w     = (const float*)d_in[8];
  const float* Wcl  = (const float*)d_in[9];
  const float* bcl  = (const float*)d_in[10];
  const float* Wclg = (const float*)d_in[11];
  const float* bclg = (const float*)d_in[12];
  const float* Wcr  = (const float*)d_in[13];
  const float* bcr  = (const float*)d_in[14];
  const float* Wcrg = (const float*)d_in[15];
  const float* bcrg = (const float*)d_in[16];
  const float* Wops = (const float*)d_in[17];
  const float* bops = (const float*)d_in[18];
  const float* Wattn   = (const float*)d_in[19];
  const float* battn   = (const float*)d_in[20];
  const float* wattn_s = (const float*)d_in[21];
  const float* battn_s = (const float*)d_in[22];
  const float* Wfattn   = (const float*)d_in[23];
  const float* bfattn   = (const float*)d_in[24];
  const float* wfattn_s = (const float*)d_in[25];
  const float* bfattn_s = (const float*)d_in[26];
  const float* Wscore   = (const float*)d_in[27];
  const float* bscore   = (const float*)d_in[28];
  const float* wscore_s = (const float*)d_in[29];
  const float* Wfp1 = (const float*)d_in[30];
  const float* bfp1 = (const float*)d_in[31];
  const float* Wfp2 = (const float*)d_in[32];
  const float* bfp2 = (const float*)d_in[33];

  float* out = (float*)d_out;
  float* out_ns   = out + 0;
  float* out_op   = out + 640;
  float* out_cn   = out + 832;
  float* out_ctx  = out + 17216;
  float* out_embw = out + 33600;
  float* out_fp   = out + 361280;

  // ws is 256 MiB
  uint8_t* wsb = (uint8_t*)d_ws;
  u16*   encb = (u16*)(wsb + 0);              //  8,388,608
  u16*   Wt   = (u16*)(wsb + 8388608);        //  1,048,576
  u16*   Wt2a = (u16*)(wsb + 9437184);        //    524,288
  u16*   Wt2b = (u16*)(wsb + 9961472);        //  1,048,576
  u16*   Wt3  = (u16*)(wsb + 11010048);       //    524,288
  u16*   Wt4  = (u16*)(wsb + 11534336);       //  1,048,576
  u16*   EW   = (u16*)(wsb + 12582912);       // 16,777,216
  u16*   embb = (u16*)(wsb + 29360128);       //    655,360
  u16*   leafb= (u16*)(wsb + 30015488);       //    131,072
  u16*   cnfs = (u16*)(wsb + 30146560);       //    131,072
  float* CWFW = (float*)(wsb + 30277632);     //    524,288
  float* Tep  = (float*)(wsb + 30801920);     //  5,242,880
  float* Tlp  = (float*)(wsb + 36044800);     //    524,288
  float* T3p  = (float*)(wsb + 36569088);     //  4,194,304
  float* fb   = (float*)(wsb + 40763392);
  float* cur_node = fb + 0;          // 16384
  float* en   = fb + 16384;          // 8192
  float* fen  = fb + 24576;          // 131072
  float* leaf = fb + 155648;         // 32768
  u16*   fctxb= (u16*)(fb + 188416); // 262144 u16
  float* gp1  = fb + 319488;         // 131072
  float* gp2  = fb + 450560;         // 131072

  // 1. mega prep (inputs only)
  k_prep1<<<3144, 256, 0, stream>>>(enc, encb, Wattn, Wfattn, Wt, Wscore, Wt2a, Wt2b,
                                    Wfp1, Wt3, Wt4,
                                    node_emb, left, has_left, Wcl, Wclg, Wcr, Wcrg,
                                    gp1, gp2, emb_w, num_pades, out_embw, embb, leafb);
  // 2. finish gates -> cur_node + cnfs
  k_p2<<<128, 256, 0, stream>>>(gp1, gp2, has_left, bcl, bclg, bcr, bcrg, fs,
                                cur_node, out_cn, cnfs);
  // 3. G1 GEMM (EW) + CWFW GEMM tile
  k_g1<<<dim3(65, 8), 256, 0, stream>>>(encb, Wt, EW, cnfs, Wt4, CWFW);
  // 4. attention scores (mask-skip, Pade tanh)
  k_enfen<<<2048, 256, 0, stream>>>(EW, CWFW, battn, bfattn, wattn_s, battn_s,
                                    wfattn_s, bfattn_s, seq_mask, en, fen);
  // 5. softmaxes + contexts, j-paired (+ leafb)
  k_ctxall<<<288, 512, 0, stream>>>(en, fen, encb, cur_node, out_ctx, leaf, fctxb, leafb);
  // 6. T_emb + T_leaf + T3 GEMMs
  k_tt<<<608, 256, 0, stream>>>(embb, Wt2a, Tep, leafb, Wt2b, Tlp, fctxb, Wt3, T3p);
  // 7. epilogue: ns + ffprob + op
  k_epi<<<864, 256, 0, stream>>>(Tep, Tlp, bscore, wscore_s, mask_nums, out_ns,
                                 T3p, bfp1, Wfp2, bfp2, out_fp,
                                 leaf, Wops, bops, out_op);
}

// Round 9
// 104.836 us; speedup vs baseline: 3.9076x; 1.0575x over previous
//
#include <hip/hip_runtime.h>
#include <hip/hip_bf16.h>
#include <stdint.h>

#define H 512
#define S 256
#define B 32
#define R 16
#define NEG -1000000000000.0f

typedef unsigned short u16;
typedef short short8 __attribute__((ext_vector_type(8)));
typedef float f32x4 __attribute__((ext_vector_type(4)));

__device__ __forceinline__ float bf2f(u16 u) {
  unsigned int v = ((unsigned int)u) << 16;
  float f; __builtin_memcpy(&f, &v, 4); return f;
}
__device__ __forceinline__ u16 f2u(float x) {
  __hip_bfloat16 h = __float2bfloat16(x);
  u16 u; __builtin_memcpy(&u, &h, 2); return u;
}
__device__ __forceinline__ float ftanh(float x) {
  float e = __expf(2.f * x);
  return 1.f - 2.f * __builtin_amdgcn_rcpf(e + 1.f);
}
// Pade(5,4) tanh: 1 rcp instead of exp+rcp; |err| < 2.3e-3 on clamp range
__device__ __forceinline__ float ptanh(float x) {
  float xc = fminf(4.f, fmaxf(-4.f, x));
  float x2 = xc * xc;
  float num = xc * (945.f + x2 * (105.f + x2));
  float den = 945.f + x2 * (420.f + 15.f * x2);
  return num * __builtin_amdgcn_rcpf(den);
}
__device__ __forceinline__ float fsig(float x) {
  return __builtin_amdgcn_rcpf(1.f + __expf(-x));
}
__device__ __forceinline__ void gload16(const void* g, void* l) {
  __builtin_amdgcn_global_load_lds(
      (const __attribute__((address_space(1))) unsigned int*)g,
      (__attribute__((address_space(3))) unsigned int*)l, 16, 0, 0);
}

// ---------- trans tile helper ----------
__device__ __forceinline__ void trans_tile(const float* __restrict__ src, int nb, int k0,
                                           u16* __restrict__ dst, int n0, int Krows,
                                           float (*tile)[65], int t) {
  #pragma unroll
  for (int it = 0; it < 16; ++it) {
    int f = it * 256 + t; int r = f >> 6, c = f & 63;
    tile[r][c] = src[(size_t)(k0 + r) * 512 + nb + c];
  }
  __syncthreads();
  #pragma unroll
  for (int it = 0; it < 16; ++it) {
    int f = it * 256 + t; int r = f >> 6, c = f & 63;
    dst[(size_t)(n0 + r) * Krows + k0 + c] = f2u(tile[c][r]);
  }
}

// ---------- mega prep ----------
__global__ __launch_bounds__(256) void k_prep1(
    const float* __restrict__ enc, u16* __restrict__ encb,
    const float* __restrict__ Wattn, const float* __restrict__ Wfattn, u16* __restrict__ Wt,
    const float* __restrict__ Wscore, u16* __restrict__ Wt2a, u16* __restrict__ Wt2b,
    const float* __restrict__ Wfp1, u16* __restrict__ Wt3,
    u16* __restrict__ Wt4,
    const float* __restrict__ node_emb, const float* __restrict__ left,
    const int* __restrict__ has_left,
    const float* __restrict__ Wcl, const float* __restrict__ Wclg,
    const float* __restrict__ Wcr, const float* __restrict__ Wcrg,
    float* __restrict__ gp1, float* __restrict__ gp2,
    const float* __restrict__ emb_w, const float* __restrict__ num_pades,
    float* __restrict__ out_embw, u16* __restrict__ embb, u16* __restrict__ leafb) {
  __shared__ float tile[64][65];
  __shared__ float x[128];
  int id = blockIdx.x, t = threadIdx.x;
  if (id < 2048) {
    int i = (id * 256 + t) * 8;
    float4 a = *(const float4*)(enc + i);
    float4 b = *(const float4*)(enc + i + 4);
    short8 o;
    o[0] = (short)f2u(a.x); o[1] = (short)f2u(a.y); o[2] = (short)f2u(a.z); o[3] = (short)f2u(a.w);
    o[4] = (short)f2u(b.x); o[5] = (short)f2u(b.y); o[6] = (short)f2u(b.z); o[7] = (short)f2u(b.w);
    *(short8*)(encb + i) = o;
  } else if (id < 2176) {            // Wt: [We | Wfe] -> [1024][512]
    int f = id - 2048; int gx = f & 15, gy = f >> 4;
    int n0 = gx * 64, k0 = gy * 64;
    const float* src = (n0 < 512) ? (Wattn + 512 * 512) : Wfattn;
    int nb = (n0 < 512) ? n0 : n0 - 512;
    trans_tile(src, nb, k0, Wt, n0, 512, tile, t);
  } else if (id < 2240) {            // Wt2a: Wscore[1024:]^T [512][512]
    int f = id - 2176; int gx = f & 7, gy = f >> 3;
    trans_tile(Wscore + 1024 * 512, gx * 64, gy * 64, Wt2a, gx * 64, 512, tile, t);
  } else if (id < 2368) {            // Wt2b: Wscore[:1024]^T [512][1024]
    int f = id - 2240; int gx = f & 7, gy = f >> 3;
    trans_tile(Wscore, gx * 64, gy * 64, Wt2b, gx * 64, 1024, tile, t);
  } else if (id < 2432) {            // Wt3: Wfp1^T [512][512]
    int f = id - 2368; int gx = f & 7, gy = f >> 3;
    trans_tile(Wfp1, gx * 64, gy * 64, Wt3, gx * 64, 512, tile, t);
  } else if (id < 2560) {            // Wt4: [Wh^T | Wff^T] -> [1024][512]
    int f = id - 2432; int gx = f & 15, gy = f >> 4;
    int n0 = gx * 64, k0 = gy * 64;
    const float* src = (n0 < 512) ? Wattn : (Wfattn + 512 * 512);
    int nb = (n0 < 512) ? n0 : n0 - 512;
    trans_tile(src, nb, k0, Wt4, n0, 512, tile, t);
  } else if (id < 2816) {            // gates partials
    int f = id - 2560;
    int b = f >> 3, kc = f & 7;
    int hl = has_left[b];
    int k0 = kc * 128;
    float* o1 = gp1 + ((size_t)b * 8 + kc) * 512;
    float* o2 = gp2 + ((size_t)b * 8 + kc) * 512;
    if (!hl && kc >= 4) { o1[t] = 0.f; o1[t + 256] = 0.f; o2[t] = 0.f; o2[t + 256] = 0.f; return; }
    if (t < 128) {
      int k = k0 + t;
      x[t] = hl ? (k < 512 ? left[b * 512 + k] : node_emb[b * 512 + k - 512])
                : node_emb[b * 512 + k];
    }
    __syncthreads();
    const float* W1 = hl ? Wcr : Wcl;
    const float* W2 = hl ? Wcrg : Wclg;
    float a1 = 0.f, a2 = 0.f, a3 = 0.f, a4 = 0.f;
    for (int kk = 0; kk < 128; ++kk) {
      float xv = x[kk];
      const float* w1r = W1 + (size_t)(k0 + kk) * 512;
      const float* w2r = W2 + (size_t)(k0 + kk) * 512;
      a1 += xv * w1r[t]; a2 += xv * w1r[t + 256];
      a3 += xv * w2r[t]; a4 += xv * w2r[t + 256];
    }
    o1[t] = a1; o1[t + 256] = a2; o2[t] = a3; o2[t + 256] = a4;
  } else if (id < 3136) {            // out_embw + embb
    int f = id - 2816;
    #pragma unroll
    for (int rr = 0; rr < 2; ++rr) {
      int row = f * 2 + rr;
      int n = row % 20, b = row / 20;
      #pragma unroll
      for (int i = 0; i < 2; ++i) {
        int h = t + 256 * i;
        float v = (n < 4) ? emb_w[n * 512 + h] : num_pades[((size_t)b * 16 + n - 4) * 512 + h];
        out_embw[(size_t)row * 512 + h] = v;
        embb[(size_t)row * 512 + h] = f2u(v);
      }
    }
  } else {                           // leafb zero-pad rows 32..63
    int f = id - 3136;               // f < 8
    int base = 32 * 1024 + (f * 256 + t) * 16;
    short8 z8 = {0,0,0,0,0,0,0,0};
    *(short8*)(leafb + base) = z8;
    *(short8*)(leafb + base + 8) = z8;
  }
}

// ---------- GEMM device body ----------
template <int FM, int FN>
__device__ __forceinline__ void gemm_body(
    const u16* __restrict__ A, const u16* __restrict__ Bt,
    u16* __restrict__ C16, float* __restrict__ C32,
    int lda, int ldb, int ldc, int ksteps,
    int bm, int bn, int kbase, long zoff,
    u16* As, u16* Bs) {
  constexpr int BM = FM * 32, BN = FN * 32;
  const int tid = threadIdx.x;
  const int lane = tid & 63;
  const int wid = tid >> 6;
  const int wr = (wid >> 1) * (FM * 16);
  const int wc = (wid & 1) * (FN * 16);
  f32x4 acc[FM][FN];
  #pragma unroll
  for (int m = 0; m < FM; ++m)
    #pragma unroll
    for (int n = 0; n < FN; ++n)
      #pragma unroll
      for (int q = 0; q < 4; ++q) acc[m][n][q] = 0.f;

  const int kb = (lane >> 4) * 8;
  const int rr = lane & 15;
  for (int ks = 0; ks < ksteps; ++ks) {
    int k0 = kbase + ks * 32;
    #pragma unroll
    for (int it = 0; it < BM / 64; ++it) {
      int c = it * 256 + tid;
      gload16(A + (size_t)(bm + (c >> 2)) * lda + k0 + (c & 3) * 8, As + c * 8);
    }
    #pragma unroll
    for (int it = 0; it < BN / 64; ++it) {
      int c = it * 256 + tid;
      gload16(Bt + (size_t)(bn + (c >> 2)) * ldb + k0 + (c & 3) * 8, Bs + c * 8);
    }
    __syncthreads();
    short8 af[FM], bf[FN];
    #pragma unroll
    for (int m = 0; m < FM; ++m)
      af[m] = *(const short8*)(As + (wr + m * 16 + rr) * 32 + kb);
    #pragma unroll
    for (int n = 0; n < FN; ++n)
      bf[n] = *(const short8*)(Bs + (wc + n * 16 + rr) * 32 + kb);
    #pragma unroll
    for (int m = 0; m < FM; ++m)
      #pragma unroll
      for (int n = 0; n < FN; ++n)
        acc[m][n] = __builtin_amdgcn_mfma_f32_16x16x32_bf16(af[m], bf[n], acc[m][n], 0, 0, 0);
    __syncthreads();
  }
  int r0 = (lane >> 4) * 4, cc = lane & 15;
  #pragma unroll
  for (int m = 0; m < FM; ++m)
    #pragma unroll
    for (int n = 0; n < FN; ++n)
      #pragma unroll
      for (int q = 0; q < 4; ++q) {
        long row = bm + wr + m * 16 + r0 + q;
        long col = bn + wc + n * 16 + cc;
        if (C16) C16[zoff + row * ldc + col] = f2u(acc[m][n][q]);
        else     C32[zoff + row * ldc + col] = acc[m][n][q];
      }
}

// ---------- G1: EW GEMM (512) + CWFW GEMM (8) + T_emb GEMM (320) ----------
__global__ __launch_bounds__(256) void k_g1(
    const u16* __restrict__ encb, const u16* __restrict__ Wt, u16* __restrict__ EW,
    const u16* __restrict__ cnfs, const u16* __restrict__ Wt4, float* __restrict__ CWFW,
    const u16* __restrict__ embb, const u16* __restrict__ Wt2a, float* __restrict__ Tep) {
  __shared__ u16 As[128 * 32];
  __shared__ u16 Bs[128 * 32];
  int q = blockIdx.x;
  if (q < 512) {
    int x = q & 63, y = q >> 6;
    gemm_body<4, 4>(encb, Wt, EW, nullptr, 512, 512, 1024, 16, x * 128, y * 128, 0, 0, As, Bs);
  } else if (q < 520) {
    int y = q - 512;
    gemm_body<4, 4>(cnfs, Wt4, nullptr, CWFW, 512, 512, 1024, 16, 0, y * 128, 0, 0, As, Bs);
  } else {                      // T_emb: 640x512 @ K=512, z=4
    int q2 = q - 520;
    int x = q2 % 10, y = (q2 / 10) % 8, z = q2 / 80;
    gemm_body<2, 2>(embb, Wt2a, nullptr, Tep, 512, 512, 512, 4,
                    x * 64, y * 64, z * 4 * 32, (long)z * 327680, As, Bs);
  }
}

// ---------- tt: T_leaf (32) + T3 (256) GEMMs + op reduce (192) ----------
__global__ __launch_bounds__(256) void k_tt(
    const u16* __restrict__ leafb, const u16* __restrict__ Wt2b, float* __restrict__ Tlp,
    const u16* __restrict__ fctxb, const u16* __restrict__ Wt3, float* __restrict__ T3p,
    const float* __restrict__ leaf, const float* __restrict__ Wops,
    const float* __restrict__ bops, float* __restrict__ out_op) {
  __shared__ u16 As[64 * 32];
  __shared__ u16 Bs[64 * 32];
  __shared__ float red[4];
  int q = blockIdx.x;
  if (q < 32) {                  // T_leaf: 64x512 @ K=1024, z=4
    int y = q % 8, z = q / 8;
    gemm_body<2, 2>(leafb, Wt2b, nullptr, Tlp, 1024, 1024, 512, 8,
                    0, y * 64, z * 8 * 32, (long)z * 32768, As, Bs);
  } else if (q < 288) {          // T3: 512x512 @ K=512, z=4
    int q2 = q - 32;
    int x = q2 % 8, y = (q2 / 8) % 8, z = q2 / 64;
    gemm_body<2, 2>(fctxb, Wt3, nullptr, T3p, 512, 512, 512, 4,
                    x * 64, y * 64, z * 4 * 32, (long)z * 262144, As, Bs);
  } else {                       // op reduce
    int f = q - 288; int o = f % 6, b = f / 6;
    int t = threadIdx.x, w = t >> 6, lane = t & 63;
    float acc = 0.f;
    #pragma unroll
    for (int i = 0; i < 4; ++i) {
      int k = t + 256 * i;
      acc += leaf[b * 1024 + k] * Wops[(size_t)k * 6 + o];
    }
    for (int off = 32; off >= 1; off >>= 1) acc += __shfl_down(acc, off);
    if (lane == 0) red[w] = acc;
    __syncthreads();
    if (t == 0) out_op[b * 6 + o] = red[0] + red[1] + red[2] + red[3] + bops[o];
  }
}

// ---------- p2lite: finish gates -> cur_node/out_cn/cnfs; fs rows; zero pad ----------
__global__ __launch_bounds__(256) void k_p2(
    const float* __restrict__ gp1, const float* __restrict__ gp2,
    const int* __restrict__ has_left,
    const float* __restrict__ bcl, const float* __restrict__ bclg,
    const float* __restrict__ bcr, const float* __restrict__ bcrg,
    const float* __restrict__ fs,
    float* __restrict__ cur_node, float* __restrict__ out_cn, u16* __restrict__ cnfs) {
  int id = blockIdx.x, t = threadIdx.x;
  if (id < 32) {
    int b = id, hl = has_left[b];
    #pragma unroll
    for (int i = 0; i < 2; ++i) {
      int h = t + 256 * i;
      float s1 = 0.f, s2 = 0.f;
      #pragma unroll
      for (int c = 0; c < 8; ++c) {
        s1 += gp1[((size_t)b * 8 + c) * 512 + h];
        s2 += gp2[((size_t)b * 8 + c) * 512 + h];
      }
      float v = ftanh(s1 + (hl ? bcr[h] : bcl[h])) * fsig(s2 + (hl ? bcrg[h] : bclg[h]));
      cur_node[b * 512 + h] = v;
      out_cn[b * 512 + h] = v;
      cnfs[b * 512 + h] = f2u(v);
    }
  } else if (id < 48) {
    int r = id - 32;
    #pragma unroll
    for (int i = 0; i < 2; ++i) {
      int h = t + 256 * i;
      cnfs[id * 512 + h] = f2u(fs[r * 512 + h]);
    }
  } else {
    #pragma unroll
    for (int i = 0; i < 2; ++i) cnfs[id * 512 + t + 256 * i] = 0;
  }
}

// ---------- en + fen fused (mask-skip, Pade tanh, 8 s per block) ----------
__global__ __launch_bounds__(256) void k_enfen(
    const u16* __restrict__ EW, const float* __restrict__ CWFW,
    const float* __restrict__ battn, const float* __restrict__ bfattn,
    const float* __restrict__ wattn_s, const float* __restrict__ battn_s,
    const float* __restrict__ wfattn_s, const float* __restrict__ bfattn_s,
    const int* __restrict__ seq_mask, float* __restrict__ en, float* __restrict__ fen) {
  __shared__ float sFW[16 * 512];
  __shared__ float swf[512], swa[512], scw[512];
  int bid = blockIdx.x;          // 1024 = 32 b * 32 s-chunks
  int b = bid >> 5;
  int s0 = (bid & 31) * 8;
  int t = threadIdx.x;
  #pragma unroll
  for (int q = 0; q < 32; ++q) {
    int flat = q * 256 + t;
    int r = flat >> 9, h = flat & 511;
    sFW[flat] = CWFW[(size_t)(32 + r) * 1024 + 512 + h] + bfattn[h];
  }
  swf[t] = wfattn_s[t]; swf[256 + t] = wfattn_s[256 + t];
  swa[t] = wattn_s[t];  swa[256 + t] = wattn_s[256 + t];
  scw[t] = CWFW[(size_t)b * 1024 + t] + battn[t];
  scw[256 + t] = CWFW[(size_t)b * 1024 + 256 + t] + battn[256 + t];
  __syncthreads();
  int w = t >> 6, lane = t & 63;
  float wav[8], wfv[8], cwv[8];
  #pragma unroll
  for (int i = 0; i < 8; ++i) {
    int h = lane + 64 * i;
    wav[i] = swa[h]; wfv[i] = swf[h]; cwv[i] = scw[h];
  }
  #pragma unroll
  for (int si = 0; si < 2; ++si) {
    int s = s0 + w * 2 + si;
    int msk = seq_mask[b * 256 + s];
    if (msk) {
      if (lane == 0) {
        en[b * 256 + s] = NEG;
        for (int r = 0; r < 16; ++r) fen[((size_t)b * 16 + r) * 256 + s] = NEG;
      }
      continue;
    }
    const u16* ew = EW + (size_t)(s * 32 + b) * 1024;
    float ewf[8];
    float accE = 0.f;
    #pragma unroll
    for (int i = 0; i < 8; ++i) {
      int h = lane + 64 * i;
      accE += ptanh(cwv[i] + bf2f(ew[h])) * wav[i];
      ewf[i] = bf2f(ew[512 + h]);
    }
    for (int o = 32; o >= 1; o >>= 1) accE += __shfl_down(accE, o);
    if (lane == 0) en[b * 256 + s] = accE + battn_s[0];
    for (int r = 0; r < 16; ++r) {
      float a = 0.f;
      #pragma unroll
      for (int i = 0; i < 8; ++i) {
        int h = lane + 64 * i;
        a += ptanh(sFW[r * 512 + h] + ewf[i]) * wfv[i];
      }
      for (int o = 32; o >= 1; o >>= 1) a += __shfl_down(a, o);
      if (lane == 0) fen[((size_t)b * 16 + r) * 256 + s] = a + bfattn_s[0];
    }
  }
}

// ---------- softmaxes + contexts, j-paired (9 blocks per b) ----------
__global__ __launch_bounds__(512) void k_ctxall(
    const float* __restrict__ en, const float* __restrict__ fen,
    const u16* __restrict__ encb, const float* __restrict__ cur_node,
    float* __restrict__ out_ctx, float* __restrict__ leaf, u16* __restrict__ fctxb,
    u16* __restrict__ leafb) {
  int br = blockIdx.x;           // 288 = 32 * 9
  int b = br / 9, k = br % 9;
  int t = threadIdx.x;
  __shared__ float red[512];
  __shared__ float sa0[256], sa1[256];
  float xe = (t < 256) ? en[b * 256 + t] : NEG;
  red[t] = xe; __syncthreads();
  for (int o = 256; o > 0; o >>= 1) { if (t < o) red[t] = fmaxf(red[t], red[t + o]); __syncthreads(); }
  float m = red[0]; __syncthreads();
  float ee = (t < 256) ? __expf(xe - m) : 0.f;
  red[t] = ee; __syncthreads();
  for (int o = 256; o > 0; o >>= 1) { if (t < o) red[t] += red[t + o]; __syncthreads(); }
  float attn_v = ee / red[0];
  __syncthreads();
  if (k < 8) {
    #pragma unroll
    for (int p = 0; p < 2; ++p) {
      int j = k + p * 8;
      float xf = (t < 256) ? fen[((size_t)b * 16 + j) * 256 + t] : NEG;
      red[t] = xf; __syncthreads();
      for (int o = 256; o > 0; o >>= 1) { if (t < o) red[t] = fmaxf(red[t], red[t + o]); __syncthreads(); }
      float mf = red[0]; __syncthreads();
      float ef = (t < 256) ? __expf(xf - mf) : 0.f;
      red[t] = ef; __syncthreads();
      for (int o = 256; o > 0; o >>= 1) { if (t < o) red[t] += red[t + o]; __syncthreads(); }
      float coef = ef / red[0] + 0.2f * attn_v;
      __syncthreads();
      if (t < 256) { if (p == 0) sa0[t] = coef; else sa1[t] = coef; }
    }
    __syncthreads();
    int h = t;
    float acc0 = 0.f, acc1 = 0.f;
    #pragma unroll 8
    for (int s = 0; s < 256; ++s) {
      float ev = bf2f(encb[((size_t)s * 32 + b) * 512 + h]);
      acc0 += sa0[s] * ev;
      acc1 += sa1[s] * ev;
    }
    fctxb[((size_t)b * 16 + k) * 512 + h] = f2u(acc0);
    fctxb[((size_t)b * 16 + k + 8) * 512 + h] = f2u(acc1);
  } else {
    if (t < 256) sa0[t] = attn_v;
    __syncthreads();
    int h = t;
    float acc = 0.f;
    #pragma unroll 8
    for (int s = 0; s < 256; ++s)
      acc += sa0[s] * bf2f(encb[((size_t)s * 32 + b) * 512 + h]);
    float cn = cur_node[b * 512 + h];
    out_ctx[b * 512 + h] = acc;
    leaf[b * 1024 + 512 + h] = acc;
    leaf[b * 1024 + h] = cn;
    leafb[b * 1024 + h] = f2u(cn);
    leafb[b * 1024 + 512 + h] = f2u(acc);
  }
}

// ---------- epilogue: num_score + formula_prob ----------
__global__ __launch_bounds__(256) void k_epi(
    const float* __restrict__ Tep, const float* __restrict__ Tlp,
    const float* __restrict__ bscore,
    const float* __restrict__ wscore_s, const int* __restrict__ mask_nums,
    float* __restrict__ out_ns,
    const float* __restrict__ T3p, const float* __restrict__ bfp1,
    const float* __restrict__ Wfp2, const float* __restrict__ bfp2,
    float* __restrict__ out_fp) {
  int id = blockIdx.x, t = threadIdx.x;
  int w = t >> 6, lane = t & 63;
  __shared__ float red[16];
  if (id < 640) {
    int row = id;
    int b = row / 20;
    float acc = 0.f;
    #pragma unroll
    for (int i = 0; i < 2; ++i) {
      int h = t + 256 * i;
      float tv = bscore[h];
      #pragma unroll
      for (int z = 0; z < 4; ++z) tv += Tep[(size_t)z * 327680 + (size_t)row * 512 + h];
      #pragma unroll
      for (int z = 0; z < 4; ++z) tv += Tlp[(size_t)z * 32768 + (size_t)b * 512 + h];
      acc += ftanh(tv) * wscore_s[h];
    }
    for (int o = 32; o >= 1; o >>= 1) acc += __shfl_down(acc, o);
    if (lane == 0) red[w] = acc;
    __syncthreads();
    if (t == 0) out_ns[row] = mask_nums[row] ? NEG : (red[0] + red[1] + red[2] + red[3]);
  } else {
    int b = id - 640;
    #pragma unroll
    for (int j2 = 0; j2 < 4; ++j2) {
      int j = w * 4 + j2;
      int row = b * 16 + j;
      float acc = 0.f;
      #pragma unroll
      for (int i = 0; i < 8; ++i) {
        int h = lane + 64 * i;
        float v = bfp1[h];
        #pragma unroll
        for (int z = 0; z < 4; ++z) v += T3p[(size_t)z * 262144 + (size_t)row * 512 + h];
        acc += ftanh(v) * Wfp2[h];
      }
      for (int o = 32; o >= 1; o >>= 1) acc += __shfl_down(acc, o);
      if (lane == 0) red[j] = acc + bfp2[0];
    }
    __syncthreads();
    if (t < 16) {
      float xx = red[t];
      float mm = xx;
      for (int o = 8; o >= 1; o >>= 1) mm = fmaxf(mm, __shfl_xor(mm, o, 16));
      float e = __expf(xx - mm);
      float s2 = e;
      for (int o = 8; o >= 1; o >>= 1) s2 += __shfl_xor(s2, o, 16);
      out_fp[b * 16 + t] = e / s2;
    }
  }
}

extern "C" void kernel_launch(void* const* d_in, const int* in_sizes, int n_in,
                              void* d_out, int out_size, void* d_ws, size_t ws_size,
                              hipStream_t stream) {
  const float* node_emb  = (const float*)d_in[0];
  const float* left      = (const float*)d_in[1];
  const float* enc       = (const float*)d_in[2];
  const float* num_pades = (const float*)d_in[3];
  const float* fs        = (const float*)d_in[4];
  const int*   has_left  = (const int*)d_in[5];
  const int*   seq_mask  = (const int*)d_in[6];
  const int*   mask_nums = (const int*)d_in[7];
  const float* emb_w     = (const float*)d_in[8];
  const float* Wcl  = (const float*)d_in[9];
  const float* bcl  = (const float*)d_in[10];
  const float* Wclg = (const float*)d_in[11];
  const float* bclg = (const float*)d_in[12];
  const float* Wcr  = (const float*)d_in[13];
  const float* bcr  = (const float*)d_in[14];
  const float* Wcrg = (const float*)d_in[15];
  const float* bcrg = (const float*)d_in[16];
  const float* Wops = (const float*)d_in[17];
  const float* bops = (const float*)d_in[18];
  const float* Wattn   = (const float*)d_in[19];
  const float* battn   = (const float*)d_in[20];
  const float* wattn_s = (const float*)d_in[21];
  const float* battn_s = (const float*)d_in[22];
  const float* Wfattn   = (const float*)d_in[23];
  const float* bfattn   = (const float*)d_in[24];
  const float* wfattn_s = (const float*)d_in[25];
  const float* bfattn_s = (const float*)d_in[26];
  const float* Wscore   = (const float*)d_in[27];
  const float* bscore   = (const float*)d_in[28];
  const float* wscore_s = (const float*)d_in[29];
  const float* Wfp1 = (const float*)d_in[30];
  const float* bfp1 = (const float*)d_in[31];
  const float* Wfp2 = (const float*)d_in[32];
  const float* bfp2 = (const float*)d_in[33];

  float* out = (float*)d_out;
  float* out_ns   = out + 0;
  float* out_op   = out + 640;
  float* out_cn   = out + 832;
  float* out_ctx  = out + 17216;
  float* out_embw = out + 33600;
  float* out_fp   = out + 361280;

  // ws is 256 MiB
  uint8_t* wsb = (uint8_t*)d_ws;
  u16*   encb = (u16*)(wsb + 0);              //  8,388,608
  u16*   Wt   = (u16*)(wsb + 8388608);        //  1,048,576
  u16*   Wt2a = (u16*)(wsb + 9437184);        //    524,288
  u16*   Wt2b = (u16*)(wsb + 9961472);        //  1,048,576
  u16*   Wt3  = (u16*)(wsb + 11010048);       //    524,288
  u16*   Wt4  = (u16*)(wsb + 11534336);       //  1,048,576
  u16*   EW   = (u16*)(wsb + 12582912);       // 16,777,216
  u16*   embb = (u16*)(wsb + 29360128);       //    655,360
  u16*   leafb= (u16*)(wsb + 30015488);       //    131,072
  u16*   cnfs = (u16*)(wsb + 30146560);       //    131,072
  float* CWFW = (float*)(wsb + 30277632);     //    524,288
  float* Tep  = (float*)(wsb + 30801920);     //  5,242,880
  float* Tlp  = (float*)(wsb + 36044800);     //    524,288
  float* T3p  = (float*)(wsb + 36569088);     //  4,194,304
  float* fb   = (float*)(wsb + 40763392);
  float* cur_node = fb + 0;          // 16384
  float* en   = fb + 16384;          // 8192
  float* fen  = fb + 24576;          // 131072
  float* leaf = fb + 155648;         // 32768
  u16*   fctxb= (u16*)(fb + 188416); // 262144 u16
  float* gp1  = fb + 319488;         // 131072
  float* gp2  = fb + 450560;         // 131072

  // 1. mega prep (inputs only)
  k_prep1<<<3144, 256, 0, stream>>>(enc, encb, Wattn, Wfattn, Wt, Wscore, Wt2a, Wt2b,
                                    Wfp1, Wt3, Wt4,
                                    node_emb, left, has_left, Wcl, Wclg, Wcr, Wcrg,
                                    gp1, gp2, emb_w, num_pades, out_embw, embb, leafb);
  // 2. finish gates -> cur_node + cnfs
  k_p2<<<128, 256, 0, stream>>>(gp1, gp2, has_left, bcl, bclg, bcr, bcrg, fs,
                                cur_node, out_cn, cnfs);
  // 3. G1: EW GEMM + CWFW GEMM + T_emb GEMM (co-scheduled)
  k_g1<<<840, 256, 0, stream>>>(encb, Wt, EW, cnfs, Wt4, CWFW, embb, Wt2a, Tep);
  // 4. attention scores (mask-skip, Pade tanh, 8 s/block)
  k_enfen<<<1024, 256, 0, stream>>>(EW, CWFW, battn, bfattn, wattn_s, battn_s,
                                    wfattn_s, bfattn_s, seq_mask, en, fen);
  // 5. softmaxes + contexts, j-paired (+ leafb)
  k_ctxall<<<288, 512, 0, stream>>>(en, fen, encb, cur_node, out_ctx, leaf, fctxb, leafb);
  // 6. T_leaf + T3 GEMMs + op reduce
  k_tt<<<480, 256, 0, stream>>>(leafb, Wt2b, Tlp, fctxb, Wt3, T3p,
                                leaf, Wops, bops, out_op);
  // 7. epilogue: ns + ffprob
  k_epi<<<672, 256, 0, stream>>>(Tep, Tlp, bscore, wscore_s, mask_nums, out_ns,
                                 T3p, bfp1, Wfp2, bfp2, out_fp);
}

// Round 10
// 99.331 us; speedup vs baseline: 4.1242x; 1.0554x over previous
//
#include <hip/hip_runtime.h>
#include <hip/hip_bf16.h>
#include <stdint.h>

#define H 512
#define S 256
#define B 32
#define R 16
#define NEG -1000000000000.0f

typedef unsigned short u16;
typedef short short8 __attribute__((ext_vector_type(8)));
typedef float f32x4 __attribute__((ext_vector_type(4)));

__device__ __forceinline__ float bf2f(u16 u) {
  unsigned int v = ((unsigned int)u) << 16;
  float f; __builtin_memcpy(&f, &v, 4); return f;
}
__device__ __forceinline__ u16 f2u(float x) {
  __hip_bfloat16 h = __float2bfloat16(x);
  u16 u; __builtin_memcpy(&u, &h, 2); return u;
}
__device__ __forceinline__ float ftanh(float x) {
  float e = __expf(2.f * x);
  return 1.f - 2.f * __builtin_amdgcn_rcpf(e + 1.f);
}
// Pade(5,4) tanh
__device__ __forceinline__ float ptanh(float x) {
  float xc = fminf(4.f, fmaxf(-4.f, x));
  float x2 = xc * xc;
  float num = xc * (945.f + x2 * (105.f + x2));
  float den = 945.f + x2 * (420.f + 15.f * x2);
  return num * __builtin_amdgcn_rcpf(den);
}
__device__ __forceinline__ float fsig(float x) {
  return __builtin_amdgcn_rcpf(1.f + __expf(-x));
}
__device__ __forceinline__ void gload16(const void* g, void* l) {
  __builtin_amdgcn_global_load_lds(
      (const __attribute__((address_space(1))) unsigned int*)g,
      (__attribute__((address_space(3))) unsigned int*)l, 16, 0, 0);
}

// ---------- trans tile helper ----------
__device__ __forceinline__ void trans_tile(const float* __restrict__ src, int nb, int k0,
                                           u16* __restrict__ dst, int n0, int Krows,
                                           float (*tile)[65], int t) {
  #pragma unroll
  for (int it = 0; it < 16; ++it) {
    int f = it * 256 + t; int r = f >> 6, c = f & 63;
    tile[r][c] = src[(size_t)(k0 + r) * 512 + nb + c];
  }
  __syncthreads();
  #pragma unroll
  for (int it = 0; it < 16; ++it) {
    int f = it * 256 + t; int r = f >> 6, c = f & 63;
    dst[(size_t)(n0 + r) * Krows + k0 + c] = f2u(tile[c][r]);
  }
}

// ---------- mega prep ----------
__global__ __launch_bounds__(256) void k_prep1(
    const float* __restrict__ enc, u16* __restrict__ encb, u16* __restrict__ encc,
    const float* __restrict__ Wattn, const float* __restrict__ Wfattn, u16* __restrict__ Wt,
    const float* __restrict__ Wscore, u16* __restrict__ Wt2a, u16* __restrict__ Wt2b,
    const float* __restrict__ Wfp1, u16* __restrict__ Wt3,
    u16* __restrict__ Wt4,
    const float* __restrict__ node_emb, const float* __restrict__ left,
    const int* __restrict__ has_left,
    const float* __restrict__ Wcl, const float* __restrict__ Wclg,
    const float* __restrict__ Wcr, const float* __restrict__ Wcrg,
    float* __restrict__ gp1, float* __restrict__ gp2,
    const float* __restrict__ emb_w, const float* __restrict__ num_pades,
    float* __restrict__ out_embw, u16* __restrict__ embb, u16* __restrict__ leafb) {
  __shared__ float tile[64][65];
  __shared__ float x[128];
  int id = blockIdx.x, t = threadIdx.x;
  if (id < 2048) {
    int i = (id * 256 + t) * 8;
    float4 a = *(const float4*)(enc + i);
    float4 b4 = *(const float4*)(enc + i + 4);
    short8 o;
    o[0] = (short)f2u(a.x); o[1] = (short)f2u(a.y); o[2] = (short)f2u(a.z); o[3] = (short)f2u(a.w);
    o[4] = (short)f2u(b4.x); o[5] = (short)f2u(b4.y); o[6] = (short)f2u(b4.z); o[7] = (short)f2u(b4.w);
    *(short8*)(encb + i) = o;
    int s = i >> 14, b = (i >> 9) & 31, h = i & 511;
    *(short8*)(encc + (((size_t)b << 8) + s) * 512 + h) = o;
  } else if (id < 2176) {            // Wt: [We | Wfe] -> [1024][512]
    int f = id - 2048; int gx = f & 15, gy = f >> 4;
    int n0 = gx * 64, k0 = gy * 64;
    const float* src = (n0 < 512) ? (Wattn + 512 * 512) : Wfattn;
    int nb = (n0 < 512) ? n0 : n0 - 512;
    trans_tile(src, nb, k0, Wt, n0, 512, tile, t);
  } else if (id < 2240) {            // Wt2a: Wscore[1024:]^T [512][512]
    int f = id - 2176; int gx = f & 7, gy = f >> 3;
    trans_tile(Wscore + 1024 * 512, gx * 64, gy * 64, Wt2a, gx * 64, 512, tile, t);
  } else if (id < 2368) {            // Wt2b: Wscore[:1024]^T [512][1024]
    int f = id - 2240; int gx = f & 7, gy = f >> 3;
    trans_tile(Wscore, gx * 64, gy * 64, Wt2b, gx * 64, 1024, tile, t);
  } else if (id < 2432) {            // Wt3: Wfp1^T [512][512]
    int f = id - 2368; int gx = f & 7, gy = f >> 3;
    trans_tile(Wfp1, gx * 64, gy * 64, Wt3, gx * 64, 512, tile, t);
  } else if (id < 2560) {            // Wt4: [Wh^T | Wff^T] -> [1024][512]
    int f = id - 2432; int gx = f & 15, gy = f >> 4;
    int n0 = gx * 64, k0 = gy * 64;
    const float* src = (n0 < 512) ? Wattn : (Wfattn + 512 * 512);
    int nb = (n0 < 512) ? n0 : n0 - 512;
    trans_tile(src, nb, k0, Wt4, n0, 512, tile, t);
  } else if (id < 2816) {            // gates partials
    int f = id - 2560;
    int b = f >> 3, kc = f & 7;
    int hl = has_left[b];
    int k0 = kc * 128;
    float* o1 = gp1 + ((size_t)b * 8 + kc) * 512;
    float* o2 = gp2 + ((size_t)b * 8 + kc) * 512;
    if (!hl && kc >= 4) { o1[t] = 0.f; o1[t + 256] = 0.f; o2[t] = 0.f; o2[t + 256] = 0.f; return; }
    if (t < 128) {
      int k = k0 + t;
      x[t] = hl ? (k < 512 ? left[b * 512 + k] : node_emb[b * 512 + k - 512])
                : node_emb[b * 512 + k];
    }
    __syncthreads();
    const float* W1 = hl ? Wcr : Wcl;
    const float* W2 = hl ? Wcrg : Wclg;
    float a1 = 0.f, a2 = 0.f, a3 = 0.f, a4 = 0.f;
    for (int kk = 0; kk < 128; ++kk) {
      float xv = x[kk];
      const float* w1r = W1 + (size_t)(k0 + kk) * 512;
      const float* w2r = W2 + (size_t)(k0 + kk) * 512;
      a1 += xv * w1r[t]; a2 += xv * w1r[t + 256];
      a3 += xv * w2r[t]; a4 += xv * w2r[t + 256];
    }
    o1[t] = a1; o1[t + 256] = a2; o2[t] = a3; o2[t + 256] = a4;
  } else if (id < 3136) {            // out_embw + embb
    int f = id - 2816;
    #pragma unroll
    for (int rr = 0; rr < 2; ++rr) {
      int row = f * 2 + rr;
      int n = row % 20, b = row / 20;
      #pragma unroll
      for (int i = 0; i < 2; ++i) {
        int h = t + 256 * i;
        float v = (n < 4) ? emb_w[n * 512 + h] : num_pades[((size_t)b * 16 + n - 4) * 512 + h];
        out_embw[(size_t)row * 512 + h] = v;
        embb[(size_t)row * 512 + h] = f2u(v);
      }
    }
  } else {                           // leafb zero-pad rows 32..63
    int f = id - 3136;               // f < 8
    int base = 32 * 1024 + (f * 256 + t) * 16;
    short8 z8 = {0,0,0,0,0,0,0,0};
    *(short8*)(leafb + base) = z8;
    *(short8*)(leafb + base + 8) = z8;
  }
}

// ---------- GEMM device body ----------
template <int FM, int FN>
__device__ __forceinline__ void gemm_body(
    const u16* __restrict__ A, const u16* __restrict__ Bt,
    u16* __restrict__ C16, float* __restrict__ C32,
    int lda, int ldb, int ldc, int ksteps,
    int bm, int bn, int kbase, long zoff,
    u16* As, u16* Bs) {
  constexpr int BM = FM * 32, BN = FN * 32;
  const int tid = threadIdx.x;
  const int lane = tid & 63;
  const int wid = tid >> 6;
  const int wr = (wid >> 1) * (FM * 16);
  const int wc = (wid & 1) * (FN * 16);
  f32x4 acc[FM][FN];
  #pragma unroll
  for (int m = 0; m < FM; ++m)
    #pragma unroll
    for (int n = 0; n < FN; ++n)
      #pragma unroll
      for (int q = 0; q < 4; ++q) acc[m][n][q] = 0.f;

  const int kb = (lane >> 4) * 8;
  const int rr = lane & 15;
  for (int ks = 0; ks < ksteps; ++ks) {
    int k0 = kbase + ks * 32;
    #pragma unroll
    for (int it = 0; it < BM / 64; ++it) {
      int c = it * 256 + tid;
      gload16(A + (size_t)(bm + (c >> 2)) * lda + k0 + (c & 3) * 8, As + c * 8);
    }
    #pragma unroll
    for (int it = 0; it < BN / 64; ++it) {
      int c = it * 256 + tid;
      gload16(Bt + (size_t)(bn + (c >> 2)) * ldb + k0 + (c & 3) * 8, Bs + c * 8);
    }
    __syncthreads();
    short8 af[FM], bf[FN];
    #pragma unroll
    for (int m = 0; m < FM; ++m)
      af[m] = *(const short8*)(As + (wr + m * 16 + rr) * 32 + kb);
    #pragma unroll
    for (int n = 0; n < FN; ++n)
      bf[n] = *(const short8*)(Bs + (wc + n * 16 + rr) * 32 + kb);
    #pragma unroll
    for (int m = 0; m < FM; ++m)
      #pragma unroll
      for (int n = 0; n < FN; ++n)
        acc[m][n] = __builtin_amdgcn_mfma_f32_16x16x32_bf16(af[m], bf[n], acc[m][n], 0, 0, 0);
    __syncthreads();
  }
  int r0 = (lane >> 4) * 4, cc = lane & 15;
  #pragma unroll
  for (int m = 0; m < FM; ++m)
    #pragma unroll
    for (int n = 0; n < FN; ++n)
      #pragma unroll
      for (int q = 0; q < 4; ++q) {
        long row = bm + wr + m * 16 + r0 + q;
        long col = bn + wc + n * 16 + cc;
        if (C16) C16[zoff + row * ldc + col] = f2u(acc[m][n][q]);
        else     C32[zoff + row * ldc + col] = acc[m][n][q];
      }
}

// ---------- G1: EW GEMM (512) + CWFW GEMM (8) + T_emb GEMM (160, z=2) ----------
__global__ __launch_bounds__(256) void k_g1(
    const u16* __restrict__ encb, const u16* __restrict__ Wt, u16* __restrict__ EW,
    const u16* __restrict__ cnfs, const u16* __restrict__ Wt4, float* __restrict__ CWFW,
    const u16* __restrict__ embb, const u16* __restrict__ Wt2a, float* __restrict__ Tep) {
  __shared__ u16 As[128 * 32];
  __shared__ u16 Bs[128 * 32];
  int q = blockIdx.x;
  if (q < 512) {
    int x = q & 63, y = q >> 6;
    gemm_body<4, 4>(encb, Wt, EW, nullptr, 512, 512, 1024, 16, x * 128, y * 128, 0, 0, As, Bs);
  } else if (q < 520) {
    int y = q - 512;
    gemm_body<4, 4>(cnfs, Wt4, nullptr, CWFW, 512, 512, 1024, 16, 0, y * 128, 0, 0, As, Bs);
  } else {                      // T_emb: 640x512 @ K=512, z=2
    int q2 = q - 520;
    int x = q2 % 10, y = (q2 / 10) % 8, z = q2 / 80;
    gemm_body<2, 2>(embb, Wt2a, nullptr, Tep, 512, 512, 512, 8,
                    x * 64, y * 64, z * 8 * 32, (long)z * 327680, As, Bs);
  }
}

// ---------- tt: T_leaf (32) + T3 (256) GEMMs + op reduce (192) ----------
__global__ __launch_bounds__(256) void k_tt(
    const u16* __restrict__ leafb, const u16* __restrict__ Wt2b, float* __restrict__ Tlp,
    const u16* __restrict__ fctxb, const u16* __restrict__ Wt3, float* __restrict__ T3p,
    const float* __restrict__ leaf, const float* __restrict__ Wops,
    const float* __restrict__ bops, float* __restrict__ out_op) {
  __shared__ u16 As[64 * 32];
  __shared__ u16 Bs[64 * 32];
  __shared__ float red[4];
  int q = blockIdx.x;
  if (q < 32) {                  // T_leaf: 64x512 @ K=1024, z=4
    int y = q % 8, z = q / 8;
    gemm_body<2, 2>(leafb, Wt2b, nullptr, Tlp, 1024, 1024, 512, 8,
                    0, y * 64, z * 8 * 32, (long)z * 32768, As, Bs);
  } else if (q < 288) {          // T3: 512x512 @ K=512, z=4
    int q2 = q - 32;
    int x = q2 % 8, y = (q2 / 8) % 8, z = q2 / 64;
    gemm_body<2, 2>(fctxb, Wt3, nullptr, T3p, 512, 512, 512, 4,
                    x * 64, y * 64, z * 4 * 32, (long)z * 262144, As, Bs);
  } else {                       // op reduce
    int f = q - 288; int o = f % 6, b = f / 6;
    int t = threadIdx.x, w = t >> 6, lane = t & 63;
    float acc = 0.f;
    #pragma unroll
    for (int i = 0; i < 4; ++i) {
      int k = t + 256 * i;
      acc += leaf[b * 1024 + k] * Wops[(size_t)k * 6 + o];
    }
    for (int off = 32; off >= 1; off >>= 1) acc += __shfl_down(acc, off);
    if (lane == 0) red[w] = acc;
    __syncthreads();
    if (t == 0) out_op[b * 6 + o] = red[0] + red[1] + red[2] + red[3] + bops[o];
  }
}

// ---------- p2lite: finish gates -> cur_node/out_cn/cnfs; fs rows; zero pad ----------
__global__ __launch_bounds__(256) void k_p2(
    const float* __restrict__ gp1, const float* __restrict__ gp2,
    const int* __restrict__ has_left,
    const float* __restrict__ bcl, const float* __restrict__ bclg,
    const float* __restrict__ bcr, const float* __restrict__ bcrg,
    const float* __restrict__ fs,
    float* __restrict__ cur_node, float* __restrict__ out_cn, u16* __restrict__ cnfs) {
  int id = blockIdx.x, t = threadIdx.x;
  if (id < 32) {
    int b = id, hl = has_left[b];
    #pragma unroll
    for (int i = 0; i < 2; ++i) {
      int h = t + 256 * i;
      float s1 = 0.f, s2 = 0.f;
      #pragma unroll
      for (int c = 0; c < 8; ++c) {
        s1 += gp1[((size_t)b * 8 + c) * 512 + h];
        s2 += gp2[((size_t)b * 8 + c) * 512 + h];
      }
      float v = ftanh(s1 + (hl ? bcr[h] : bcl[h])) * fsig(s2 + (hl ? bcrg[h] : bclg[h]));
      cur_node[b * 512 + h] = v;
      out_cn[b * 512 + h] = v;
      cnfs[b * 512 + h] = f2u(v);
    }
  } else if (id < 48) {
    int r = id - 32;
    #pragma unroll
    for (int i = 0; i < 2; ++i) {
      int h = t + 256 * i;
      cnfs[id * 512 + h] = f2u(fs[r * 512 + h]);
    }
  } else {
    #pragma unroll
    for (int i = 0; i < 2; ++i) cnfs[id * 512 + t + 256 * i] = 0;
  }
}

// ---------- en + fen fused (mask-skip, shared sFW reads across s-pair) ----------
__global__ __launch_bounds__(256) void k_enfen(
    const u16* __restrict__ EW, const float* __restrict__ CWFW,
    const float* __restrict__ battn, const float* __restrict__ bfattn,
    const float* __restrict__ wattn_s, const float* __restrict__ battn_s,
    const float* __restrict__ wfattn_s, const float* __restrict__ bfattn_s,
    const int* __restrict__ seq_mask, float* __restrict__ en, float* __restrict__ fen) {
  __shared__ float sFW[16 * 512];
  __shared__ float swf[512], swa[512], scw[512];
  int bid = blockIdx.x;          // 1024 = 32 b * 32 s-chunks
  int b = bid >> 5;
  int s0 = (bid & 31) * 8;
  int t = threadIdx.x;
  #pragma unroll
  for (int q = 0; q < 32; ++q) {
    int flat = q * 256 + t;
    int r = flat >> 9, h = flat & 511;
    sFW[flat] = CWFW[(size_t)(32 + r) * 1024 + 512 + h] + bfattn[h];
  }
  swf[t] = wfattn_s[t]; swf[256 + t] = wfattn_s[256 + t];
  swa[t] = wattn_s[t];  swa[256 + t] = wattn_s[256 + t];
  scw[t] = CWFW[(size_t)b * 1024 + t] + battn[t];
  scw[256 + t] = CWFW[(size_t)b * 1024 + 256 + t] + battn[256 + t];
  __syncthreads();
  int w = t >> 6, lane = t & 63;
  int sA = s0 + w * 2, sB = sA + 1;
  int mA = seq_mask[b * 256 + sA], mB = seq_mask[b * 256 + sB];
  if (mA && mB) {
    if (lane == 0) {
      en[b * 256 + sA] = NEG; en[b * 256 + sB] = NEG;
      for (int r = 0; r < 16; ++r) {
        fen[((size_t)b * 16 + r) * 256 + sA] = NEG;
        fen[((size_t)b * 16 + r) * 256 + sB] = NEG;
      }
    }
    return;
  }
  const u16* ewA = EW + (size_t)(sA * 32 + b) * 1024;
  const u16* ewB = EW + (size_t)(sB * 32 + b) * 1024;
  float ewfA[8], ewfB[8], wfv[8];
  float accA = 0.f, accB = 0.f;
  #pragma unroll
  for (int i = 0; i < 8; ++i) {
    int h = lane + 64 * i;
    float cw = scw[h], wa = swa[h];
    accA += ptanh(cw + bf2f(ewA[h])) * wa;
    accB += ptanh(cw + bf2f(ewB[h])) * wa;
    ewfA[i] = bf2f(ewA[512 + h]);
    ewfB[i] = bf2f(ewB[512 + h]);
    wfv[i] = swf[h];
  }
  for (int o = 32; o >= 1; o >>= 1) {
    accA += __shfl_down(accA, o);
    accB += __shfl_down(accB, o);
  }
  if (lane == 0) {
    en[b * 256 + sA] = mA ? NEG : (accA + battn_s[0]);
    en[b * 256 + sB] = mB ? NEG : (accB + battn_s[0]);
  }
  for (int r = 0; r < 16; ++r) {
    float a0 = 0.f, a1 = 0.f;
    #pragma unroll
    for (int i = 0; i < 8; ++i) {
      int h = lane + 64 * i;
      float fwv = sFW[r * 512 + h];
      a0 += ptanh(fwv + ewfA[i]) * wfv[i];
      a1 += ptanh(fwv + ewfB[i]) * wfv[i];
    }
    for (int o = 32; o >= 1; o >>= 1) {
      a0 += __shfl_down(a0, o);
      a1 += __shfl_down(a1, o);
    }
    if (lane == 0) {
      fen[((size_t)b * 16 + r) * 256 + sA] = mA ? NEG : (a0 + bfattn_s[0]);
      fen[((size_t)b * 16 + r) * 256 + sB] = mB ? NEG : (a1 + bfattn_s[0]);
    }
  }
}

// ---------- softmaxes + contexts, j-paired, contiguous encc ----------
__global__ __launch_bounds__(512) void k_ctxall(
    const float* __restrict__ en, const float* __restrict__ fen,
    const u16* __restrict__ encc, const float* __restrict__ cur_node,
    float* __restrict__ out_ctx, float* __restrict__ leaf, u16* __restrict__ fctxb,
    u16* __restrict__ leafb) {
  int br = blockIdx.x;           // 288 = 32 * 9
  int b = br / 9, k = br % 9;
  int t = threadIdx.x;
  __shared__ float red[512];
  __shared__ float sa0[256], sa1[256];
  float xe = (t < 256) ? en[b * 256 + t] : NEG;
  red[t] = xe; __syncthreads();
  for (int o = 256; o > 0; o >>= 1) { if (t < o) red[t] = fmaxf(red[t], red[t + o]); __syncthreads(); }
  float m = red[0]; __syncthreads();
  float ee = (t < 256) ? __expf(xe - m) : 0.f;
  red[t] = ee; __syncthreads();
  for (int o = 256; o > 0; o >>= 1) { if (t < o) red[t] += red[t + o]; __syncthreads(); }
  float attn_v = ee / red[0];
  __syncthreads();
  const u16* eb = encc + (size_t)b * 131072;
  if (k < 8) {
    #pragma unroll
    for (int p = 0; p < 2; ++p) {
      int j = k + p * 8;
      float xf = (t < 256) ? fen[((size_t)b * 16 + j) * 256 + t] : NEG;
      red[t] = xf; __syncthreads();
      for (int o = 256; o > 0; o >>= 1) { if (t < o) red[t] = fmaxf(red[t], red[t + o]); __syncthreads(); }
      float mf = red[0]; __syncthreads();
      float ef = (t < 256) ? __expf(xf - mf) : 0.f;
      red[t] = ef; __syncthreads();
      for (int o = 256; o > 0; o >>= 1) { if (t < o) red[t] += red[t + o]; __syncthreads(); }
      float coef = ef / red[0] + 0.2f * attn_v;
      __syncthreads();
      if (t < 256) { if (p == 0) sa0[t] = coef; else sa1[t] = coef; }
    }
    __syncthreads();
    int h = t;
    float acc0 = 0.f, acc1 = 0.f;
    #pragma unroll 8
    for (int s = 0; s < 256; ++s) {
      float ev = bf2f(eb[(size_t)s * 512 + h]);
      acc0 += sa0[s] * ev;
      acc1 += sa1[s] * ev;
    }
    fctxb[((size_t)b * 16 + k) * 512 + h] = f2u(acc0);
    fctxb[((size_t)b * 16 + k + 8) * 512 + h] = f2u(acc1);
  } else {
    if (t < 256) sa0[t] = attn_v;
    __syncthreads();
    int h = t;
    float acc = 0.f;
    #pragma unroll 8
    for (int s = 0; s < 256; ++s)
      acc += sa0[s] * bf2f(eb[(size_t)s * 512 + h]);
    float cn = cur_node[b * 512 + h];
    out_ctx[b * 512 + h] = acc;
    leaf[b * 1024 + 512 + h] = acc;
    leaf[b * 1024 + h] = cn;
    leafb[b * 1024 + h] = f2u(cn);
    leafb[b * 1024 + 512 + h] = f2u(acc);
  }
}

// ---------- epilogue: num_score + formula_prob ----------
__global__ __launch_bounds__(256) void k_epi(
    const float* __restrict__ Tep, const float* __restrict__ Tlp,
    const float* __restrict__ bscore,
    const float* __restrict__ wscore_s, const int* __restrict__ mask_nums,
    float* __restrict__ out_ns,
    const float* __restrict__ T3p, const float* __restrict__ bfp1,
    const float* __restrict__ Wfp2, const float* __restrict__ bfp2,
    float* __restrict__ out_fp) {
  int id = blockIdx.x, t = threadIdx.x;
  int w = t >> 6, lane = t & 63;
  __shared__ float red[16];
  if (id < 640) {
    int row = id;
    int b = row / 20;
    float acc = 0.f;
    #pragma unroll
    for (int i = 0; i < 2; ++i) {
      int h = t + 256 * i;
      float tv = bscore[h];
      #pragma unroll
      for (int z = 0; z < 2; ++z) tv += Tep[(size_t)z * 327680 + (size_t)row * 512 + h];
      #pragma unroll
      for (int z = 0; z < 4; ++z) tv += Tlp[(size_t)z * 32768 + (size_t)b * 512 + h];
      acc += ftanh(tv) * wscore_s[h];
    }
    for (int o = 32; o >= 1; o >>= 1) acc += __shfl_down(acc, o);
    if (lane == 0) red[w] = acc;
    __syncthreads();
    if (t == 0) out_ns[row] = mask_nums[row] ? NEG : (red[0] + red[1] + red[2] + red[3]);
  } else {
    int b = id - 640;
    #pragma unroll
    for (int j2 = 0; j2 < 4; ++j2) {
      int j = w * 4 + j2;
      int row = b * 16 + j;
      float acc = 0.f;
      #pragma unroll
      for (int i = 0; i < 8; ++i) {
        int h = lane + 64 * i;
        float v = bfp1[h];
        #pragma unroll
        for (int z = 0; z < 4; ++z) v += T3p[(size_t)z * 262144 + (size_t)row * 512 + h];
        acc += ftanh(v) * Wfp2[h];
      }
      for (int o = 32; o >= 1; o >>= 1) acc += __shfl_down(acc, o);
      if (lane == 0) red[j] = acc + bfp2[0];
    }
    __syncthreads();
    if (t < 16) {
      float xx = red[t];
      float mm = xx;
      for (int o = 8; o >= 1; o >>= 1) mm = fmaxf(mm, __shfl_xor(mm, o, 16));
      float e = __expf(xx - mm);
      float s2 = e;
      for (int o = 8; o >= 1; o >>= 1) s2 += __shfl_xor(s2, o, 16);
      out_fp[b * 16 + t] = e / s2;
    }
  }
}

extern "C" void kernel_launch(void* const* d_in, const int* in_sizes, int n_in,
                              void* d_out, int out_size, void* d_ws, size_t ws_size,
                              hipStream_t stream) {
  const float* node_emb  = (const float*)d_in[0];
  const float* left      = (const float*)d_in[1];
  const float* enc       = (const float*)d_in[2];
  const float* num_pades = (const float*)d_in[3];
  const float* fs        = (const float*)d_in[4];
  const int*   has_left  = (const int*)d_in[5];
  const int*   seq_mask  = (const int*)d_in[6];
  const int*   mask_nums = (const int*)d_in[7];
  const float* emb_w     = (const float*)d_in[8];
  const float* Wcl  = (const float*)d_in[9];
  const float* bcl  = (const float*)d_in[10];
  const float* Wclg = (const float*)d_in[11];
  const float* bclg = (const float*)d_in[12];
  const float* Wcr  = (const float*)d_in[13];
  const float* bcr  = (const float*)d_in[14];
  const float* Wcrg = (const float*)d_in[15];
  const float* bcrg = (const float*)d_in[16];
  const float* Wops = (const float*)d_in[17];
  const float* bops = (const float*)d_in[18];
  const float* Wattn   = (const float*)d_in[19];
  const float* battn   = (const float*)d_in[20];
  const float* wattn_s = (const float*)d_in[21];
  const float* battn_s = (const float*)d_in[22];
  const float* Wfattn   = (const float*)d_in[23];
  const float* bfattn   = (const float*)d_in[24];
  const float* wfattn_s = (const float*)d_in[25];
  const float* bfattn_s = (const float*)d_in[26];
  const float* Wscore   = (const float*)d_in[27];
  const float* bscore   = (const float*)d_in[28];
  const float* wscore_s = (const float*)d_in[29];
  const float* Wfp1 = (const float*)d_in[30];
  const float* bfp1 = (const float*)d_in[31];
  const float* Wfp2 = (const float*)d_in[32];
  const float* bfp2 = (const float*)d_in[33];

  float* out = (float*)d_out;
  float* out_ns   = out + 0;
  float* out_op   = out + 640;
  float* out_cn   = out + 832;
  float* out_ctx  = out + 17216;
  float* out_embw = out + 33600;
  float* out_fp   = out + 361280;

  // ws is 256 MiB
  uint8_t* wsb = (uint8_t*)d_ws;
  u16*   encb = (u16*)(wsb + 0);              //  8,388,608
  u16*   Wt   = (u16*)(wsb + 8388608);        //  1,048,576
  u16*   Wt2a = (u16*)(wsb + 9437184);        //    524,288
  u16*   Wt2b = (u16*)(wsb + 9961472);        //  1,048,576
  u16*   Wt3  = (u16*)(wsb + 11010048);       //    524,288
  u16*   Wt4  = (u16*)(wsb + 11534336);       //  1,048,576
  u16*   EW   = (u16*)(wsb + 12582912);       // 16,777,216
  u16*   embb = (u16*)(wsb + 29360128);       //    655,360
  u16*   leafb= (u16*)(wsb + 30015488);       //    131,072
  u16*   cnfs = (u16*)(wsb + 30146560);       //    131,072
  float* CWFW = (float*)(wsb + 30277632);     //    524,288
  float* Tep  = (float*)(wsb + 30801920);     //  5,242,880 (z=2 uses 2.5MB)
  float* Tlp  = (float*)(wsb + 36044800);     //    524,288
  float* T3p  = (float*)(wsb + 36569088);     //  4,194,304
  float* fb   = (float*)(wsb + 40763392);
  float* cur_node = fb + 0;          // 16384
  float* en   = fb + 16384;          // 8192
  float* fen  = fb + 24576;          // 131072
  float* leaf = fb + 155648;         // 32768
  u16*   fctxb= (u16*)(fb + 188416); // 262144 u16
  float* gp1  = fb + 319488;         // 131072
  float* gp2  = fb + 450560;         // 131072
  u16*   encc = (u16*)(wsb + 45088768);       //  8,388,608

  // 1. mega prep (inputs only)
  k_prep1<<<3144, 256, 0, stream>>>(enc, encb, encc, Wattn, Wfattn, Wt, Wscore, Wt2a, Wt2b,
                                    Wfp1, Wt3, Wt4,
                                    node_emb, left, has_left, Wcl, Wclg, Wcr, Wcrg,
                                    gp1, gp2, emb_w, num_pades, out_embw, embb, leafb);
  // 2. finish gates -> cur_node + cnfs
  k_p2<<<128, 256, 0, stream>>>(gp1, gp2, has_left, bcl, bclg, bcr, bcrg, fs,
                                cur_node, out_cn, cnfs);
  // 3. G1: EW GEMM + CWFW GEMM + T_emb GEMM (z=2, co-scheduled)
  k_g1<<<680, 256, 0, stream>>>(encb, Wt, EW, cnfs, Wt4, CWFW, embb, Wt2a, Tep);
  // 4. attention scores (mask-skip, shared sFW reads)
  k_enfen<<<1024, 256, 0, stream>>>(EW, CWFW, battn, bfattn, wattn_s, battn_s,
                                    wfattn_s, bfattn_s, seq_mask, en, fen);
  // 5. softmaxes + contexts, j-paired, contiguous encc
  k_ctxall<<<288, 512, 0, stream>>>(en, fen, encc, cur_node, out_ctx, leaf, fctxb, leafb);
  // 6. T_leaf + T3 GEMMs + op reduce
  k_tt<<<480, 256, 0, stream>>>(leafb, Wt2b, Tlp, fctxb, Wt3, T3p,
                                leaf, Wops, bops, out_op);
  // 7. epilogue: ns + ffprob
  k_epi<<<672, 256, 0, stream>>>(Tep, Tlp, bscore, wscore_s, mask_nums, out_ns,
                                 T3p, bfp1, Wfp2, bfp2, out_fp);
}